// Round 1
// baseline (1205.279 us; speedup 1.0000x reference)
//
#include <hip/hip_runtime.h>

// HKSABlock on MI355X (gfx950). Round 1: full correct pipeline, bf16 MFMA GEMMs.
// B=2, T=1024, D=1024, NH=16, HD=64, H=64, M=16.

typedef unsigned short u16;
typedef unsigned int   u32;
typedef __bf16 bf16x8 __attribute__((ext_vector_type(8)));
typedef float  f32x4  __attribute__((ext_vector_type(4)));

#define B_  2
#define T_  1024
#define D_  1024
#define NH_ 16
#define HD_ 64
#define H_  64
#define M_  16

__device__ __forceinline__ float b2f(u16 u) {
    return __uint_as_float(((u32)u) << 16);
}
__device__ __forceinline__ u16 f2b(float f) {
    u32 u = __float_as_uint(f);
    u32 r = (u + 0x7FFFu + ((u >> 16) & 1u)) >> 16;  // RNE
    return (u16)r;
}

// ---------------------------------------------------------------------------
// Generic MFMA GEMM: C[M,N] = A[M,K] * Bt[N,K]^T  (A,Bt bf16 row-major).
// MODE 0: C fp32 (+ optional fp32 addend). MODE 1: C bf16.
// MODE 2: bf16 scatter into o_mat[(b*T + row)*1024 + h*64 + col], z = b*16+h.
// CAUSAL: skip blocks with n0 > m0+BM-1 (for S=Q*K^T).
// TRUNCK: K truncated to m0+BM (for P*V with causal-zeroed P).
// ---------------------------------------------------------------------------
template<int BN, int MODE, bool TRUNCK, bool CAUSAL>
__global__ __launch_bounds__(256) void gemm_bt(
    const u16* __restrict__ A, const u16* __restrict__ Bt,
    void* __restrict__ Cout, const float* __restrict__ addend,
    int M, int N, int K, long strideA, long strideB, long strideC)
{
    constexpr int BM = 128, BK = 32;
    constexpr int NT = BN / 32;           // n-subtiles per wave (4 or 2)
    const int z  = blockIdx.z;
    const int m0 = blockIdx.y * BM;
    const int n0 = blockIdx.x * BN;
    if (CAUSAL && n0 > m0 + BM - 1) return;
    const int Keff = TRUNCK ? (K < m0 + BM ? K : m0 + BM) : K;

    const u16* Ab = A  + (size_t)z * (size_t)strideA;
    const u16* Bb = Bt + (size_t)z * (size_t)strideB;

    __shared__ alignas(16) u16 As[BM * BK];
    __shared__ alignas(16) u16 Bs[BN * BK];

    const int tid  = threadIdx.x;
    const int lane = tid & 63, w = tid >> 6;
    const int wr = w >> 1, wc = w & 1;
    const int quad = lane >> 4, l16 = lane & 15;

    f32x4 acc[4][NT] = {};

    constexpr int AITER = (BM * BK / 8) / 256;   // 2
    constexpr int BITER = (BN * BK / 8) / 256;   // 2 or 1

    for (int k0 = 0; k0 < Keff; k0 += BK) {
        #pragma unroll
        for (int it = 0; it < AITER; ++it) {
            int c = tid + it * 256;
            int m = c >> 2, kc = c & 3;
            uint4 v = *(const uint4*)(Ab + (size_t)(m0 + m) * K + k0 + kc * 8);
            *(uint4*)&As[m * BK + kc * 8] = v;
        }
        #pragma unroll
        for (int it = 0; it < BITER; ++it) {
            int c = tid + it * 256;
            int n = c >> 2, kc = c & 3;
            uint4 v = *(const uint4*)(Bb + (size_t)(n0 + n) * K + k0 + kc * 8);
            *(uint4*)&Bs[n * BK + kc * 8] = v;
        }
        __syncthreads();

        bf16x8 af[4], bfr[NT];
        #pragma unroll
        for (int mt = 0; mt < 4; ++mt)
            af[mt] = *(const bf16x8*)&As[(wr * 64 + mt * 16 + l16) * BK + quad * 8];
        #pragma unroll
        for (int nt = 0; nt < NT; ++nt)
            bfr[nt] = *(const bf16x8*)&Bs[(wc * (BN / 2) + nt * 16 + l16) * BK + quad * 8];

        #pragma unroll
        for (int mt = 0; mt < 4; ++mt)
            #pragma unroll
            for (int nt = 0; nt < NT; ++nt)
                acc[mt][nt] = __builtin_amdgcn_mfma_f32_16x16x32_bf16(
                    af[mt], bfr[nt], acc[mt][nt], 0, 0, 0);
        __syncthreads();
    }

    // Epilogue. C/D layout: col = lane&15, row = (lane>>4)*4 + reg  [m89-verified]
    #pragma unroll
    for (int mt = 0; mt < 4; ++mt) {
        #pragma unroll
        for (int nt = 0; nt < NT; ++nt) {
            #pragma unroll
            for (int r = 0; r < 4; ++r) {
                int row = m0 + wr * 64 + mt * 16 + quad * 4 + r;
                int col = n0 + wc * (BN / 2) + nt * 16 + l16;
                float val = acc[mt][nt][r];
                if (MODE == 0) {
                    if (addend) val += addend[(size_t)row * N + col];
                    ((float*)Cout)[(size_t)z * (size_t)strideC + (size_t)row * N + col] = val;
                } else if (MODE == 1) {
                    ((u16*)Cout)[(size_t)z * (size_t)strideC + (size_t)row * N + col] = f2b(val);
                } else {
                    size_t idx = ((size_t)(z >> 4) * T_ + row) * (size_t)D_ + (z & 15) * HD_ + col;
                    ((u16*)Cout)[idx] = f2b(val);
                }
            }
        }
    }
}

// ---------------------------------------------------------------------------
// rmsnorm: rows of 1024 fp32 -> bf16   (out = x * rsqrt(mean(x^2)+eps) * w)
// ---------------------------------------------------------------------------
__global__ __launch_bounds__(256) void rmsnorm_k(
    const float* __restrict__ x, const float* __restrict__ w, u16* __restrict__ out)
{
    const int row = blockIdx.x, tid = threadIdx.x;
    float4 v = ((const float4*)(x + (size_t)row * D_))[tid];
    float ss = v.x * v.x + v.y * v.y + v.z * v.z + v.w * v.w;
    #pragma unroll
    for (int o = 32; o >= 1; o >>= 1) ss += __shfl_xor(ss, o, 64);
    __shared__ float red[4];
    if ((tid & 63) == 0) red[tid >> 6] = ss;
    __syncthreads();
    ss = red[0] + red[1] + red[2] + red[3];
    float scale = rsqrtf(ss * (1.0f / D_) + 1e-5f);
    float4 wv = ((const float4*)w)[tid];
    ushort4 o4;
    o4.x = f2b(v.x * scale * wv.x);
    o4.y = f2b(v.y * scale * wv.y);
    o4.z = f2b(v.z * scale * wv.z);
    o4.w = f2b(v.w * scale * wv.w);
    ((ushort4*)(out + (size_t)row * D_))[tid] = o4;
}

// ---------------------------------------------------------------------------
// Weight convert+transpose: in fp32 [R,C] -> out bf16 [C,R]   (block 32x8)
// ---------------------------------------------------------------------------
__global__ void convT_k(const float* __restrict__ in, u16* __restrict__ out, int R, int C)
{
    __shared__ float tile[32][33];
    const int c0 = blockIdx.x * 32, r0 = blockIdx.y * 32;
    const int tx = threadIdx.x, ty = threadIdx.y;
    #pragma unroll
    for (int k = 0; k < 4; ++k)
        tile[ty + 8 * k][tx] = in[(size_t)(r0 + ty + 8 * k) * C + c0 + tx];
    __syncthreads();
    #pragma unroll
    for (int k = 0; k < 4; ++k)
        out[(size_t)(c0 + ty + 8 * k) * R + r0 + tx] = f2b(tile[tx][ty + 8 * k]);
}

// Batched bf16 transpose: per z, in [R,C] -> out [C,R]   (block 32x8)
__global__ void transpose_bf16_k(const u16* __restrict__ in_, u16* __restrict__ out_, int R, int C)
{
    __shared__ u16 tile[32][33];
    const u16* in = in_ + (size_t)blockIdx.z * R * C;
    u16* out      = out_ + (size_t)blockIdx.z * R * C;
    const int c0 = blockIdx.x * 32, r0 = blockIdx.y * 32;
    const int tx = threadIdx.x, ty = threadIdx.y;
    #pragma unroll
    for (int k = 0; k < 4; ++k)
        tile[ty + 8 * k][tx] = in[(size_t)(r0 + ty + 8 * k) * C + c0 + tx];
    __syncthreads();
    #pragma unroll
    for (int k = 0; k < 4; ++k)
        out[(size_t)(c0 + ty + 8 * k) * R + r0 + tx] = tile[tx][ty + 8 * k];
}

// ---------------------------------------------------------------------------
// RoPE + layout: qkv fp32 (b*T+t, 3072) -> Q,K,V bf16 in (b,h,t,d)
// ---------------------------------------------------------------------------
__global__ __launch_bounds__(256) void rope_k(
    const float* __restrict__ qkv, u16* __restrict__ Qb, u16* __restrict__ Kb, u16* __restrict__ Vb)
{
    const int bt = blockIdx.x;
    const int b = bt >> 10, t = bt & (T_ - 1);
    const float* row = qkv + (size_t)bt * 3072;
    const int tid = threadIdx.x;
    #pragma unroll
    for (int it = 0; it < 2; ++it) {
        int p = tid + it * 256;              // 512 (h, pair) slots
        int h = p >> 5, i = p & 31;
        // inv_freq = 10000^(-2i/64) = 2^(-i * log2(10000)/32)
        float ang = (float)t * exp2f(-(float)i * 0.41524101186092034f);
        float sn, cs;
        sincosf(ang, &sn, &cs);
        float q1 = row[h * 64 + i], q2 = row[h * 64 + i + 32];
        float k1 = row[1024 + h * 64 + i], k2 = row[1024 + h * 64 + i + 32];
        size_t ob = ((size_t)(b * NH_ + h) * T_ + t) * HD_ + i;
        Qb[ob]      = f2b(q1 * cs - q2 * sn);
        Qb[ob + 32] = f2b(q2 * cs + q1 * sn);
        Kb[ob]      = f2b(k1 * cs - k2 * sn);
        Kb[ob + 32] = f2b(k2 * cs + k1 * sn);
    }
    #pragma unroll
    for (int it = 0; it < 4; ++it) {
        int d = tid + it * 256;
        int h = d >> 6, i = d & 63;
        Vb[((size_t)(b * NH_ + h) * T_ + t) * HD_ + i] = f2b(row[2048 + d]);
    }
}

// ---------------------------------------------------------------------------
// Causal softmax over S rows (in-place bf16, scale 1/8, zero masked tail)
// ---------------------------------------------------------------------------
__global__ __launch_bounds__(256) void softmax_causal_k(u16* __restrict__ S)
{
    const int z = blockIdx.x;                 // (b*NH+h)*T + t
    const int t = z & (T_ - 1);
    u16* row = S + (size_t)z * T_;
    const int tid = threadIdx.x;
    const int n = t + 1;
    __shared__ float red[8];
    float vals[4];
    float mx = -1e30f;
    #pragma unroll
    for (int it = 0; it < 4; ++it) {
        int k = tid + it * 256;
        float v = (k < n) ? b2f(row[k]) * 0.125f : -1e30f;
        vals[it] = v;
        mx = fmaxf(mx, v);
    }
    #pragma unroll
    for (int o = 32; o >= 1; o >>= 1) mx = fmaxf(mx, __shfl_xor(mx, o, 64));
    if ((tid & 63) == 0) red[tid >> 6] = mx;
    __syncthreads();
    mx = fmaxf(fmaxf(red[0], red[1]), fmaxf(red[2], red[3]));
    float sum = 0.f;
    #pragma unroll
    for (int it = 0; it < 4; ++it) {
        int k = tid + it * 256;
        float e = (k < n) ? __expf(vals[it] - mx) : 0.f;
        vals[it] = e;
        sum += e;
    }
    #pragma unroll
    for (int o = 32; o >= 1; o >>= 1) sum += __shfl_xor(sum, o, 64);
    if ((tid & 63) == 0) red[4 + (tid >> 6)] = sum;
    __syncthreads();
    sum = red[4] + red[5] + red[6] + red[7];
    float inv = 1.0f / sum;
    #pragma unroll
    for (int it = 0; it < 4; ++it) {
        int k = tid + it * 256;
        row[k] = f2b(vals[it] * inv);         // masked lanes write 0
    }
}

// ---------------------------------------------------------------------------
// Gate softmax: 2M rows of 17 bf16, in place. 1 thread / row.
// ---------------------------------------------------------------------------
__global__ __launch_bounds__(256) void gate_softmax_k(u16* __restrict__ gates)
{
    size_t r = (size_t)blockIdx.x * 256 + threadIdx.x;
    u16* g = gates + r * 17;
    float v[17];
    float mx = -1e30f;
    #pragma unroll
    for (int j = 0; j < 17; ++j) { v[j] = b2f(g[j]); mx = fmaxf(mx, v[j]); }
    float sum = 0.f;
    #pragma unroll
    for (int j = 0; j < 17; ++j) { v[j] = __expf(v[j] - mx); sum += v[j]; }
    float inv = 1.0f / sum;
    #pragma unroll
    for (int j = 0; j < 17; ++j) g[j] = f2b(v[j] * inv);
}

// ---------------------------------------------------------------------------
// Sequential linear recurrence: s_t = A_t s_{t-1} + a0_t * v_t per (b,hh).
// 1 wave per chain; lane (i = l>>2, q = l&3) does a 4-wide partial of row i.
// Gate/v data staged per-64-step chunk into LDS (keeps HBM latency out of
// the serial chain). State lives in registers via shfl reduce + gather.
// ---------------------------------------------------------------------------
#define SCHUNK 64
__global__ __launch_bounds__(64) void scan_k(
    const u16* __restrict__ gates, const float* __restrict__ vv, u16* __restrict__ hout)
{
    const int chain = blockIdx.x;             // b*64 + hh
    const int b = chain >> 6, hh = chain & 63;
    const int lane = threadIdx.x;
    const int i = lane >> 2, q = lane & 3;
    __shared__ alignas(16) u16 glds[SCHUNK][272];   // 16 rows x 17 bf16 per step
    __shared__ float vlds[SCHUNK][16];
    float s0 = 0.f, s1 = 0.f, s2 = 0.f, s3 = 0.f;   // state[4q+0..3]

    for (int t0 = 0; t0 < T_; t0 += SCHUNK) {
        __syncthreads();
        for (int st = 0; st < SCHUNK; ++st) {
            const uint4* src = (const uint4*)(gates + ((size_t)(b * T_ + t0 + st) * H_ + hh) * 272);
            if (lane < 34) ((uint4*)&glds[st][0])[lane] = src[lane];
            if (lane < 16) vlds[st][lane] = vv[(size_t)(b * T_ + t0 + st) * D_ + hh * 16 + lane];
        }
        __syncthreads();
        #pragma unroll 4
        for (int st = 0; st < SCHUNK; ++st) {
            const u16* g = &glds[st][i * 17];
            float a0 = b2f(g[0]);
            float p = b2f(g[1 + 4 * q + 0]) * s0 + b2f(g[1 + 4 * q + 1]) * s1
                    + b2f(g[1 + 4 * q + 2]) * s2 + b2f(g[1 + 4 * q + 3]) * s3;
            p += __shfl_xor(p, 1, 64);
            p += __shfl_xor(p, 2, 64);
            float snew = p + a0 * vlds[st][i];          // s_new[i], all 4 lanes of row i
            if (q == 0)
                hout[(size_t)(b * T_ + t0 + st) * D_ + hh * 16 + i] = f2b(snew);
            s0 = __shfl(snew, (4 * q + 0) * 4, 64);
            s1 = __shfl(snew, (4 * q + 1) * 4, 64);
            s2 = __shfl(snew, (4 * q + 2) * 4, 64);
            s3 = __shfl(snew, (4 * q + 3) * 4, 64);
        }
    }
}

// ---------------------------------------------------------------------------
extern "C" void kernel_launch(void* const* d_in, const int* in_sizes, int n_in,
                              void* d_out, int out_size, void* d_ws, size_t ws_size,
                              hipStream_t stream)
{
    const float* x    = (const float*)d_in[0];
    const float* anw  = (const float*)d_in[1];
    const float* wqkv = (const float*)d_in[2];
    const float* wao  = (const float*)d_in[3];
    const float* lnw  = (const float*)d_in[4];
    const float* wv   = (const float*)d_in[5];
    const float* wa   = (const float*)d_in[6];
    const float* wop  = (const float*)d_in[7];

    char* ws = (char*)d_ws;
    const size_t MB = 1u << 20;
    u16*   h     = (u16*)  (ws +   0 * MB);   //  4 MB  rmsnorm1 out
    u16*   h2    = (u16*)  (ws +   4 * MB);   //  4 MB  rmsnorm2 out
    u16*   wqkvT = (u16*)  (ws +   8 * MB);   //  6 MB
    u16*   waoT  = (u16*)  (ws +  14 * MB);   //  2 MB
    u16*   wvT   = (u16*)  (ws +  16 * MB);   //  2 MB
    u16*   wopT  = (u16*)  (ws +  18 * MB);   //  2 MB
    u16*   waT   = (u16*)  (ws +  20 * MB);   // 34 MB
    float* qkvf  = (float*)(ws +  54 * MB);   // 24 MB  (dead after rope)
    float* x2    = (float*)(ws +  54 * MB);   //  8 MB  aliases qkvf
    float* vvf   = (float*)(ws +  62 * MB);   //  8 MB  aliases qkvf tail
    u16*   Qb    = (u16*)  (ws +  78 * MB);   //  4 MB
    u16*   Kb    = (u16*)  (ws +  82 * MB);   //  4 MB
    u16*   Vb    = (u16*)  (ws +  86 * MB);   //  4 MB
    u16*   Vt    = (u16*)  (ws +  90 * MB);   //  4 MB
    u16*   S     = (u16*)  (ws +  94 * MB);   // 64 MB  (dead after PV)
    u16*   omat  = (u16*)  (ws + 158 * MB);   //  4 MB  (dead after attn_out)
    u16*   gates = (u16*)  (ws +  94 * MB);   // 68 MB  aliases S+omat
    u16*   hout  = (u16*)  (ws + 162 * MB);   //  4 MB  (end: 166 MB)
    (void)in_sizes; (void)n_in; (void)out_size; (void)ws_size;

    dim3 tb(32, 8);
    // weights -> bf16, transposed (N x K)
    convT_k<<<dim3( 96, 32), tb, 0, stream>>>(wqkv, wqkvT, 1024, 3072);
    convT_k<<<dim3( 32, 32), tb, 0, stream>>>(wao,  waoT,  1024, 1024);
    convT_k<<<dim3( 32, 32), tb, 0, stream>>>(wv,   wvT,   1024, 1024);
    convT_k<<<dim3(544, 32), tb, 0, stream>>>(wa,   waT,   1024, 17408);
    convT_k<<<dim3( 32, 32), tb, 0, stream>>>(wop,  wopT,  1024, 1024);

    rmsnorm_k<<<2048, 256, 0, stream>>>(x, anw, h);
    gemm_bt<128, 0, false, false><<<dim3(24, 16, 1), 256, 0, stream>>>(
        h, wqkvT, (void*)qkvf, nullptr, 2048, 3072, 1024, 0, 0, 0);
    rope_k<<<2048, 256, 0, stream>>>(qkvf, Qb, Kb, Vb);
    transpose_bf16_k<<<dim3(2, 32, 32), tb, 0, stream>>>(Vb, Vt, 1024, 64);

    // S = Q K^T  (batched over 32 (b,h); skip blocks fully above diagonal)
    gemm_bt<128, 1, false, true><<<dim3(8, 8, 32), 256, 0, stream>>>(
        Qb, Kb, (void*)S, nullptr, 1024, 1024, 64, 65536, 65536, 1048576);
    softmax_causal_k<<<32768, 256, 0, stream>>>(S);
    // O = P V   (N=64; K truncated at diagonal; scatter into (b,t,h*64+d))
    gemm_bt<64, 2, true, false><<<dim3(1, 8, 32), 256, 0, stream>>>(
        S, Vt, (void*)omat, nullptr, 1024, 64, 1024, 1048576, 65536, 0);

    // x2 = x + O @ w_attn_out
    gemm_bt<128, 0, false, false><<<dim3(8, 16, 1), 256, 0, stream>>>(
        omat, waoT, (void*)x2, x, 2048, 1024, 1024, 0, 0, 0);
    rmsnorm_k<<<2048, 256, 0, stream>>>(x2, lnw, h2);
    gemm_bt<128, 0, false, false><<<dim3(8, 16, 1), 256, 0, stream>>>(
        h2, wvT, (void*)vvf, nullptr, 2048, 1024, 1024, 0, 0, 0);
    gemm_bt<128, 1, false, false><<<dim3(136, 16, 1), 256, 0, stream>>>(
        h2, waT, (void*)gates, nullptr, 2048, 17408, 1024, 0, 0, 0);
    gate_softmax_k<<<8192, 256, 0, stream>>>(gates);
    scan_k<<<128, 64, 0, stream>>>(gates, vvf, hout);
    // out = x2 + h_out @ w_out_proj  (fp32)
    gemm_bt<128, 0, false, false><<<dim3(8, 16, 1), 256, 0, stream>>>(
        hout, wopT, d_out, x2, 2048, 1024, 1024, 0, 0, 0);
}

// Round 2
// 638.697 us; speedup vs baseline: 1.8871x; 1.8871x over previous
//
#include <hip/hip_runtime.h>

// HKSABlock on MI355X (gfx950). Round 2: chunk-parallel scan + global_load_lds staging.
// B=2, T=1024, D=1024, NH=16, HD=64, H=64, M=16.

typedef unsigned short u16;
typedef unsigned int   u32;
typedef __bf16 bf16x8 __attribute__((ext_vector_type(8)));
typedef float  f32x4  __attribute__((ext_vector_type(4)));

#define B_  2
#define T_  1024
#define D_  1024
#define NH_ 16
#define HD_ 64
#define H_  64
#define M_  16

__device__ __forceinline__ float b2f(u16 u) {
    return __uint_as_float(((u32)u) << 16);
}
__device__ __forceinline__ u16 f2b(float f) {
    u32 u = __float_as_uint(f);
    u32 r = (u + 0x7FFFu + ((u >> 16) & 1u)) >> 16;  // RNE
    return (u16)r;
}

// Async global->LDS, 16 B per lane. LDS dest is wave-uniform base + lane*16.
__device__ __forceinline__ void stage16(const void* gp, void* lp) {
    typedef __attribute__((address_space(1))) const unsigned int GU;
    typedef __attribute__((address_space(3))) unsigned int LU;
    __builtin_amdgcn_global_load_lds((GU*)gp, (LU*)lp, 16, 0, 0);
}

// ---------------------------------------------------------------------------
// Generic MFMA GEMM: C[M,N] = A[M,K] * Bt[N,K]^T  (A,Bt bf16 row-major).
// MODE 0: C fp32 (+ optional fp32 addend). MODE 1: C bf16.
// MODE 2: bf16 scatter into o_mat[(b*T + row)*1024 + h*64 + col], z = b*16+h.
// MODE 3: bf16 scatter into gates scan layout [chain][t][272] (col = hh*272+rem).
// MODE 4: fp32 scatter into vvT scan layout [chain][t][16]   (col = hh*16+i).
// CAUSAL: skip blocks with n0 > m0+BM-1. TRUNCK: K truncated to m0+BM.
// ---------------------------------------------------------------------------
template<int BN, int MODE, bool TRUNCK, bool CAUSAL>
__global__ __launch_bounds__(256) void gemm_bt(
    const u16* __restrict__ A, const u16* __restrict__ Bt,
    void* __restrict__ Cout, const float* __restrict__ addend,
    int M, int N, int K, long strideA, long strideB, long strideC)
{
    constexpr int BM = 128, BK = 32;
    constexpr int NT = BN / 32;           // n-subtiles per wave (4 or 2)
    const int z  = blockIdx.z;
    const int m0 = blockIdx.y * BM;
    const int n0 = blockIdx.x * BN;
    if (CAUSAL && n0 > m0 + BM - 1) return;
    const int Keff = TRUNCK ? (K < m0 + BM ? K : m0 + BM) : K;

    const u16* Ab = A  + (size_t)z * (size_t)strideA;
    const u16* Bb = Bt + (size_t)z * (size_t)strideB;

    __shared__ alignas(16) u16 As[BM * BK];
    __shared__ alignas(16) u16 Bs[BN * BK];

    const int tid  = threadIdx.x;
    const int lane = tid & 63, w = tid >> 6;
    const int wb = w << 9;                // wave's LDS u16 offset within a 2048-u16 slab
    const int wr = w >> 1, wc = w & 1;
    const int quad = lane >> 4, l16 = lane & 15;

    f32x4 acc[4][NT] = {};

    constexpr int AITER = (BM * BK / 8) / 256;   // 2
    constexpr int BITER = (BN * BK / 8) / 256;   // 2 or 1

    for (int k0 = 0; k0 < Keff; k0 += BK) {
        #pragma unroll
        for (int it = 0; it < AITER; ++it) {
            int c = tid + it * 256;
            int m = c >> 2, kc = c & 3;
            stage16(Ab + (size_t)(m0 + m) * K + k0 + kc * 8, &As[it * 2048 + wb]);
        }
        #pragma unroll
        for (int it = 0; it < BITER; ++it) {
            int c = tid + it * 256;
            int n = c >> 2, kc = c & 3;
            stage16(Bb + (size_t)(n0 + n) * K + k0 + kc * 8, &Bs[it * 2048 + wb]);
        }
        __syncthreads();

        bf16x8 af[4], bfr[NT];
        #pragma unroll
        for (int mt = 0; mt < 4; ++mt)
            af[mt] = *(const bf16x8*)&As[(wr * 64 + mt * 16 + l16) * BK + quad * 8];
        #pragma unroll
        for (int nt = 0; nt < NT; ++nt)
            bfr[nt] = *(const bf16x8*)&Bs[(wc * (BN / 2) + nt * 16 + l16) * BK + quad * 8];

        #pragma unroll
        for (int mt = 0; mt < 4; ++mt)
            #pragma unroll
            for (int nt = 0; nt < NT; ++nt)
                acc[mt][nt] = __builtin_amdgcn_mfma_f32_16x16x32_bf16(
                    af[mt], bfr[nt], acc[mt][nt], 0, 0, 0);
        __syncthreads();
    }

    // Epilogue. C/D layout: col = lane&15, row = (lane>>4)*4 + reg  [m89-verified]
    #pragma unroll
    for (int mt = 0; mt < 4; ++mt) {
        #pragma unroll
        for (int nt = 0; nt < NT; ++nt) {
            #pragma unroll
            for (int r = 0; r < 4; ++r) {
                int row = m0 + wr * 64 + mt * 16 + quad * 4 + r;
                int col = n0 + wc * (BN / 2) + nt * 16 + l16;
                float val = acc[mt][nt][r];
                if (MODE == 0) {
                    if (addend) val += addend[(size_t)row * N + col];
                    ((float*)Cout)[(size_t)z * (size_t)strideC + (size_t)row * N + col] = val;
                } else if (MODE == 1) {
                    ((u16*)Cout)[(size_t)z * (size_t)strideC + (size_t)row * N + col] = f2b(val);
                } else if (MODE == 2) {
                    size_t idx = ((size_t)(z >> 4) * T_ + row) * (size_t)D_ + (z & 15) * HD_ + col;
                    ((u16*)Cout)[idx] = f2b(val);
                } else if (MODE == 3) {
                    int b = row >> 10, t = row & (T_ - 1);
                    int hh = col / 272, rem = col - hh * 272;
                    ((u16*)Cout)[(((size_t)(b * 64 + hh)) * T_ + t) * 272 + rem] = f2b(val);
                } else {
                    int b = row >> 10, t = row & (T_ - 1);
                    int hh = col >> 4, ii = col & 15;
                    ((float*)Cout)[(((size_t)(b * 64 + hh)) * T_ + t) * 16 + ii] = val;
                }
            }
        }
    }
}

// ---------------------------------------------------------------------------
// rmsnorm: rows of 1024 fp32 -> bf16
// ---------------------------------------------------------------------------
__global__ __launch_bounds__(256) void rmsnorm_k(
    const float* __restrict__ x, const float* __restrict__ w, u16* __restrict__ out)
{
    const int row = blockIdx.x, tid = threadIdx.x;
    float4 v = ((const float4*)(x + (size_t)row * D_))[tid];
    float ss = v.x * v.x + v.y * v.y + v.z * v.z + v.w * v.w;
    #pragma unroll
    for (int o = 32; o >= 1; o >>= 1) ss += __shfl_xor(ss, o, 64);
    __shared__ float red[4];
    if ((tid & 63) == 0) red[tid >> 6] = ss;
    __syncthreads();
    ss = red[0] + red[1] + red[2] + red[3];
    float scale = rsqrtf(ss * (1.0f / D_) + 1e-5f);
    float4 wv = ((const float4*)w)[tid];
    ushort4 o4;
    o4.x = f2b(v.x * scale * wv.x);
    o4.y = f2b(v.y * scale * wv.y);
    o4.z = f2b(v.z * scale * wv.z);
    o4.w = f2b(v.w * scale * wv.w);
    ((ushort4*)(out + (size_t)row * D_))[tid] = o4;
}

// ---------------------------------------------------------------------------
// Weight convert+transpose: fp32 [R,C] -> bf16 [C,R]   (block 32x8)
// ---------------------------------------------------------------------------
__global__ void convT_k(const float* __restrict__ in, u16* __restrict__ out, int R, int C)
{
    __shared__ float tile[32][33];
    const int c0 = blockIdx.x * 32, r0 = blockIdx.y * 32;
    const int tx = threadIdx.x, ty = threadIdx.y;
    #pragma unroll
    for (int k = 0; k < 4; ++k)
        tile[ty + 8 * k][tx] = in[(size_t)(r0 + ty + 8 * k) * C + c0 + tx];
    __syncthreads();
    #pragma unroll
    for (int k = 0; k < 4; ++k)
        out[(size_t)(c0 + ty + 8 * k) * R + r0 + tx] = f2b(tile[tx][ty + 8 * k]);
}

// Batched bf16 transpose: per z, in [R,C] -> out [C,R]   (block 32x8)
__global__ void transpose_bf16_k(const u16* __restrict__ in_, u16* __restrict__ out_, int R, int C)
{
    __shared__ u16 tile[32][33];
    const u16* in = in_ + (size_t)blockIdx.z * R * C;
    u16* out      = out_ + (size_t)blockIdx.z * R * C;
    const int c0 = blockIdx.x * 32, r0 = blockIdx.y * 32;
    const int tx = threadIdx.x, ty = threadIdx.y;
    #pragma unroll
    for (int k = 0; k < 4; ++k)
        tile[ty + 8 * k][tx] = in[(size_t)(r0 + ty + 8 * k) * C + c0 + tx];
    __syncthreads();
    #pragma unroll
    for (int k = 0; k < 4; ++k)
        out[(size_t)(c0 + ty + 8 * k) * R + r0 + tx] = tile[tx][ty + 8 * k];
}

// ---------------------------------------------------------------------------
// RoPE + layout: qkv fp32 (b*T+t, 3072) -> Q,K,V bf16 in (b,h,t,d)
// ---------------------------------------------------------------------------
__global__ __launch_bounds__(256) void rope_k(
    const float* __restrict__ qkv, u16* __restrict__ Qb, u16* __restrict__ Kb, u16* __restrict__ Vb)
{
    const int bt = blockIdx.x;
    const int b = bt >> 10, t = bt & (T_ - 1);
    const float* row = qkv + (size_t)bt * 3072;
    const int tid = threadIdx.x;
    #pragma unroll
    for (int it = 0; it < 2; ++it) {
        int p = tid + it * 256;
        int h = p >> 5, i = p & 31;
        float ang = (float)t * exp2f(-(float)i * 0.41524101186092034f);
        float sn, cs;
        sincosf(ang, &sn, &cs);
        float q1 = row[h * 64 + i], q2 = row[h * 64 + i + 32];
        float k1 = row[1024 + h * 64 + i], k2 = row[1024 + h * 64 + i + 32];
        size_t ob = ((size_t)(b * NH_ + h) * T_ + t) * HD_ + i;
        Qb[ob]      = f2b(q1 * cs - q2 * sn);
        Qb[ob + 32] = f2b(q2 * cs + q1 * sn);
        Kb[ob]      = f2b(k1 * cs - k2 * sn);
        Kb[ob + 32] = f2b(k2 * cs + k1 * sn);
    }
    #pragma unroll
    for (int it = 0; it < 4; ++it) {
        int d = tid + it * 256;
        int h = d >> 6, i = d & 63;
        Vb[((size_t)(b * NH_ + h) * T_ + t) * HD_ + i] = f2b(row[2048 + d]);
    }
}

// ---------------------------------------------------------------------------
// Causal softmax over S rows (in-place bf16, scale 1/8, zero masked tail)
// ---------------------------------------------------------------------------
__global__ __launch_bounds__(256) void softmax_causal_k(u16* __restrict__ S)
{
    const int z = blockIdx.x;
    const int t = z & (T_ - 1);
    u16* row = S + (size_t)z * T_;
    const int tid = threadIdx.x;
    const int n = t + 1;
    __shared__ float red[8];
    float vals[4];
    float mx = -1e30f;
    #pragma unroll
    for (int it = 0; it < 4; ++it) {
        int k = tid + it * 256;
        float v = (k < n) ? b2f(row[k]) * 0.125f : -1e30f;
        vals[it] = v;
        mx = fmaxf(mx, v);
    }
    #pragma unroll
    for (int o = 32; o >= 1; o >>= 1) mx = fmaxf(mx, __shfl_xor(mx, o, 64));
    if ((tid & 63) == 0) red[tid >> 6] = mx;
    __syncthreads();
    mx = fmaxf(fmaxf(red[0], red[1]), fmaxf(red[2], red[3]));
    float sum = 0.f;
    #pragma unroll
    for (int it = 0; it < 4; ++it) {
        int k = tid + it * 256;
        float e = (k < n) ? __expf(vals[it] - mx) : 0.f;
        vals[it] = e;
        sum += e;
    }
    #pragma unroll
    for (int o = 32; o >= 1; o >>= 1) sum += __shfl_xor(sum, o, 64);
    if ((tid & 63) == 0) red[4 + (tid >> 6)] = sum;
    __syncthreads();
    sum = red[4] + red[5] + red[6] + red[7];
    float inv = 1.0f / sum;
    #pragma unroll
    for (int it = 0; it < 4; ++it) {
        int k = tid + it * 256;
        row[k] = f2b(vals[it] * inv);
    }
}

// ---------------------------------------------------------------------------
// Shared helper: softmax over the staged 64-step gate chunk in LDS.
// glds layout: [st][16 rows][17 bf16] == row r = st*16+i at glds + r*17.
// ---------------------------------------------------------------------------
__device__ __forceinline__ void gate_softmax_lds(u16* glds, int lane)
{
    for (int r = lane; r < 1024; r += 64) {
        u16* g = glds + r * 17;
        float v[17];
        float mx = -1e30f;
        #pragma unroll
        for (int j = 0; j < 17; ++j) { v[j] = b2f(g[j]); mx = fmaxf(mx, v[j]); }
        float sum = 0.f;
        #pragma unroll
        for (int j = 0; j < 17; ++j) { v[j] = __expf(v[j] - mx); sum += v[j]; }
        float inv = 1.0f / sum;
        #pragma unroll
        for (int j = 0; j < 17; ++j) g[j] = f2b(v[j] * inv);
    }
}

// ---------------------------------------------------------------------------
// Chunk-parallel linear recurrence, pass 1: per chunk of L=64 steps compute
// transition matrix P_c = A_{t0+63}..A_{t0} (fp32) and offset e_c.
// 1 wave / chunk; lane (i=l>>2, q=l&3) holds P[i][4q..4q+3]; P double-buffered
// in LDS for cross-lane access; e via shuffle matvec.
// ---------------------------------------------------------------------------
__global__ __launch_bounds__(64) void scan_p1(
    const u16* __restrict__ gates, const float* __restrict__ vvT,
    float* __restrict__ Pmat, float* __restrict__ evec)
{
    const int c = blockIdx.x, chain = blockIdx.y;
    const int t0 = c * 64;
    const int lane = threadIdx.x;
    const int i = lane >> 2, q = lane & 3;
    __shared__ alignas(16) u16   glds[64 * 272];   // 34816 B
    __shared__ alignas(16) float vlds[64 * 16];    //  4096 B
    __shared__ alignas(16) float Pb[2][256];       //  2048 B

    const u16*   gbase = gates + ((size_t)chain * T_ + t0) * 272;
    const float* vbase = vvT   + ((size_t)chain * T_ + t0) * 16;
    #pragma unroll
    for (int it = 0; it < 34; ++it)
        stage16(gbase + it * 512 + lane * 8, &glds[it * 512]);
    #pragma unroll
    for (int it = 0; it < 4; ++it)
        stage16(vbase + it * 256 + lane * 4, &vlds[it * 256]);
    __syncthreads();

    gate_softmax_lds(glds, lane);
    #pragma unroll
    for (int jj = 0; jj < 4; ++jj)
        Pb[0][i * 16 + q * 4 + jj] = (i == q * 4 + jj) ? 1.f : 0.f;
    float e4[4] = {0.f, 0.f, 0.f, 0.f};
    float prf[4] = {0.f, 0.f, 0.f, 0.f};
    __syncthreads();

    int cur = 0;
    for (int st = 0; st < 64; ++st) {
        const u16* g = &glds[st * 272 + i * 17];
        float a0 = b2f(g[0]);
        float ar[16];
        #pragma unroll
        for (int k = 0; k < 16; ++k) ar[k] = b2f(g[1 + k]);
        // e <- A e + a0*v
        float pe = ar[q * 4 + 0] * e4[0] + ar[q * 4 + 1] * e4[1]
                 + ar[q * 4 + 2] * e4[2] + ar[q * 4 + 3] * e4[3];
        pe += __shfl_xor(pe, 1, 64);
        pe += __shfl_xor(pe, 2, 64);
        float ne = pe + a0 * vlds[st * 16 + i];
        #pragma unroll
        for (int m = 0; m < 4; ++m) e4[m] = __shfl(ne, (q * 4 + m) * 4, 64);
        // P <- A P  (reads Pb[cur] broadcast, writes Pb[cur^1])
        float np0 = 0.f, np1 = 0.f, np2 = 0.f, np3 = 0.f;
        #pragma unroll
        for (int k = 0; k < 16; ++k) {
            const float4 pk = *(const float4*)&Pb[cur][k * 16 + q * 4];
            np0 += ar[k] * pk.x; np1 += ar[k] * pk.y;
            np2 += ar[k] * pk.z; np3 += ar[k] * pk.w;
        }
        *(float4*)&Pb[cur ^ 1][i * 16 + q * 4] = make_float4(np0, np1, np2, np3);
        prf[0] = np0; prf[1] = np1; prf[2] = np2; prf[3] = np3;
        __syncthreads();
        cur ^= 1;
    }
    float* Pd = Pmat + ((size_t)chain * 16 + c) * 256;
    *(float4*)&Pd[i * 16 + q * 4] = make_float4(prf[0], prf[1], prf[2], prf[3]);
    if (i == 0) {
        float* Ed = evec + ((size_t)chain * 16 + c) * 16;
        #pragma unroll
        for (int m = 0; m < 4; ++m) Ed[q * 4 + m] = e4[m];
    }
}

// ---------------------------------------------------------------------------
// Pass 2: per chain, sequentially combine 16 chunks: sIn[c]=s; s = P_c s + e_c.
// ---------------------------------------------------------------------------
__global__ __launch_bounds__(64) void scan_comb(
    const float* __restrict__ Pmat, const float* __restrict__ evec, float* __restrict__ sIn)
{
    const int chain = blockIdx.x;
    const int lane = threadIdx.x;
    const int i = lane >> 2, q = lane & 3;
    __shared__ alignas(16) float Pl[4096];
    __shared__ alignas(16) float El[256];
    const float* Pg = Pmat + (size_t)chain * 4096;
    const float* Eg = evec + (size_t)chain * 256;
    #pragma unroll
    for (int it = 0; it < 16; ++it)
        stage16(Pg + it * 256 + lane * 4, &Pl[it * 256]);
    stage16(Eg + lane * 4, &El[0]);
    __syncthreads();
    float s4[4] = {0.f, 0.f, 0.f, 0.f};
    for (int cc = 0; cc < 16; ++cc) {
        if (i == 0) {
            #pragma unroll
            for (int m = 0; m < 4; ++m)
                sIn[((size_t)chain * 16 + cc) * 16 + q * 4 + m] = s4[m];
        }
        const float4 pr = *(const float4*)&Pl[cc * 256 + i * 16 + q * 4];
        float ps = pr.x * s4[0] + pr.y * s4[1] + pr.z * s4[2] + pr.w * s4[3];
        ps += __shfl_xor(ps, 1, 64);
        ps += __shfl_xor(ps, 2, 64);
        float ns = ps + El[cc * 16 + i];
        #pragma unroll
        for (int m = 0; m < 4; ++m) s4[m] = __shfl(ns, (q * 4 + m) * 4, 64);
    }
}

// ---------------------------------------------------------------------------
// Pass 3: replay each chunk from its entry state, write h_out.
// ---------------------------------------------------------------------------
__global__ __launch_bounds__(64) void scan_p2(
    const u16* __restrict__ gates, const float* __restrict__ vvT,
    const float* __restrict__ sIn, u16* __restrict__ hout)
{
    const int c = blockIdx.x, chain = blockIdx.y;
    const int b = chain >> 6, hh = chain & 63;
    const int t0 = c * 64;
    const int lane = threadIdx.x;
    const int i = lane >> 2, q = lane & 3;
    __shared__ alignas(16) u16   glds[64 * 272];
    __shared__ alignas(16) float vlds[64 * 16];

    const u16*   gbase = gates + ((size_t)chain * T_ + t0) * 272;
    const float* vbase = vvT   + ((size_t)chain * T_ + t0) * 16;
    #pragma unroll
    for (int it = 0; it < 34; ++it)
        stage16(gbase + it * 512 + lane * 8, &glds[it * 512]);
    #pragma unroll
    for (int it = 0; it < 4; ++it)
        stage16(vbase + it * 256 + lane * 4, &vlds[it * 256]);
    __syncthreads();

    gate_softmax_lds(glds, lane);
    __syncthreads();

    float s4[4];
    #pragma unroll
    for (int m = 0; m < 4; ++m)
        s4[m] = sIn[((size_t)chain * 16 + c) * 16 + q * 4 + m];

    u16* hbase = hout + ((size_t)(b * T_ + t0)) * D_ + hh * 16;
    for (int st = 0; st < 64; ++st) {
        const u16* g = &glds[st * 272 + i * 17];
        float a0 = b2f(g[0]);
        float p = b2f(g[1 + q * 4 + 0]) * s4[0] + b2f(g[1 + q * 4 + 1]) * s4[1]
                + b2f(g[1 + q * 4 + 2]) * s4[2] + b2f(g[1 + q * 4 + 3]) * s4[3];
        p += __shfl_xor(p, 1, 64);
        p += __shfl_xor(p, 2, 64);
        float sn = p + a0 * vlds[st * 16 + i];
        if (q == 0) hbase[(size_t)st * D_ + i] = f2b(sn);
        #pragma unroll
        for (int m = 0; m < 4; ++m) s4[m] = __shfl(sn, (q * 4 + m) * 4, 64);
    }
}

// ---------------------------------------------------------------------------
extern "C" void kernel_launch(void* const* d_in, const int* in_sizes, int n_in,
                              void* d_out, int out_size, void* d_ws, size_t ws_size,
                              hipStream_t stream)
{
    const float* x    = (const float*)d_in[0];
    const float* anw  = (const float*)d_in[1];
    const float* wqkv = (const float*)d_in[2];
    const float* wao  = (const float*)d_in[3];
    const float* lnw  = (const float*)d_in[4];
    const float* wv   = (const float*)d_in[5];
    const float* wa   = (const float*)d_in[6];
    const float* wop  = (const float*)d_in[7];

    char* ws = (char*)d_ws;
    const size_t MB = 1u << 20;
    u16*   h     = (u16*)  (ws +   0 * MB);   //  4 MB  rmsnorm1 out
    u16*   h2    = (u16*)  (ws +   4 * MB);   //  4 MB  rmsnorm2 out
    u16*   wqkvT = (u16*)  (ws +   8 * MB);   //  6 MB
    u16*   waoT  = (u16*)  (ws +  14 * MB);   //  2 MB
    u16*   wvT   = (u16*)  (ws +  16 * MB);   //  2 MB
    u16*   wopT  = (u16*)  (ws +  18 * MB);   //  2 MB
    u16*   waT   = (u16*)  (ws +  20 * MB);   // 34 MB
    float* qkvf  = (float*)(ws +  54 * MB);   // 24 MB  (dead after rope)
    float* x2    = (float*)(ws +  54 * MB);   //  8 MB  aliases qkvf
    float* vvT   = (float*)(ws +  62 * MB);   //  8 MB  scan layout [chain][t][16]
    u16*   Qb    = (u16*)  (ws +  78 * MB);   //  4 MB  (dead after QK^T)
    float* Pmat  = (float*)(ws +  78 * MB);   //  2 MB  aliases Qb (scan phase)
    float* evec  = (float*)(ws +  80 * MB);   // 128 KB
    float* sIn   = (float*)(ws +  80 * MB + 256 * 1024); // 128 KB
    u16*   Kb    = (u16*)  (ws +  82 * MB);   //  4 MB
    u16*   Vb    = (u16*)  (ws +  86 * MB);   //  4 MB
    u16*   Vt    = (u16*)  (ws +  90 * MB);   //  4 MB
    u16*   S     = (u16*)  (ws +  94 * MB);   // 64 MB  (dead after PV)
    u16*   omat  = (u16*)  (ws + 158 * MB);   //  4 MB  (dead after attn_out)
    u16*   gates = (u16*)  (ws +  94 * MB);   // 68 MB  aliases S+omat, scan layout
    u16*   hout  = (u16*)  (ws + 162 * MB);   //  4 MB  (end: 166 MB)
    (void)in_sizes; (void)n_in; (void)out_size; (void)ws_size;

    dim3 tb(32, 8);
    convT_k<<<dim3( 96, 32), tb, 0, stream>>>(wqkv, wqkvT, 1024, 3072);
    convT_k<<<dim3( 32, 32), tb, 0, stream>>>(wao,  waoT,  1024, 1024);
    convT_k<<<dim3( 32, 32), tb, 0, stream>>>(wv,   wvT,   1024, 1024);
    convT_k<<<dim3(544, 32), tb, 0, stream>>>(wa,   waT,   1024, 17408);
    convT_k<<<dim3( 32, 32), tb, 0, stream>>>(wop,  wopT,  1024, 1024);

    rmsnorm_k<<<2048, 256, 0, stream>>>(x, anw, h);
    gemm_bt<128, 0, false, false><<<dim3(24, 16, 1), 256, 0, stream>>>(
        h, wqkvT, (void*)qkvf, nullptr, 2048, 3072, 1024, 0, 0, 0);
    rope_k<<<2048, 256, 0, stream>>>(qkvf, Qb, Kb, Vb);
    transpose_bf16_k<<<dim3(2, 32, 32), tb, 0, stream>>>(Vb, Vt, 1024, 64);

    gemm_bt<128, 1, false, true><<<dim3(8, 8, 32), 256, 0, stream>>>(
        Qb, Kb, (void*)S, nullptr, 1024, 1024, 64, 65536, 65536, 1048576);
    softmax_causal_k<<<32768, 256, 0, stream>>>(S);
    gemm_bt<64, 2, true, false><<<dim3(1, 8, 32), 256, 0, stream>>>(
        S, Vt, (void*)omat, nullptr, 1024, 64, 1024, 1048576, 65536, 0);

    gemm_bt<128, 0, false, false><<<dim3(8, 16, 1), 256, 0, stream>>>(
        omat, waoT, (void*)x2, x, 2048, 1024, 1024, 0, 0, 0);
    rmsnorm_k<<<2048, 256, 0, stream>>>(x2, lnw, h2);
    // vv in scan layout (fp32), gate logits in scan layout (bf16)
    gemm_bt<128, 4, false, false><<<dim3(8, 16, 1), 256, 0, stream>>>(
        h2, wvT, (void*)vvT, nullptr, 2048, 1024, 1024, 0, 0, 0);
    gemm_bt<128, 3, false, false><<<dim3(136, 16, 1), 256, 0, stream>>>(
        h2, waT, (void*)gates, nullptr, 2048, 17408, 1024, 0, 0, 0);

    scan_p1<<<dim3(16, 128), 64, 0, stream>>>(gates, vvT, Pmat, evec);
    scan_comb<<<128, 64, 0, stream>>>(Pmat, evec, sIn);
    scan_p2<<<dim3(16, 128), 64, 0, stream>>>(gates, vvT, sIn, hout);

    gemm_bt<128, 0, false, false><<<dim3(8, 16, 1), 256, 0, stream>>>(
        hout, wopT, d_out, x2, 2048, 1024, 1024, 0, 0, 0);
}

// Round 3
// 567.656 us; speedup vs baseline: 2.1233x; 1.1251x over previous
//
#include <hip/hip_runtime.h>

// HKSABlock on MI355X (gfx950). Round 3: gate_prep + latency-optimized scan.
// B=2, T=1024, D=1024, NH=16, HD=64, H=64, M=16.

typedef unsigned short u16;
typedef unsigned int   u32;
typedef __bf16 bf16x8 __attribute__((ext_vector_type(8)));
typedef float  f32x4  __attribute__((ext_vector_type(4)));

#define B_  2
#define T_  1024
#define D_  1024
#define NH_ 16
#define HD_ 64
#define H_  64
#define M_  16

__device__ __forceinline__ float b2f(u16 u) {
    return __uint_as_float(((u32)u) << 16);
}
__device__ __forceinline__ u16 f2b(float f) {
    u32 u = __float_as_uint(f);
    u32 r = (u + 0x7FFFu + ((u >> 16) & 1u)) >> 16;  // RNE
    return (u16)r;
}
__device__ __forceinline__ float blo(u32 u) { return __uint_as_float(u << 16); }
__device__ __forceinline__ float bhi(u32 u) { return __uint_as_float(u & 0xFFFF0000u); }

// Async global->LDS, 16 B per lane. LDS dest must be wave-uniform base.
__device__ __forceinline__ void stage16(const void* gp, void* lp) {
    typedef __attribute__((address_space(1))) const unsigned int GU;
    typedef __attribute__((address_space(3))) unsigned int LU;
    __builtin_amdgcn_global_load_lds((GU*)gp, (LU*)lp, 16, 0, 0);
}

// ---------------------------------------------------------------------------
// Generic MFMA GEMM: C[M,N] = A[M,K] * Bt[N,K]^T  (A,Bt bf16 row-major).
// MODE 0: C fp32 (+ optional fp32 addend). MODE 1: C bf16.
// MODE 2: bf16 scatter into o_mat[(b*T + row)*1024 + h*64 + col], z = b*16+h.
// MODE 3: bf16 scatter into gates scan layout [chain][t][272] (col = hh*272+rem).
// MODE 4: fp32 scatter into vvT scan layout [chain][t][16]   (col = hh*16+i).
// CAUSAL: skip blocks with n0 > m0+BM-1. TRUNCK: K truncated to m0+BM.
// ---------------------------------------------------------------------------
template<int BN, int MODE, bool TRUNCK, bool CAUSAL>
__global__ __launch_bounds__(256) void gemm_bt(
    const u16* __restrict__ A, const u16* __restrict__ Bt,
    void* __restrict__ Cout, const float* __restrict__ addend,
    int M, int N, int K, long strideA, long strideB, long strideC)
{
    constexpr int BM = 128, BK = 32;
    constexpr int NT = BN / 32;
    const int z  = blockIdx.z;
    const int m0 = blockIdx.y * BM;
    const int n0 = blockIdx.x * BN;
    if (CAUSAL && n0 > m0 + BM - 1) return;
    const int Keff = TRUNCK ? (K < m0 + BM ? K : m0 + BM) : K;

    const u16* Ab = A  + (size_t)z * (size_t)strideA;
    const u16* Bb = Bt + (size_t)z * (size_t)strideB;

    __shared__ alignas(16) u16 As[BM * BK];
    __shared__ alignas(16) u16 Bs[BN * BK];

    const int tid  = threadIdx.x;
    const int lane = tid & 63, w = tid >> 6;
    const int wb = w << 9;
    const int wr = w >> 1, wc = w & 1;
    const int quad = lane >> 4, l16 = lane & 15;

    f32x4 acc[4][NT] = {};

    constexpr int AITER = (BM * BK / 8) / 256;
    constexpr int BITER = (BN * BK / 8) / 256;

    for (int k0 = 0; k0 < Keff; k0 += BK) {
        #pragma unroll
        for (int it = 0; it < AITER; ++it) {
            int c = tid + it * 256;
            int m = c >> 2, kc = c & 3;
            stage16(Ab + (size_t)(m0 + m) * K + k0 + kc * 8, &As[it * 2048 + wb]);
        }
        #pragma unroll
        for (int it = 0; it < BITER; ++it) {
            int c = tid + it * 256;
            int n = c >> 2, kc = c & 3;
            stage16(Bb + (size_t)(n0 + n) * K + k0 + kc * 8, &Bs[it * 2048 + wb]);
        }
        __syncthreads();

        bf16x8 af[4], bfr[NT];
        #pragma unroll
        for (int mt = 0; mt < 4; ++mt)
            af[mt] = *(const bf16x8*)&As[(wr * 64 + mt * 16 + l16) * BK + quad * 8];
        #pragma unroll
        for (int nt = 0; nt < NT; ++nt)
            bfr[nt] = *(const bf16x8*)&Bs[(wc * (BN / 2) + nt * 16 + l16) * BK + quad * 8];

        #pragma unroll
        for (int mt = 0; mt < 4; ++mt)
            #pragma unroll
            for (int nt = 0; nt < NT; ++nt)
                acc[mt][nt] = __builtin_amdgcn_mfma_f32_16x16x32_bf16(
                    af[mt], bfr[nt], acc[mt][nt], 0, 0, 0);
        __syncthreads();
    }

    #pragma unroll
    for (int mt = 0; mt < 4; ++mt) {
        #pragma unroll
        for (int nt = 0; nt < NT; ++nt) {
            #pragma unroll
            for (int r = 0; r < 4; ++r) {
                int row = m0 + wr * 64 + mt * 16 + quad * 4 + r;
                int col = n0 + wc * (BN / 2) + nt * 16 + l16;
                float val = acc[mt][nt][r];
                if (MODE == 0) {
                    if (addend) val += addend[(size_t)row * N + col];
                    ((float*)Cout)[(size_t)z * (size_t)strideC + (size_t)row * N + col] = val;
                } else if (MODE == 1) {
                    ((u16*)Cout)[(size_t)z * (size_t)strideC + (size_t)row * N + col] = f2b(val);
                } else if (MODE == 2) {
                    size_t idx = ((size_t)(z >> 4) * T_ + row) * (size_t)D_ + (z & 15) * HD_ + col;
                    ((u16*)Cout)[idx] = f2b(val);
                } else if (MODE == 3) {
                    int b = row >> 10, t = row & (T_ - 1);
                    int hh = col / 272, rem = col - hh * 272;
                    ((u16*)Cout)[(((size_t)(b * 64 + hh)) * T_ + t) * 272 + rem] = f2b(val);
                } else {
                    int b = row >> 10, t = row & (T_ - 1);
                    int hh = col >> 4, ii = col & 15;
                    ((float*)Cout)[(((size_t)(b * 64 + hh)) * T_ + t) * 16 + ii] = val;
                }
            }
        }
    }
}

// ---------------------------------------------------------------------------
__global__ __launch_bounds__(256) void rmsnorm_k(
    const float* __restrict__ x, const float* __restrict__ w, u16* __restrict__ out)
{
    const int row = blockIdx.x, tid = threadIdx.x;
    float4 v = ((const float4*)(x + (size_t)row * D_))[tid];
    float ss = v.x * v.x + v.y * v.y + v.z * v.z + v.w * v.w;
    #pragma unroll
    for (int o = 32; o >= 1; o >>= 1) ss += __shfl_xor(ss, o, 64);
    __shared__ float red[4];
    if ((tid & 63) == 0) red[tid >> 6] = ss;
    __syncthreads();
    ss = red[0] + red[1] + red[2] + red[3];
    float scale = rsqrtf(ss * (1.0f / D_) + 1e-5f);
    float4 wv = ((const float4*)w)[tid];
    ushort4 o4;
    o4.x = f2b(v.x * scale * wv.x);
    o4.y = f2b(v.y * scale * wv.y);
    o4.z = f2b(v.z * scale * wv.z);
    o4.w = f2b(v.w * scale * wv.w);
    ((ushort4*)(out + (size_t)row * D_))[tid] = o4;
}

// ---------------------------------------------------------------------------
__global__ void convT_k(const float* __restrict__ in, u16* __restrict__ out, int R, int C)
{
    __shared__ float tile[32][33];
    const int c0 = blockIdx.x * 32, r0 = blockIdx.y * 32;
    const int tx = threadIdx.x, ty = threadIdx.y;
    #pragma unroll
    for (int k = 0; k < 4; ++k)
        tile[ty + 8 * k][tx] = in[(size_t)(r0 + ty + 8 * k) * C + c0 + tx];
    __syncthreads();
    #pragma unroll
    for (int k = 0; k < 4; ++k)
        out[(size_t)(c0 + ty + 8 * k) * R + r0 + tx] = f2b(tile[tx][ty + 8 * k]);
}

__global__ void transpose_bf16_k(const u16* __restrict__ in_, u16* __restrict__ out_, int R, int C)
{
    __shared__ u16 tile[32][33];
    const u16* in = in_ + (size_t)blockIdx.z * R * C;
    u16* out      = out_ + (size_t)blockIdx.z * R * C;
    const int c0 = blockIdx.x * 32, r0 = blockIdx.y * 32;
    const int tx = threadIdx.x, ty = threadIdx.y;
    #pragma unroll
    for (int k = 0; k < 4; ++k)
        tile[ty + 8 * k][tx] = in[(size_t)(r0 + ty + 8 * k) * C + c0 + tx];
    __syncthreads();
    #pragma unroll
    for (int k = 0; k < 4; ++k)
        out[(size_t)(c0 + ty + 8 * k) * R + r0 + tx] = tile[tx][ty + 8 * k];
}

// ---------------------------------------------------------------------------
__global__ __launch_bounds__(256) void rope_k(
    const float* __restrict__ qkv, u16* __restrict__ Qb, u16* __restrict__ Kb, u16* __restrict__ Vb)
{
    const int bt = blockIdx.x;
    const int b = bt >> 10, t = bt & (T_ - 1);
    const float* row = qkv + (size_t)bt * 3072;
    const int tid = threadIdx.x;
    #pragma unroll
    for (int it = 0; it < 2; ++it) {
        int p = tid + it * 256;
        int h = p >> 5, i = p & 31;
        float ang = (float)t * exp2f(-(float)i * 0.41524101186092034f);
        float sn, cs;
        sincosf(ang, &sn, &cs);
        float q1 = row[h * 64 + i], q2 = row[h * 64 + i + 32];
        float k1 = row[1024 + h * 64 + i], k2 = row[1024 + h * 64 + i + 32];
        size_t ob = ((size_t)(b * NH_ + h) * T_ + t) * HD_ + i;
        Qb[ob]      = f2b(q1 * cs - q2 * sn);
        Qb[ob + 32] = f2b(q2 * cs + q1 * sn);
        Kb[ob]      = f2b(k1 * cs - k2 * sn);
        Kb[ob + 32] = f2b(k2 * cs + k1 * sn);
    }
    #pragma unroll
    for (int it = 0; it < 4; ++it) {
        int d = tid + it * 256;
        int h = d >> 6, i = d & 63;
        Vb[((size_t)(b * NH_ + h) * T_ + t) * HD_ + i] = f2b(row[2048 + d]);
    }
}

// ---------------------------------------------------------------------------
__global__ __launch_bounds__(256) void softmax_causal_k(u16* __restrict__ S)
{
    const int z = blockIdx.x;
    const int t = z & (T_ - 1);
    u16* row = S + (size_t)z * T_;
    const int tid = threadIdx.x;
    const int n = t + 1;
    __shared__ float red[8];
    float vals[4];
    float mx = -1e30f;
    #pragma unroll
    for (int it = 0; it < 4; ++it) {
        int k = tid + it * 256;
        float v = (k < n) ? b2f(row[k]) * 0.125f : -1e30f;
        vals[it] = v;
        mx = fmaxf(mx, v);
    }
    #pragma unroll
    for (int o = 32; o >= 1; o >>= 1) mx = fmaxf(mx, __shfl_xor(mx, o, 64));
    if ((tid & 63) == 0) red[tid >> 6] = mx;
    __syncthreads();
    mx = fmaxf(fmaxf(red[0], red[1]), fmaxf(red[2], red[3]));
    float sum = 0.f;
    #pragma unroll
    for (int it = 0; it < 4; ++it) {
        int k = tid + it * 256;
        float e = (k < n) ? __expf(vals[it] - mx) : 0.f;
        vals[it] = e;
        sum += e;
    }
    #pragma unroll
    for (int o = 32; o >= 1; o >>= 1) sum += __shfl_xor(sum, o, 64);
    if ((tid & 63) == 0) red[4 + (tid >> 6)] = sum;
    __syncthreads();
    sum = red[4] + red[5] + red[6] + red[7];
    float inv = 1.0f / sum;
    #pragma unroll
    for (int it = 0; it < 4; ++it) {
        int k = tid + it * 256;
        row[k] = f2b(vals[it] * inv);
    }
}

// ---------------------------------------------------------------------------
// gate_prep: softmax over each 17-logit row; write A rows (16 bf16, 32B
// aligned) into the first 512B of each 544B slot (in place), and E = a0*v
// as fp32 [chain][t][16]. One block per (chain, 64-t block).
// ---------------------------------------------------------------------------
__global__ __launch_bounds__(256) void gate_prep_k(
    u16* __restrict__ gates, const float* __restrict__ vvT, float* __restrict__ E)
{
    const int t0 = blockIdx.x * 64, chain = blockIdx.y;
    const int tid = threadIdx.x, lane = tid & 63, w = tid >> 6;
    __shared__ alignas(16) u16   glds[64 * 272];   // 34816 B
    __shared__ alignas(16) float vlds[64 * 16];    //  4096 B

    const char* gbase = (const char*)(gates + ((size_t)chain * T_ + t0) * 272);
    #pragma unroll
    for (int it = 0; it < 9; ++it) {
        int off = it * 4096 + w * 1024;
        if (off < 34816)
            stage16(gbase + off + lane * 16, (char*)glds + off);
    }
    {
        const char* vbase = (const char*)(vvT + ((size_t)chain * T_ + t0) * 16);
        int off = w * 1024;
        stage16(vbase + off + lane * 16, (char*)vlds + off);
    }
    __syncthreads();

    #pragma unroll
    for (int it = 0; it < 4; ++it) {
        int r = it * 256 + tid;
        int s = r >> 4, i = r & 15;
        const u16* g = &glds[s * 272 + i * 17];
        float v[17];
        float mx = -1e30f;
        #pragma unroll
        for (int j = 0; j < 17; ++j) { v[j] = b2f(g[j]); mx = fmaxf(mx, v[j]); }
        float sum = 0.f;
        #pragma unroll
        for (int j = 0; j < 17; ++j) { v[j] = __expf(v[j] - mx); sum += v[j]; }
        float inv = 1.0f / sum;
        uint4 w0, w1;
        w0.x = (u32)f2b(v[1] * inv)  | ((u32)f2b(v[2] * inv)  << 16);
        w0.y = (u32)f2b(v[3] * inv)  | ((u32)f2b(v[4] * inv)  << 16);
        w0.z = (u32)f2b(v[5] * inv)  | ((u32)f2b(v[6] * inv)  << 16);
        w0.w = (u32)f2b(v[7] * inv)  | ((u32)f2b(v[8] * inv)  << 16);
        w1.x = (u32)f2b(v[9] * inv)  | ((u32)f2b(v[10] * inv) << 16);
        w1.y = (u32)f2b(v[11] * inv) | ((u32)f2b(v[12] * inv) << 16);
        w1.z = (u32)f2b(v[13] * inv) | ((u32)f2b(v[14] * inv) << 16);
        w1.w = (u32)f2b(v[15] * inv) | ((u32)f2b(v[16] * inv) << 16);
        char* slot = (char*)(gates + ((size_t)chain * T_ + t0 + s) * 272) + i * 32;
        ((uint4*)slot)[0] = w0;
        ((uint4*)slot)[1] = w1;
        E[((size_t)chain * T_ + t0 + s) * 16 + i] = (v[0] * inv) * vlds[s * 16 + i];
    }
}

// ---------------------------------------------------------------------------
// scan pass 1: per chunk of L=32 steps compute P_c = A_{31}..A_0, e_c.
// 1 wave / chunk. lane (i=l>>2, q=l&3): holds P row i, cols 4q..4q+3.
// Full e vector replicated in every lane's registers (4x f32x4).
// A rows 32B-aligned in LDS -> 2x b128; P reads batched (16x b128) before FMA.
// ---------------------------------------------------------------------------
__global__ __launch_bounds__(64) void scan_p1(
    const u16* __restrict__ gates, const float* __restrict__ E,
    float* __restrict__ Pmat, float* __restrict__ evec)
{
    const int c = blockIdx.x, chain = blockIdx.y;
    const int lane = threadIdx.x;
    const int i = lane >> 2, q = lane & 3;
    __shared__ alignas(16) u16   glds[32 * 272];   // 17408 B
    __shared__ alignas(16) float elds[32 * 16];    //  2048 B
    __shared__ alignas(16) float Pb[2][256];       //  2048 B
    __shared__ alignas(16) float slds[16];

    const char* gbase = (const char*)(gates + ((size_t)chain * T_ + c * 32) * 272);
    #pragma unroll
    for (int it = 0; it < 17; ++it)
        stage16(gbase + it * 1024 + lane * 16, (char*)glds + it * 1024);
    const char* ebase = (const char*)(E + ((size_t)chain * T_ + c * 32) * 16);
    #pragma unroll
    for (int it = 0; it < 2; ++it)
        stage16(ebase + it * 1024 + lane * 16, (char*)elds + it * 1024);
    __syncthreads();

    {
        f32x4 idq;
        #pragma unroll
        for (int m = 0; m < 4; ++m) idq[m] = (i == q * 4 + m) ? 1.f : 0.f;
        *(f32x4*)&Pb[0][i * 16 + q * 4] = idq;
    }
    f32x4 e4[4] = {};
    f32x4 np = {};
    float neLast = 0.f;
    int cur = 0;

    for (int st = 0; st < 32; ++st) {
        const uint4* rp = (const uint4*)((const char*)glds + st * 544 + i * 32);
        uint4 d0 = rp[0], d1 = rp[1];
        float ar[16];
        ar[0]  = blo(d0.x); ar[1]  = bhi(d0.x);
        ar[2]  = blo(d0.y); ar[3]  = bhi(d0.y);
        ar[4]  = blo(d0.z); ar[5]  = bhi(d0.z);
        ar[6]  = blo(d0.w); ar[7]  = bhi(d0.w);
        ar[8]  = blo(d1.x); ar[9]  = bhi(d1.x);
        ar[10] = blo(d1.y); ar[11] = bhi(d1.y);
        ar[12] = blo(d1.z); ar[13] = bhi(d1.z);
        ar[14] = blo(d1.w); ar[15] = bhi(d1.w);

        // batched P reads (independent -> pipelined issue)
        f32x4 pk[16];
        #pragma unroll
        for (int k = 0; k < 16; ++k)
            pk[k] = *(const f32x4*)&Pb[cur][k * 16 + q * 4];

        f32x4 a = pk[0] * ar[0];
        #pragma unroll
        for (int k = 1; k < 16; ++k) a += pk[k] * ar[k];
        np = a;

        float ne0 = ar[0] * e4[0][0] + ar[1] * e4[0][1] + ar[2] * e4[0][2] + ar[3] * e4[0][3];
        float ne1 = ar[4] * e4[1][0] + ar[5] * e4[1][1] + ar[6] * e4[1][2] + ar[7] * e4[1][3];
        float ne2 = ar[8] * e4[2][0] + ar[9] * e4[2][1] + ar[10] * e4[2][2] + ar[11] * e4[2][3];
        float ne3 = ar[12] * e4[3][0] + ar[13] * e4[3][1] + ar[14] * e4[3][2] + ar[15] * e4[3][3];
        float ne = (ne0 + ne1) + (ne2 + ne3) + elds[st * 16 + i];

        *(f32x4*)&Pb[cur ^ 1][i * 16 + q * 4] = np;
        if (q == 0) slds[i] = ne;
        #pragma unroll
        for (int m = 0; m < 4; ++m) e4[m] = *(const f32x4*)&slds[m * 4];
        neLast = ne;
        cur ^= 1;
    }

    float* Pd = Pmat + ((size_t)chain * 32 + c) * 256;
    *(f32x4*)&Pd[i * 16 + q * 4] = np;
    if (q == 0) evec[((size_t)chain * 32 + c) * 16 + i] = neLast;
}

// ---------------------------------------------------------------------------
// scan pass 2: per chain, sequentially combine 32 chunks; sIn[c] = entry state.
// ---------------------------------------------------------------------------
__global__ __launch_bounds__(64) void scan_comb(
    const float* __restrict__ Pmat, const float* __restrict__ evec, float* __restrict__ sIn)
{
    const int chain = blockIdx.x;
    const int lane = threadIdx.x;
    const int i = lane >> 2, q = lane & 3;
    __shared__ alignas(16) float Pl[32 * 256];   // 32768 B
    __shared__ alignas(16) float El[32 * 16];    //  2048 B
    __shared__ alignas(16) float slds[16];

    const char* Pg = (const char*)(Pmat + (size_t)chain * 32 * 256);
    #pragma unroll
    for (int it = 0; it < 32; ++it)
        stage16(Pg + it * 1024 + lane * 16, (char*)Pl + it * 1024);
    const char* Eg = (const char*)(evec + (size_t)chain * 32 * 16);
    #pragma unroll
    for (int it = 0; it < 2; ++it)
        stage16(Eg + it * 1024 + lane * 16, (char*)El + it * 1024);
    __syncthreads();

    f32x4 s4[4] = {};
    if (q == 0) sIn[((size_t)chain * 32 + 0) * 16 + i] = 0.f;
    for (int cc = 0; cc < 32; ++cc) {
        f32x4 pr[4];
        #pragma unroll
        for (int m = 0; m < 4; ++m)
            pr[m] = *(const f32x4*)&Pl[cc * 256 + i * 16 + m * 4];
        float ne = 0.f;
        #pragma unroll
        for (int k = 0; k < 16; ++k) ne += pr[k >> 2][k & 3] * s4[k >> 2][k & 3];
        ne += El[cc * 16 + i];
        if (q == 0) {
            slds[i] = ne;
            if (cc < 31) sIn[((size_t)chain * 32 + cc + 1) * 16 + i] = ne;
        }
        #pragma unroll
        for (int m = 0; m < 4; ++m) s4[m] = *(const f32x4*)&slds[m * 4];
    }
}

// ---------------------------------------------------------------------------
// scan pass 3: replay each chunk from its entry state, write h_out.
// ---------------------------------------------------------------------------
__global__ __launch_bounds__(64) void scan_p2(
    const u16* __restrict__ gates, const float* __restrict__ E,
    const float* __restrict__ sIn, u16* __restrict__ hout)
{
    const int c = blockIdx.x, chain = blockIdx.y;
    const int b = chain >> 6, hh = chain & 63;
    const int lane = threadIdx.x;
    const int i = lane >> 2, q = lane & 3;
    __shared__ alignas(16) u16   glds[32 * 272];
    __shared__ alignas(16) float elds[32 * 16];
    __shared__ alignas(16) float slds[16];

    const char* gbase = (const char*)(gates + ((size_t)chain * T_ + c * 32) * 272);
    #pragma unroll
    for (int it = 0; it < 17; ++it)
        stage16(gbase + it * 1024 + lane * 16, (char*)glds + it * 1024);
    const char* ebase = (const char*)(E + ((size_t)chain * T_ + c * 32) * 16);
    #pragma unroll
    for (int it = 0; it < 2; ++it)
        stage16(ebase + it * 1024 + lane * 16, (char*)elds + it * 1024);
    __syncthreads();

    const float* sp = sIn + ((size_t)chain * 32 + c) * 16;
    f32x4 s4[4];
    #pragma unroll
    for (int m = 0; m < 4; ++m) s4[m] = *(const f32x4*)(sp + m * 4);

    u16* hbase = hout + ((size_t)(b * T_ + c * 32)) * D_ + hh * 16;
    for (int st = 0; st < 32; ++st) {
        const uint4* rp = (const uint4*)((const char*)glds + st * 544 + i * 32);
        uint4 d0 = rp[0], d1 = rp[1];
        float ne0 = blo(d0.x) * s4[0][0] + bhi(d0.x) * s4[0][1]
                  + blo(d0.y) * s4[0][2] + bhi(d0.y) * s4[0][3];
        float ne1 = blo(d0.z) * s4[1][0] + bhi(d0.z) * s4[1][1]
                  + blo(d0.w) * s4[1][2] + bhi(d0.w) * s4[1][3];
        float ne2 = blo(d1.x) * s4[2][0] + bhi(d1.x) * s4[2][1]
                  + blo(d1.y) * s4[2][2] + bhi(d1.y) * s4[2][3];
        float ne3 = blo(d1.z) * s4[3][0] + bhi(d1.z) * s4[3][1]
                  + blo(d1.w) * s4[3][2] + bhi(d1.w) * s4[3][3];
        float ne = (ne0 + ne1) + (ne2 + ne3) + elds[st * 16 + i];
        if (q == 0) {
            slds[i] = ne;
            hbase[(size_t)st * D_ + i] = f2b(ne);
        }
        #pragma unroll
        for (int m = 0; m < 4; ++m) s4[m] = *(const f32x4*)&slds[m * 4];
    }
}

// ---------------------------------------------------------------------------
extern "C" void kernel_launch(void* const* d_in, const int* in_sizes, int n_in,
                              void* d_out, int out_size, void* d_ws, size_t ws_size,
                              hipStream_t stream)
{
    const float* x    = (const float*)d_in[0];
    const float* anw  = (const float*)d_in[1];
    const float* wqkv = (const float*)d_in[2];
    const float* wao  = (const float*)d_in[3];
    const float* lnw  = (const float*)d_in[4];
    const float* wv   = (const float*)d_in[5];
    const float* wa   = (const float*)d_in[6];
    const float* wop  = (const float*)d_in[7];

    char* ws = (char*)d_ws;
    const size_t MB = 1u << 20;
    u16*   h     = (u16*)  (ws +   0 * MB);   //  4 MB
    u16*   h2    = (u16*)  (ws +   4 * MB);   //  4 MB
    u16*   wqkvT = (u16*)  (ws +   8 * MB);   //  6 MB
    u16*   waoT  = (u16*)  (ws +  14 * MB);   //  2 MB
    u16*   wvT   = (u16*)  (ws +  16 * MB);   //  2 MB
    u16*   wopT  = (u16*)  (ws +  18 * MB);   //  2 MB
    u16*   waT   = (u16*)  (ws +  20 * MB);   // 34 MB
    float* qkvf  = (float*)(ws +  54 * MB);   // 24 MB (dead after rope)
    float* x2    = (float*)(ws +  54 * MB);   //  8 MB aliases qkvf
    float* vvT   = (float*)(ws +  62 * MB);   //  8 MB scan layout [chain][t][16]
    u16*   Qb    = (u16*)  (ws +  78 * MB);   //  4 MB (dead after QK^T)
    float* Pmat  = (float*)(ws +  78 * MB);   //  4 MB aliases Qb (scan phase)
    u16*   Kb    = (u16*)  (ws +  82 * MB);   //  4 MB (dead after QK^T)
    float* Ebuf  = (float*)(ws +  86 * MB);   //  8 MB aliases Vb/Vt tail (dead after PV)
    u16*   Vb    = (u16*)  (ws +  86 * MB);   //  4 MB (dead after transpose; E after PV)
    u16*   Vt    = (u16*)  (ws +  90 * MB);   //  4 MB (dead after PV)
    float* evec  = (float*)(ws +  82 * MB);   // 256 KB aliases Kb (scan phase)
    float* sIn   = (float*)(ws +  82 * MB + 256 * 1024);  // 256 KB
    u16*   S     = (u16*)  (ws +  94 * MB);   // 64 MB (dead after PV)
    u16*   omat  = (u16*)  (ws + 158 * MB);   //  4 MB (dead after attn_out)
    u16*   gates = (u16*)  (ws +  94 * MB);   // 68 MB aliases S+omat, scan layout
    u16*   hout  = (u16*)  (ws + 162 * MB);   //  4 MB (end: 166 MB)
    (void)in_sizes; (void)n_in; (void)out_size; (void)ws_size;

    dim3 tb(32, 8);
    convT_k<<<dim3( 96, 32), tb, 0, stream>>>(wqkv, wqkvT, 1024, 3072);
    convT_k<<<dim3( 32, 32), tb, 0, stream>>>(wao,  waoT,  1024, 1024);
    convT_k<<<dim3( 32, 32), tb, 0, stream>>>(wv,   wvT,   1024, 1024);
    convT_k<<<dim3(544, 32), tb, 0, stream>>>(wa,   waT,   1024, 17408);
    convT_k<<<dim3( 32, 32), tb, 0, stream>>>(wop,  wopT,  1024, 1024);

    rmsnorm_k<<<2048, 256, 0, stream>>>(x, anw, h);
    gemm_bt<128, 0, false, false><<<dim3(24, 16, 1), 256, 0, stream>>>(
        h, wqkvT, (void*)qkvf, nullptr, 2048, 3072, 1024, 0, 0, 0);
    rope_k<<<2048, 256, 0, stream>>>(qkvf, Qb, Kb, Vb);
    transpose_bf16_k<<<dim3(2, 32, 32), tb, 0, stream>>>(Vb, Vt, 1024, 64);

    gemm_bt<128, 1, false, true><<<dim3(8, 8, 32), 256, 0, stream>>>(
        Qb, Kb, (void*)S, nullptr, 1024, 1024, 64, 65536, 65536, 1048576);
    softmax_causal_k<<<32768, 256, 0, stream>>>(S);
    gemm_bt<64, 2, true, false><<<dim3(1, 8, 32), 256, 0, stream>>>(
        S, Vt, (void*)omat, nullptr, 1024, 64, 1024, 1048576, 65536, 0);

    gemm_bt<128, 0, false, false><<<dim3(8, 16, 1), 256, 0, stream>>>(
        omat, waoT, (void*)x2, x, 2048, 1024, 1024, 0, 0, 0);
    rmsnorm_k<<<2048, 256, 0, stream>>>(x2, lnw, h2);
    gemm_bt<128, 4, false, false><<<dim3(8, 16, 1), 256, 0, stream>>>(
        h2, wvT, (void*)vvT, nullptr, 2048, 1024, 1024, 0, 0, 0);
    gemm_bt<128, 3, false, false><<<dim3(136, 16, 1), 256, 0, stream>>>(
        h2, waT, (void*)gates, nullptr, 2048, 17408, 1024, 0, 0, 0);

    gate_prep_k<<<dim3(16, 128), 256, 0, stream>>>(gates, vvT, Ebuf);
    scan_p1<<<dim3(32, 128), 64, 0, stream>>>(gates, Ebuf, Pmat, evec);
    scan_comb<<<128, 64, 0, stream>>>(Pmat, evec, sIn);
    scan_p2<<<dim3(32, 128), 64, 0, stream>>>(gates, Ebuf, sIn, hout);

    gemm_bt<128, 0, false, false><<<dim3(8, 16, 1), 256, 0, stream>>>(
        hout, wopT, d_out, x2, 2048, 1024, 1024, 0, 0, 0);
}

// Round 4
// 560.214 us; speedup vs baseline: 2.1515x; 1.0133x over previous
//
#include <hip/hip_runtime.h>

// HKSABlock on MI355X (gfx950). Round 4: fused gate+wv GEMM (BK=64, swapped
// grid), in-scan gate softmax (gate_prep eliminated), bounded causal softmax,
// merged weight-convert. B=2, T=1024, D=1024, NH=16, HD=64, H=64, M=16.

typedef unsigned short u16;
typedef unsigned int   u32;
typedef __bf16 bf16x8 __attribute__((ext_vector_type(8)));
typedef float  f32x4  __attribute__((ext_vector_type(4)));

#define B_  2
#define T_  1024
#define D_  1024
#define NH_ 16
#define HD_ 64
#define H_  64
#define M_  16

__device__ __forceinline__ float b2f(u16 u) {
    return __uint_as_float(((u32)u) << 16);
}
__device__ __forceinline__ u16 f2b(float f) {
    u32 u = __float_as_uint(f);
    u32 r = (u + 0x7FFFu + ((u >> 16) & 1u)) >> 16;  // RNE
    return (u16)r;
}
__device__ __forceinline__ float blo(u32 u) { return __uint_as_float(u << 16); }
__device__ __forceinline__ float bhi(u32 u) { return __uint_as_float(u & 0xFFFF0000u); }

// Async global->LDS, 16 B per lane. LDS dest must be wave-uniform base.
__device__ __forceinline__ void stage16(const void* gp, void* lp) {
    typedef __attribute__((address_space(1))) const unsigned int GU;
    typedef __attribute__((address_space(3))) unsigned int LU;
    __builtin_amdgcn_global_load_lds((GU*)gp, (LU*)lp, 16, 0, 0);
}

// ---------------------------------------------------------------------------
// Generic MFMA GEMM: C[M,N] = A[M,K] * Bt[N,K]^T  (A,Bt bf16 row-major).
// MODE 0: C fp32 (+ optional fp32 addend). MODE 1: C bf16.
// MODE 2: bf16 scatter into o_mat[(b*T + row)*1024 + h*64 + col], z = b*16+h.
// MODE 5: cols <17408 -> gates scan layout [chain][t][272] bf16;
//         cols >=17408 -> vvT scan layout [chain][t][16] fp32 (Cout2).
// CAUSAL: skip blocks with n0 > m0+BM-1. TRUNCK: K truncated to m0+BM.
// SWAP: m-tiles on blockIdx.x (fast) for B-panel L2 reuse.
// ---------------------------------------------------------------------------
template<int BN, int BK, int MODE, bool TRUNCK, bool CAUSAL, bool SWAP>
__global__ __launch_bounds__(256) void gemm_bt(
    const u16* __restrict__ A, const u16* __restrict__ Bt,
    void* __restrict__ Cout, void* __restrict__ Cout2,
    const float* __restrict__ addend,
    int M, int N, int K, long strideA, long strideB, long strideC)
{
    constexpr int BM = 128;
    constexpr int NT = BN / 32;
    constexpr int KCH = BK / 8;                  // 16B slots per row
    const int z  = blockIdx.z;
    const int m0 = (SWAP ? blockIdx.x : blockIdx.y) * BM;
    const int n0 = (SWAP ? blockIdx.y : blockIdx.x) * BN;
    if (CAUSAL && n0 > m0 + BM - 1) return;
    const int Keff = TRUNCK ? (K < m0 + BM ? K : m0 + BM) : K;

    const u16* Ab = A  + (size_t)z * (size_t)strideA;
    const u16* Bb = Bt + (size_t)z * (size_t)strideB;

    __shared__ alignas(16) u16 As[BM * BK];
    __shared__ alignas(16) u16 Bs[BN * BK];

    const int tid  = threadIdx.x;
    const int lane = tid & 63, w = tid >> 6;
    const int wr = w >> 1, wc = w & 1;
    const int quad = lane >> 4, l16 = lane & 15;

    f32x4 acc[4][NT] = {};

    constexpr int AITER = (BM * BK / 8) / 256;
    constexpr int BITER = (BN * BK / 8) / 256;

    for (int k0 = 0; k0 < Keff; k0 += BK) {
        #pragma unroll
        for (int it = 0; it < AITER; ++it) {
            int c = it * 256 + tid;
            int m = c / KCH, kc = c % KCH;
            stage16(Ab + (size_t)(m0 + m) * K + k0 + kc * 8,
                    &As[(it * 256 + w * 64) * 8]);
        }
        #pragma unroll
        for (int it = 0; it < BITER; ++it) {
            int c = it * 256 + tid;
            int n = c / KCH, kc = c % KCH;
            stage16(Bb + (size_t)(n0 + n) * K + k0 + kc * 8,
                    &Bs[(it * 256 + w * 64) * 8]);
        }
        __syncthreads();

        #pragma unroll
        for (int kk = 0; kk < BK; kk += 32) {
            bf16x8 af[4], bfr[NT];
            #pragma unroll
            for (int mt = 0; mt < 4; ++mt)
                af[mt] = *(const bf16x8*)&As[(wr * 64 + mt * 16 + l16) * BK + kk + quad * 8];
            #pragma unroll
            for (int nt = 0; nt < NT; ++nt)
                bfr[nt] = *(const bf16x8*)&Bs[(wc * (BN / 2) + nt * 16 + l16) * BK + kk + quad * 8];
            #pragma unroll
            for (int mt = 0; mt < 4; ++mt)
                #pragma unroll
                for (int nt = 0; nt < NT; ++nt)
                    acc[mt][nt] = __builtin_amdgcn_mfma_f32_16x16x32_bf16(
                        af[mt], bfr[nt], acc[mt][nt], 0, 0, 0);
        }
        __syncthreads();
    }

    // Epilogue. C/D layout: col = lane&15, row = (lane>>4)*4 + reg  [m89]
    #pragma unroll
    for (int mt = 0; mt < 4; ++mt) {
        #pragma unroll
        for (int nt = 0; nt < NT; ++nt) {
            #pragma unroll
            for (int r = 0; r < 4; ++r) {
                int row = m0 + wr * 64 + mt * 16 + quad * 4 + r;
                int col = n0 + wc * (BN / 2) + nt * 16 + l16;
                float val = acc[mt][nt][r];
                if (MODE == 0) {
                    if (addend) val += addend[(size_t)row * N + col];
                    ((float*)Cout)[(size_t)z * (size_t)strideC + (size_t)row * N + col] = val;
                } else if (MODE == 1) {
                    ((u16*)Cout)[(size_t)z * (size_t)strideC + (size_t)row * N + col] = f2b(val);
                } else if (MODE == 2) {
                    size_t idx = ((size_t)(z >> 4) * T_ + row) * (size_t)D_ + (z & 15) * HD_ + col;
                    ((u16*)Cout)[idx] = f2b(val);
                } else {  // MODE 5
                    int b = row >> 10, t = row & (T_ - 1);
                    if (col < 17408) {
                        int hh = col / 272, rem = col - hh * 272;
                        ((u16*)Cout)[(((size_t)(b * 64 + hh)) * T_ + t) * 272 + rem] = f2b(val);
                    } else {
                        int c2 = col - 17408;
                        int hh = c2 >> 4, ii = c2 & 15;
                        ((float*)Cout2)[(((size_t)(b * 64 + hh)) * T_ + t) * 16 + ii] = val;
                    }
                }
            }
        }
    }
}

// ---------------------------------------------------------------------------
__global__ __launch_bounds__(256) void rmsnorm_k(
    const float* __restrict__ x, const float* __restrict__ w, u16* __restrict__ out)
{
    const int row = blockIdx.x, tid = threadIdx.x;
    float4 v = ((const float4*)(x + (size_t)row * D_))[tid];
    float ss = v.x * v.x + v.y * v.y + v.z * v.z + v.w * v.w;
    #pragma unroll
    for (int o = 32; o >= 1; o >>= 1) ss += __shfl_xor(ss, o, 64);
    __shared__ float red[4];
    if ((tid & 63) == 0) red[tid >> 6] = ss;
    __syncthreads();
    ss = red[0] + red[1] + red[2] + red[3];
    float scale = rsqrtf(ss * (1.0f / D_) + 1e-5f);
    float4 wv = ((const float4*)w)[tid];
    ushort4 o4;
    o4.x = f2b(v.x * scale * wv.x);
    o4.y = f2b(v.y * scale * wv.y);
    o4.z = f2b(v.z * scale * wv.z);
    o4.w = f2b(v.w * scale * wv.w);
    ((ushort4*)(out + (size_t)row * D_))[tid] = o4;
}

// ---------------------------------------------------------------------------
// All weight converts in one launch. Segments by blockIdx.x (all R=1024):
//   [0,96)   wqkv C=3072 -> wqkvT
//   [96,128) wao  C=1024 -> waoT
//   [128,160)wv   C=1024 -> waT + 17408*1024 (contiguous with waT!)
//   [160,704)wa   C=17408-> waT
//   [704,736)wop  C=1024 -> wopT
// ---------------------------------------------------------------------------
__global__ void convT_all(
    const float* __restrict__ wqkv, const float* __restrict__ wao,
    const float* __restrict__ wv,   const float* __restrict__ wa,
    const float* __restrict__ wop,
    u16* __restrict__ wqkvT, u16* __restrict__ waoT,
    u16* __restrict__ waT,   u16* __restrict__ wopT)
{
    const int x = blockIdx.x;
    const float* in; u16* out; int C, xb;
    if (x < 96)       { in = wqkv; out = wqkvT; C = 3072;  xb = x; }
    else if (x < 128) { in = wao;  out = waoT;  C = 1024;  xb = x - 96; }
    else if (x < 160) { in = wv;   out = waT + (size_t)17408 * 1024; C = 1024; xb = x - 128; }
    else if (x < 704) { in = wa;   out = waT;   C = 17408; xb = x - 160; }
    else              { in = wop;  out = wopT;  C = 1024;  xb = x - 704; }
    constexpr int R = 1024;
    __shared__ float tile[32][33];
    const int c0 = xb * 32, r0 = blockIdx.y * 32;
    const int tx = threadIdx.x, ty = threadIdx.y;
    #pragma unroll
    for (int k = 0; k < 4; ++k)
        tile[ty + 8 * k][tx] = in[(size_t)(r0 + ty + 8 * k) * C + c0 + tx];
    __syncthreads();
    #pragma unroll
    for (int k = 0; k < 4; ++k)
        out[(size_t)(c0 + ty + 8 * k) * R + r0 + tx] = f2b(tile[tx][ty + 8 * k]);
}

__global__ void transpose_bf16_k(const u16* __restrict__ in_, u16* __restrict__ out_, int R, int C)
{
    __shared__ u16 tile[32][33];
    const u16* in = in_ + (size_t)blockIdx.z * R * C;
    u16* out      = out_ + (size_t)blockIdx.z * R * C;
    const int c0 = blockIdx.x * 32, r0 = blockIdx.y * 32;
    const int tx = threadIdx.x, ty = threadIdx.y;
    #pragma unroll
    for (int k = 0; k < 4; ++k)
        tile[ty + 8 * k][tx] = in[(size_t)(r0 + ty + 8 * k) * C + c0 + tx];
    __syncthreads();
    #pragma unroll
    for (int k = 0; k < 4; ++k)
        out[(size_t)(c0 + ty + 8 * k) * R + r0 + tx] = tile[tx][ty + 8 * k];
}

// ---------------------------------------------------------------------------
__global__ __launch_bounds__(256) void rope_k(
    const float* __restrict__ qkv, u16* __restrict__ Qb, u16* __restrict__ Kb, u16* __restrict__ Vb)
{
    const int bt = blockIdx.x;
    const int b = bt >> 10, t = bt & (T_ - 1);
    const float* row = qkv + (size_t)bt * 3072;
    const int tid = threadIdx.x;
    #pragma unroll
    for (int it = 0; it < 2; ++it) {
        int p = tid + it * 256;
        int h = p >> 5, i = p & 31;
        float ang = (float)t * exp2f(-(float)i * 0.41524101186092034f);
        float sn, cs;
        sincosf(ang, &sn, &cs);
        float q1 = row[h * 64 + i], q2 = row[h * 64 + i + 32];
        float k1 = row[1024 + h * 64 + i], k2 = row[1024 + h * 64 + i + 32];
        size_t ob = ((size_t)(b * NH_ + h) * T_ + t) * HD_ + i;
        Qb[ob]      = f2b(q1 * cs - q2 * sn);
        Qb[ob + 32] = f2b(q2 * cs + q1 * sn);
        Kb[ob]      = f2b(k1 * cs - k2 * sn);
        Kb[ob + 32] = f2b(k2 * cs + k1 * sn);
    }
    #pragma unroll
    for (int it = 0; it < 4; ++it) {
        int d = tid + it * 256;
        int h = d >> 6, i = d & 63;
        Vb[((size_t)(b * NH_ + h) * T_ + t) * HD_ + i] = f2b(row[2048 + d]);
    }
}

// ---------------------------------------------------------------------------
// Causal softmax, bounded: only k < kmax = roundup(t+1,128) is ever read by
// the TRUNCK'd PV GEMM, so process/write exactly that range.
// ---------------------------------------------------------------------------
__global__ __launch_bounds__(256) void softmax_causal_k(u16* __restrict__ S)
{
    const int z = blockIdx.x;
    const int t = z & (T_ - 1);
    u16* row = S + (size_t)z * T_;
    const int tid = threadIdx.x;
    const int n = t + 1;
    const int kmax = (t & ~127) + 128;
    __shared__ float red[8];
    float vals[4];
    float mx = -1e30f;
    #pragma unroll
    for (int it = 0; it < 4; ++it) {
        int k = tid + it * 256;
        float v = (k < n && (it << 8) < kmax) ? b2f(row[k]) * 0.125f : -1e30f;
        vals[it] = v;
        mx = fmaxf(mx, v);
    }
    #pragma unroll
    for (int o = 32; o >= 1; o >>= 1) mx = fmaxf(mx, __shfl_xor(mx, o, 64));
    if ((tid & 63) == 0) red[tid >> 6] = mx;
    __syncthreads();
    mx = fmaxf(fmaxf(red[0], red[1]), fmaxf(red[2], red[3]));
    float sum = 0.f;
    #pragma unroll
    for (int it = 0; it < 4; ++it) {
        int k = tid + it * 256;
        float e = (k < n) ? __expf(vals[it] - mx) : 0.f;
        vals[it] = e;
        sum += e;
    }
    #pragma unroll
    for (int o = 32; o >= 1; o >>= 1) sum += __shfl_xor(sum, o, 64);
    if ((tid & 63) == 0) red[4 + (tid >> 6)] = sum;
    __syncthreads();
    sum = red[4] + red[5] + red[6] + red[7];
    float inv = 1.0f / sum;
    #pragma unroll
    for (int it = 0; it < 4; ++it) {
        int k = tid + it * 256;
        if (k < kmax) row[k] = f2b(vals[it] * inv);
    }
}

// ---------------------------------------------------------------------------
// Scan-chunk prep (shared by p1/p2): raw gate logits for a 32-step chunk are
// in glds (32 x 16 rows x 17 bf16 @ 34 B). Softmax each row, repack the 16
// A-entries in place to (st*16+i)*32 B (bf16), and scale vlds (v -> a0*v).
// Single-wave block: intra-wave data deps order LDS ops; barriers guard the
// in-place overlap between read and write phases.
// ---------------------------------------------------------------------------
__device__ __forceinline__ void scan_prep(u16* glds, float* vlds, int lane)
{
    #pragma unroll
    for (int rnd = 0; rnd < 2; ++rnd) {
        float p[4][17];
        #pragma unroll
        for (int j = 0; j < 4; ++j) {
            int r = rnd * 256 + j * 64 + lane;
            const u16* g = &glds[r * 17];
            float vv[17];
            float mx = -1e30f;
            #pragma unroll
            for (int tt = 0; tt < 17; ++tt) { vv[tt] = b2f(g[tt]); mx = fmaxf(mx, vv[tt]); }
            float s = 0.f;
            #pragma unroll
            for (int tt = 0; tt < 17; ++tt) { vv[tt] = __expf(vv[tt] - mx); s += vv[tt]; }
            float inv = 1.0f / s;
            #pragma unroll
            for (int tt = 0; tt < 17; ++tt) p[j][tt] = vv[tt] * inv;
        }
        __syncthreads();
        #pragma unroll
        for (int j = 0; j < 4; ++j) {
            int r = rnd * 256 + j * 64 + lane;
            uint4 w0, w1;
            w0.x = (u32)f2b(p[j][1])  | ((u32)f2b(p[j][2])  << 16);
            w0.y = (u32)f2b(p[j][3])  | ((u32)f2b(p[j][4])  << 16);
            w0.z = (u32)f2b(p[j][5])  | ((u32)f2b(p[j][6])  << 16);
            w0.w = (u32)f2b(p[j][7])  | ((u32)f2b(p[j][8])  << 16);
            w1.x = (u32)f2b(p[j][9])  | ((u32)f2b(p[j][10]) << 16);
            w1.y = (u32)f2b(p[j][11]) | ((u32)f2b(p[j][12]) << 16);
            w1.z = (u32)f2b(p[j][13]) | ((u32)f2b(p[j][14]) << 16);
            w1.w = (u32)f2b(p[j][15]) | ((u32)f2b(p[j][16]) << 16);
            ((uint4*)glds)[r * 2]     = w0;
            ((uint4*)glds)[r * 2 + 1] = w1;
            vlds[r] *= p[j][0];
        }
        __syncthreads();
    }
}

// ---------------------------------------------------------------------------
// scan pass 1: per chunk of 32 steps compute P_c = A_31..A_0, e_c.
// 1 wave/chunk; lane (i=l>>2, q=l&3) holds P row i cols 4q..4q+3.
// ---------------------------------------------------------------------------
__global__ __launch_bounds__(64) void scan_p1(
    const u16* __restrict__ gates, const float* __restrict__ vvT,
    float* __restrict__ Pmat, float* __restrict__ evec)
{
    const int c = blockIdx.x, chain = blockIdx.y;
    const int lane = threadIdx.x;
    const int i = lane >> 2, q = lane & 3;
    __shared__ alignas(16) u16   glds[32 * 272];   // 17408 B raw -> 16 KB repacked
    __shared__ alignas(16) float vlds[32 * 16];    //  2048 B; becomes E in prep
    __shared__ alignas(16) float Pb[2][256];
    __shared__ float slds[16];

    const char* gbase = (const char*)(gates + ((size_t)chain * T_ + c * 32) * 272);
    #pragma unroll
    for (int it = 0; it < 17; ++it)
        stage16(gbase + it * 1024 + lane * 16, (char*)glds + it * 1024);
    const char* vbase = (const char*)(vvT + ((size_t)chain * T_ + c * 32) * 16);
    #pragma unroll
    for (int it = 0; it < 2; ++it)
        stage16(vbase + it * 1024 + lane * 16, (char*)vlds + it * 1024);
    __syncthreads();

    scan_prep(glds, vlds, lane);

    {
        f32x4 idq;
        #pragma unroll
        for (int m = 0; m < 4; ++m) idq[m] = (i == q * 4 + m) ? 1.f : 0.f;
        *(f32x4*)&Pb[0][i * 16 + q * 4] = idq;
    }
    f32x4 e4[4] = {};
    f32x4 np = {};
    float neLast = 0.f;
    int cur = 0;

    for (int st = 0; st < 32; ++st) {
        const uint4* rp = (const uint4*)((const char*)glds + (st * 16 + i) * 32);
        uint4 d0 = rp[0], d1 = rp[1];
        float ar[16];
        ar[0]  = blo(d0.x); ar[1]  = bhi(d0.x);
        ar[2]  = blo(d0.y); ar[3]  = bhi(d0.y);
        ar[4]  = blo(d0.z); ar[5]  = bhi(d0.z);
        ar[6]  = blo(d0.w); ar[7]  = bhi(d0.w);
        ar[8]  = blo(d1.x); ar[9]  = bhi(d1.x);
        ar[10] = blo(d1.y); ar[11] = bhi(d1.y);
        ar[12] = blo(d1.z); ar[13] = bhi(d1.z);
        ar[14] = blo(d1.w); ar[15] = bhi(d1.w);

        f32x4 pk[16];
        #pragma unroll
        for (int k = 0; k < 16; ++k)
            pk[k] = *(const f32x4*)&Pb[cur][k * 16 + q * 4];

        f32x4 a = pk[0] * ar[0];
        #pragma unroll
        for (int k = 1; k < 16; ++k) a += pk[k] * ar[k];
        np = a;

        float ne0 = ar[0] * e4[0][0] + ar[1] * e4[0][1] + ar[2] * e4[0][2] + ar[3] * e4[0][3];
        float ne1 = ar[4] * e4[1][0] + ar[5] * e4[1][1] + ar[6] * e4[1][2] + ar[7] * e4[1][3];
        float ne2 = ar[8] * e4[2][0] + ar[9] * e4[2][1] + ar[10] * e4[2][2] + ar[11] * e4[2][3];
        float ne3 = ar[12] * e4[3][0] + ar[13] * e4[3][1] + ar[14] * e4[3][2] + ar[15] * e4[3][3];
        float ne = (ne0 + ne1) + (ne2 + ne3) + vlds[st * 16 + i];

        *(f32x4*)&Pb[cur ^ 1][i * 16 + q * 4] = np;
        if (q == 0) slds[i] = ne;
        #pragma unroll
        for (int m = 0; m < 4; ++m) e4[m] = *(const f32x4*)&slds[m * 4];
        neLast = ne;
        cur ^= 1;
    }

    float* Pd = Pmat + ((size_t)chain * 32 + c) * 256;
    *(f32x4*)&Pd[i * 16 + q * 4] = np;
    if (q == 0) evec[((size_t)chain * 32 + c) * 16 + i] = neLast;
}

// ---------------------------------------------------------------------------
// scan pass 2: per chain, sequentially combine 32 chunks; sIn[c] = entry state.
// ---------------------------------------------------------------------------
__global__ __launch_bounds__(64) void scan_comb(
    const float* __restrict__ Pmat, const float* __restrict__ evec, float* __restrict__ sIn)
{
    const int chain = blockIdx.x;
    const int lane = threadIdx.x;
    const int i = lane >> 2, q = lane & 3;
    __shared__ alignas(16) float Pl[32 * 256];
    __shared__ alignas(16) float El[32 * 16];
    __shared__ float slds[16];

    const char* Pg = (const char*)(Pmat + (size_t)chain * 32 * 256);
    #pragma unroll
    for (int it = 0; it < 32; ++it)
        stage16(Pg + it * 1024 + lane * 16, (char*)Pl + it * 1024);
    const char* Eg = (const char*)(evec + (size_t)chain * 32 * 16);
    #pragma unroll
    for (int it = 0; it < 2; ++it)
        stage16(Eg + it * 1024 + lane * 16, (char*)El + it * 1024);
    __syncthreads();

    f32x4 s4[4] = {};
    if (q == 0) sIn[((size_t)chain * 32 + 0) * 16 + i] = 0.f;
    for (int cc = 0; cc < 32; ++cc) {
        f32x4 pr[4];
        #pragma unroll
        for (int m = 0; m < 4; ++m)
            pr[m] = *(const f32x4*)&Pl[cc * 256 + i * 16 + m * 4];
        float ne = 0.f;
        #pragma unroll
        for (int k = 0; k < 16; ++k) ne += pr[k >> 2][k & 3] * s4[k >> 2][k & 3];
        ne += El[cc * 16 + i];
        if (q == 0) {
            slds[i] = ne;
            if (cc < 31) sIn[((size_t)chain * 32 + cc + 1) * 16 + i] = ne;
        }
        #pragma unroll
        for (int m = 0; m < 4; ++m) s4[m] = *(const f32x4*)&slds[m * 4];
    }
}

// ---------------------------------------------------------------------------
// scan pass 3: replay each chunk from its entry state, write h_out.
// ---------------------------------------------------------------------------
__global__ __launch_bounds__(64) void scan_p2(
    const u16* __restrict__ gates, const float* __restrict__ vvT,
    const float* __restrict__ sIn, u16* __restrict__ hout)
{
    const int c = blockIdx.x, chain = blockIdx.y;
    const int b = chain >> 6, hh = chain & 63;
    const int lane = threadIdx.x;
    const int i = lane >> 2, q = lane & 3;
    __shared__ alignas(16) u16   glds[32 * 272];
    __shared__ alignas(16) float vlds[32 * 16];
    __shared__ float slds[16];

    const char* gbase = (const char*)(gates + ((size_t)chain * T_ + c * 32) * 272);
    #pragma unroll
    for (int it = 0; it < 17; ++it)
        stage16(gbase + it * 1024 + lane * 16, (char*)glds + it * 1024);
    const char* vbase = (const char*)(vvT + ((size_t)chain * T_ + c * 32) * 16);
    #pragma unroll
    for (int it = 0; it < 2; ++it)
        stage16(vbase + it * 1024 + lane * 16, (char*)vlds + it * 1024);
    __syncthreads();

    scan_prep(glds, vlds, lane);

    const float* sp = sIn + ((size_t)chain * 32 + c) * 16;
    f32x4 s4[4];
    #pragma unroll
    for (int m = 0; m < 4; ++m) s4[m] = *(const f32x4*)(sp + m * 4);

    u16* hbase = hout + ((size_t)(b * T_ + c * 32)) * D_ + hh * 16;
    for (int st = 0; st < 32; ++st) {
        const uint4* rp = (const uint4*)((const char*)glds + (st * 16 + i) * 32);
        uint4 d0 = rp[0], d1 = rp[1];
        float ne0 = blo(d0.x) * s4[0][0] + bhi(d0.x) * s4[0][1]
                  + blo(d0.y) * s4[0][2] + bhi(d0.y) * s4[0][3];
        float ne1 = blo(d0.z) * s4[1][0] + bhi(d0.z) * s4[1][1]
                  + blo(d0.w) * s4[1][2] + bhi(d0.w) * s4[1][3];
        float ne2 = blo(d1.x) * s4[2][0] + bhi(d1.x) * s4[2][1]
                  + blo(d1.y) * s4[2][2] + bhi(d1.y) * s4[2][3];
        float ne3 = blo(d1.z) * s4[3][0] + bhi(d1.z) * s4[3][1]
                  + blo(d1.w) * s4[3][2] + bhi(d1.w) * s4[3][3];
        float ne = (ne0 + ne1) + (ne2 + ne3) + vlds[st * 16 + i];
        if (q == 0) {
            slds[i] = ne;
            hbase[(size_t)st * D_ + i] = f2b(ne);
        }
        #pragma unroll
        for (int m = 0; m < 4; ++m) s4[m] = *(const f32x4*)&slds[m * 4];
    }
}

// ---------------------------------------------------------------------------
extern "C" void kernel_launch(void* const* d_in, const int* in_sizes, int n_in,
                              void* d_out, int out_size, void* d_ws, size_t ws_size,
                              hipStream_t stream)
{
    const float* x    = (const float*)d_in[0];
    const float* anw  = (const float*)d_in[1];
    const float* wqkv = (const float*)d_in[2];
    const float* wao  = (const float*)d_in[3];
    const float* lnw  = (const float*)d_in[4];
    const float* wv   = (const float*)d_in[5];
    const float* wa   = (const float*)d_in[6];
    const float* wop  = (const float*)d_in[7];

    char* ws = (char*)d_ws;
    const size_t MB = 1u << 20;
    u16*   h     = (u16*)  (ws +   0 * MB);   //  4 MB
    u16*   h2    = (u16*)  (ws +   4 * MB);   //  4 MB
    u16*   wqkvT = (u16*)  (ws +   8 * MB);   //  6 MB
    u16*   waoT  = (u16*)  (ws +  14 * MB);   //  2 MB
    u16*   wopT  = (u16*)  (ws +  16 * MB);   //  2 MB
    u16*   waT   = (u16*)  (ws +  18 * MB);   // 36 MB (wa 17408 rows + wv 1024 rows)
    float* qkvf  = (float*)(ws +  54 * MB);   // 24 MB (dead after rope)
    float* x2    = (float*)(ws +  54 * MB);   //  8 MB aliases qkvf head
    float* vvT   = (float*)(ws +  62 * MB);   //  8 MB scan layout [chain][t][16]
    u16*   Qb    = (u16*)  (ws +  78 * MB);   //  4 MB (dead after QK^T)
    float* Pmat  = (float*)(ws +  78 * MB);   //  4 MB aliases Qb
    u16*   Kb    = (u16*)  (ws +  82 * MB);   //  4 MB (dead after QK^T)
    float* evec  = (float*)(ws +  82 * MB);   // 256 KB aliases Kb
    float* sIn   = (float*)(ws +  82 * MB + 256 * 1024); // 256 KB
    u16*   Vb    = (u16*)  (ws +  86 * MB);   //  4 MB (dead after transpose)
    u16*   Vt    = (u16*)  (ws +  90 * MB);   //  4 MB (dead after PV)
    u16*   S     = (u16*)  (ws +  94 * MB);   // 64 MB (dead after PV)
    u16*   omat  = (u16*)  (ws + 158 * MB);   //  4 MB (dead after attn_out)
    u16*   gates = (u16*)  (ws +  94 * MB);   // 68 MB aliases S+omat
    u16*   hout  = (u16*)  (ws + 162 * MB);   //  4 MB (end: 166 MB)
    (void)in_sizes; (void)n_in; (void)out_size; (void)ws_size;

    dim3 tb(32, 8);
    convT_all<<<dim3(736, 32), tb, 0, stream>>>(
        wqkv, wao, wv, wa, wop, wqkvT, waoT, waT, wopT);

    rmsnorm_k<<<2048, 256, 0, stream>>>(x, anw, h);
    gemm_bt<128, 64, 0, false, false, false><<<dim3(24, 16, 1), 256, 0, stream>>>(
        h, wqkvT, (void*)qkvf, nullptr, nullptr, 2048, 3072, 1024, 0, 0, 0);
    rope_k<<<2048, 256, 0, stream>>>(qkvf, Qb, Kb, Vb);
    transpose_bf16_k<<<dim3(2, 32, 32), tb, 0, stream>>>(Vb, Vt, 1024, 64);

    gemm_bt<128, 32, 1, false, true, false><<<dim3(8, 8, 32), 256, 0, stream>>>(
        Qb, Kb, (void*)S, nullptr, nullptr, 1024, 1024, 64, 65536, 65536, 1048576);
    softmax_causal_k<<<32768, 256, 0, stream>>>(S);
    gemm_bt<64, 32, 2, true, false, false><<<dim3(1, 8, 32), 256, 0, stream>>>(
        S, Vt, (void*)omat, nullptr, nullptr, 1024, 64, 1024, 1048576, 65536, 0);

    gemm_bt<128, 32, 0, false, false, false><<<dim3(8, 16, 1), 256, 0, stream>>>(
        omat, waoT, (void*)x2, nullptr, x, 2048, 1024, 1024, 0, 0, 0);
    rmsnorm_k<<<2048, 256, 0, stream>>>(x2, lnw, h2);

    // fused gates + w_v GEMM: N = 17408 + 1024, swapped grid (m fast)
    gemm_bt<128, 64, 5, false, false, true><<<dim3(16, 144, 1), 256, 0, stream>>>(
        h2, waT, (void*)gates, (void*)vvT, nullptr, 2048, 18432, 1024, 0, 0, 0);

    scan_p1<<<dim3(32, 128), 64, 0, stream>>>(gates, vvT, Pmat, evec);
    scan_comb<<<128, 64, 0, stream>>>(Pmat, evec, sIn);
    scan_p2<<<dim3(32, 128), 64, 0, stream>>>(gates, vvT, sIn, hout);

    gemm_bt<128, 32, 0, false, false, false><<<dim3(8, 16, 1), 256, 0, stream>>>(
        hout, wopT, d_out, nullptr, x2, 2048, 1024, 1024, 0, 0, 0);
}

// Round 5
// 548.143 us; speedup vs baseline: 2.1988x; 1.0220x over previous
//
#include <hip/hip_runtime.h>

// HKSABlock on MI355X (gfx950). Round 5: revert gate GEMM to BK=32/non-swap
// (R4's BK=64+SWAP regressed: occupancy 28->19.5%, conflicts 3x, FETCH 2x),
// scalar-division MODE-5 epilogue, BM-templated GEMM (PV at BM=64 for 2x
// occupancy), QK^T at BK=64 (single staging round).
// B=2, T=1024, D=1024, NH=16, HD=64, H=64, M=16.

typedef unsigned short u16;
typedef unsigned int   u32;
typedef __bf16 bf16x8 __attribute__((ext_vector_type(8)));
typedef float  f32x4  __attribute__((ext_vector_type(4)));

#define B_  2
#define T_  1024
#define D_  1024
#define NH_ 16
#define HD_ 64
#define H_  64
#define M_  16

__device__ __forceinline__ float b2f(u16 u) {
    return __uint_as_float(((u32)u) << 16);
}
__device__ __forceinline__ u16 f2b(float f) {
    u32 u = __float_as_uint(f);
    u32 r = (u + 0x7FFFu + ((u >> 16) & 1u)) >> 16;  // RNE
    return (u16)r;
}
__device__ __forceinline__ float blo(u32 u) { return __uint_as_float(u << 16); }
__device__ __forceinline__ float bhi(u32 u) { return __uint_as_float(u & 0xFFFF0000u); }

// Async global->LDS, 16 B per lane. LDS dest must be wave-uniform base.
__device__ __forceinline__ void stage16(const void* gp, void* lp) {
    typedef __attribute__((address_space(1))) const unsigned int GU;
    typedef __attribute__((address_space(3))) unsigned int LU;
    __builtin_amdgcn_global_load_lds((GU*)gp, (LU*)lp, 16, 0, 0);
}

// ---------------------------------------------------------------------------
// Generic MFMA GEMM: C[M,N] = A[M,K] * Bt[N,K]^T  (A,Bt bf16 row-major).
// 4 waves: wr = w>>1 (m-half), wc = w&1 (n-half). MT = BM/32, NT = BN/32.
// MODE 0: C fp32 (+ optional fp32 addend). MODE 1: C bf16.
// MODE 2: bf16 scatter into o_mat[(b*T + row)*1024 + h*64 + col], z = b*16+h.
// MODE 5: col<17408 -> gates scan layout [chain][t][272] bf16 (hh = cg/17
//         computed on SGPRs — cg is lane-uniform); col>=17408 -> vvT scan
//         layout [chain][t][16] fp32 (Cout2).
// CAUSAL: skip blocks with n0 > m0+BM-1. TRUNCK: K truncated to m0+BM.
// ---------------------------------------------------------------------------
template<int BM, int BN, int BK, int MODE, bool TRUNCK, bool CAUSAL>
__global__ __launch_bounds__(256) void gemm_bt(
    const u16* __restrict__ A, const u16* __restrict__ Bt,
    void* __restrict__ Cout, void* __restrict__ Cout2,
    const float* __restrict__ addend,
    int M, int N, int K, long strideA, long strideB, long strideC)
{
    constexpr int MT = BM / 32;
    constexpr int NT = BN / 32;
    constexpr int KCH = BK / 8;                  // 16B slots per row
    const int z  = blockIdx.z;
    const int m0 = blockIdx.y * BM;
    const int n0 = blockIdx.x * BN;
    if (CAUSAL && n0 > m0 + BM - 1) return;
    const int Keff = TRUNCK ? (K < m0 + BM ? K : m0 + BM) : K;

    const u16* Ab = A  + (size_t)z * (size_t)strideA;
    const u16* Bb = Bt + (size_t)z * (size_t)strideB;

    __shared__ alignas(16) u16 As[BM * BK];
    __shared__ alignas(16) u16 Bs[BN * BK];

    const int tid  = threadIdx.x;
    const int lane = tid & 63, w = tid >> 6;
    const int wr = w >> 1, wc = w & 1;
    const int quad = lane >> 4, l16 = lane & 15;

    f32x4 acc[MT][NT] = {};

    constexpr int AITER = (BM * BK / 8) / 256;
    constexpr int BITER = (BN * BK / 8) / 256;

    for (int k0 = 0; k0 < Keff; k0 += BK) {
        #pragma unroll
        for (int it = 0; it < AITER; ++it) {
            int c = it * 256 + tid;
            int m = c / KCH, kc = c % KCH;
            stage16(Ab + (size_t)(m0 + m) * K + k0 + kc * 8,
                    &As[(it * 256 + w * 64) * 8]);
        }
        #pragma unroll
        for (int it = 0; it < BITER; ++it) {
            int c = it * 256 + tid;
            int n = c / KCH, kc = c % KCH;
            stage16(Bb + (size_t)(n0 + n) * K + k0 + kc * 8,
                    &Bs[(it * 256 + w * 64) * 8]);
        }
        __syncthreads();

        #pragma unroll
        for (int kk = 0; kk < BK; kk += 32) {
            bf16x8 af[MT], bfr[NT];
            #pragma unroll
            for (int mt = 0; mt < MT; ++mt)
                af[mt] = *(const bf16x8*)&As[(wr * (BM / 2) + mt * 16 + l16) * BK + kk + quad * 8];
            #pragma unroll
            for (int nt = 0; nt < NT; ++nt)
                bfr[nt] = *(const bf16x8*)&Bs[(wc * (BN / 2) + nt * 16 + l16) * BK + kk + quad * 8];
            #pragma unroll
            for (int mt = 0; mt < MT; ++mt)
                #pragma unroll
                for (int nt = 0; nt < NT; ++nt)
                    acc[mt][nt] = __builtin_amdgcn_mfma_f32_16x16x32_bf16(
                        af[mt], bfr[nt], acc[mt][nt], 0, 0, 0);
        }
        __syncthreads();
    }

    // Epilogue. C/D layout: col = lane&15, row = (lane>>4)*4 + reg  [m89]
    #pragma unroll
    for (int mt = 0; mt < MT; ++mt) {
        #pragma unroll
        for (int nt = 0; nt < NT; ++nt) {
            #pragma unroll
            for (int r = 0; r < 4; ++r) {
                int row = m0 + wr * (BM / 2) + mt * 16 + quad * 4 + r;
                int col = n0 + wc * (BN / 2) + nt * 16 + l16;
                float val = acc[mt][nt][r];
                if (MODE == 0) {
                    if (addend) val += addend[(size_t)row * N + col];
                    ((float*)Cout)[(size_t)z * (size_t)strideC + (size_t)row * N + col] = val;
                } else if (MODE == 1) {
                    ((u16*)Cout)[(size_t)z * (size_t)strideC + (size_t)row * N + col] = f2b(val);
                } else if (MODE == 2) {
                    size_t idx = ((size_t)(z >> 4) * T_ + row) * (size_t)D_ + (z & 15) * HD_ + col;
                    ((u16*)Cout)[idx] = f2b(val);
                } else {  // MODE 5 — cg is lane-uniform: scalar div by 17
                    const int t  = row & (T_ - 1);
                    const int bb = m0 >> 10;
                    const int cg = (n0 >> 4) + wc * (BN / 32) + nt;
                    if (cg >= 1088) {
                        const int hh = cg - 1088;
                        ((float*)Cout2)[(((size_t)(bb * 64 + hh)) * T_ + t) * 16 + l16] = val;
                    } else {
                        const int hh  = cg / 17;
                        const int rem = cg - hh * 17;
                        ((u16*)Cout)[(((size_t)(bb * 64 + hh)) * T_ + t) * 272 + rem * 16 + l16] = f2b(val);
                    }
                }
            }
        }
    }
}

// ---------------------------------------------------------------------------
__global__ __launch_bounds__(256) void rmsnorm_k(
    const float* __restrict__ x, const float* __restrict__ w, u16* __restrict__ out)
{
    const int row = blockIdx.x, tid = threadIdx.x;
    float4 v = ((const float4*)(x + (size_t)row * D_))[tid];
    float ss = v.x * v.x + v.y * v.y + v.z * v.z + v.w * v.w;
    #pragma unroll
    for (int o = 32; o >= 1; o >>= 1) ss += __shfl_xor(ss, o, 64);
    __shared__ float red[4];
    if ((tid & 63) == 0) red[tid >> 6] = ss;
    __syncthreads();
    ss = red[0] + red[1] + red[2] + red[3];
    float scale = rsqrtf(ss * (1.0f / D_) + 1e-5f);
    float4 wv = ((const float4*)w)[tid];
    ushort4 o4;
    o4.x = f2b(v.x * scale * wv.x);
    o4.y = f2b(v.y * scale * wv.y);
    o4.z = f2b(v.z * scale * wv.z);
    o4.w = f2b(v.w * scale * wv.w);
    ((ushort4*)(out + (size_t)row * D_))[tid] = o4;
}

// ---------------------------------------------------------------------------
// All weight converts in one launch. Segments by blockIdx.x (all R=1024):
//   [0,96)   wqkv C=3072 -> wqkvT
//   [96,128) wao  C=1024 -> waoT
//   [128,160)wv   C=1024 -> waT + 17408*1024 (contiguous with waT)
//   [160,704)wa   C=17408-> waT
//   [704,736)wop  C=1024 -> wopT
// ---------------------------------------------------------------------------
__global__ void convT_all(
    const float* __restrict__ wqkv, const float* __restrict__ wao,
    const float* __restrict__ wv,   const float* __restrict__ wa,
    const float* __restrict__ wop,
    u16* __restrict__ wqkvT, u16* __restrict__ waoT,
    u16* __restrict__ waT,   u16* __restrict__ wopT)
{
    const int x = blockIdx.x;
    const float* in; u16* out; int C, xb;
    if (x < 96)       { in = wqkv; out = wqkvT; C = 3072;  xb = x; }
    else if (x < 128) { in = wao;  out = waoT;  C = 1024;  xb = x - 96; }
    else if (x < 160) { in = wv;   out = waT + (size_t)17408 * 1024; C = 1024; xb = x - 128; }
    else if (x < 704) { in = wa;   out = waT;   C = 17408; xb = x - 160; }
    else              { in = wop;  out = wopT;  C = 1024;  xb = x - 704; }
    constexpr int R = 1024;
    __shared__ float tile[32][33];
    const int c0 = xb * 32, r0 = blockIdx.y * 32;
    const int tx = threadIdx.x, ty = threadIdx.y;
    #pragma unroll
    for (int k = 0; k < 4; ++k)
        tile[ty + 8 * k][tx] = in[(size_t)(r0 + ty + 8 * k) * C + c0 + tx];
    __syncthreads();
    #pragma unroll
    for (int k = 0; k < 4; ++k)
        out[(size_t)(c0 + ty + 8 * k) * R + r0 + tx] = f2b(tile[tx][ty + 8 * k]);
}

__global__ void transpose_bf16_k(const u16* __restrict__ in_, u16* __restrict__ out_, int R, int C)
{
    __shared__ u16 tile[32][33];
    const u16* in = in_ + (size_t)blockIdx.z * R * C;
    u16* out      = out_ + (size_t)blockIdx.z * R * C;
    const int c0 = blockIdx.x * 32, r0 = blockIdx.y * 32;
    const int tx = threadIdx.x, ty = threadIdx.y;
    #pragma unroll
    for (int k = 0; k < 4; ++k)
        tile[ty + 8 * k][tx] = in[(size_t)(r0 + ty + 8 * k) * C + c0 + tx];
    __syncthreads();
    #pragma unroll
    for (int k = 0; k < 4; ++k)
        out[(size_t)(c0 + ty + 8 * k) * R + r0 + tx] = tile[tx][ty + 8 * k];
}

// ---------------------------------------------------------------------------
__global__ __launch_bounds__(256) void rope_k(
    const float* __restrict__ qkv, u16* __restrict__ Qb, u16* __restrict__ Kb, u16* __restrict__ Vb)
{
    const int bt = blockIdx.x;
    const int b = bt >> 10, t = bt & (T_ - 1);
    const float* row = qkv + (size_t)bt * 3072;
    const int tid = threadIdx.x;
    #pragma unroll
    for (int it = 0; it < 2; ++it) {
        int p = tid + it * 256;
        int h = p >> 5, i = p & 31;
        float ang = (float)t * exp2f(-(float)i * 0.41524101186092034f);
        float sn, cs;
        sincosf(ang, &sn, &cs);
        float q1 = row[h * 64 + i], q2 = row[h * 64 + i + 32];
        float k1 = row[1024 + h * 64 + i], k2 = row[1024 + h * 64 + i + 32];
        size_t ob = ((size_t)(b * NH_ + h) * T_ + t) * HD_ + i;
        Qb[ob]      = f2b(q1 * cs - q2 * sn);
        Qb[ob + 32] = f2b(q2 * cs + q1 * sn);
        Kb[ob]      = f2b(k1 * cs - k2 * sn);
        Kb[ob + 32] = f2b(k2 * cs + k1 * sn);
    }
    #pragma unroll
    for (int it = 0; it < 4; ++it) {
        int d = tid + it * 256;
        int h = d >> 6, i = d & 63;
        Vb[((size_t)(b * NH_ + h) * T_ + t) * HD_ + i] = f2b(row[2048 + d]);
    }
}

// ---------------------------------------------------------------------------
// Causal softmax, bounded: only k < kmax = roundup(t+1,64) is ever read by
// the TRUNCK'd PV GEMM (BM=64), so process/write exactly that range.
// ---------------------------------------------------------------------------
__global__ __launch_bounds__(256) void softmax_causal_k(u16* __restrict__ S)
{
    const int z = blockIdx.x;
    const int t = z & (T_ - 1);
    u16* row = S + (size_t)z * T_;
    const int tid = threadIdx.x;
    const int n = t + 1;
    const int kmax = (t & ~63) + 64;
    __shared__ float red[8];
    float vals[4];
    float mx = -1e30f;
    #pragma unroll
    for (int it = 0; it < 4; ++it) {
        int k = tid + it * 256;
        float v = (k < n && (it << 8) < kmax) ? b2f(row[k]) * 0.125f : -1e30f;
        vals[it] = v;
        mx = fmaxf(mx, v);
    }
    #pragma unroll
    for (int o = 32; o >= 1; o >>= 1) mx = fmaxf(mx, __shfl_xor(mx, o, 64));
    if ((tid & 63) == 0) red[tid >> 6] = mx;
    __syncthreads();
    mx = fmaxf(fmaxf(red[0], red[1]), fmaxf(red[2], red[3]));
    float sum = 0.f;
    #pragma unroll
    for (int it = 0; it < 4; ++it) {
        int k = tid + it * 256;
        float e = (k < n) ? __expf(vals[it] - mx) : 0.f;
        vals[it] = e;
        sum += e;
    }
    #pragma unroll
    for (int o = 32; o >= 1; o >>= 1) sum += __shfl_xor(sum, o, 64);
    if ((tid & 63) == 0) red[4 + (tid >> 6)] = sum;
    __syncthreads();
    sum = red[4] + red[5] + red[6] + red[7];
    float inv = 1.0f / sum;
    #pragma unroll
    for (int it = 0; it < 4; ++it) {
        int k = tid + it * 256;
        if (k < kmax) row[k] = f2b(vals[it] * inv);
    }
}

// ---------------------------------------------------------------------------
// Scan-chunk prep (shared by p1/p2): raw gate logits for a 32-step chunk in
// glds (32 x 16 rows x 17 bf16 @ 34 B). Softmax each row, repack the 16
// A-entries in place to (st*16+i)*32 B (bf16), scale vlds (v -> a0*v).
// ---------------------------------------------------------------------------
__device__ __forceinline__ void scan_prep(u16* glds, float* vlds, int lane)
{
    #pragma unroll
    for (int rnd = 0; rnd < 2; ++rnd) {
        float p[4][17];
        #pragma unroll
        for (int j = 0; j < 4; ++j) {
            int r = rnd * 256 + j * 64 + lane;
            const u16* g = &glds[r * 17];
            float vv[17];
            float mx = -1e30f;
            #pragma unroll
            for (int tt = 0; tt < 17; ++tt) { vv[tt] = b2f(g[tt]); mx = fmaxf(mx, vv[tt]); }
            float s = 0.f;
            #pragma unroll
            for (int tt = 0; tt < 17; ++tt) { vv[tt] = __expf(vv[tt] - mx); s += vv[tt]; }
            float inv = 1.0f / s;
            #pragma unroll
            for (int tt = 0; tt < 17; ++tt) p[j][tt] = vv[tt] * inv;
        }
        __syncthreads();
        #pragma unroll
        for (int j = 0; j < 4; ++j) {
            int r = rnd * 256 + j * 64 + lane;
            uint4 w0, w1;
            w0.x = (u32)f2b(p[j][1])  | ((u32)f2b(p[j][2])  << 16);
            w0.y = (u32)f2b(p[j][3])  | ((u32)f2b(p[j][4])  << 16);
            w0.z = (u32)f2b(p[j][5])  | ((u32)f2b(p[j][6])  << 16);
            w0.w = (u32)f2b(p[j][7])  | ((u32)f2b(p[j][8])  << 16);
            w1.x = (u32)f2b(p[j][9])  | ((u32)f2b(p[j][10]) << 16);
            w1.y = (u32)f2b(p[j][11]) | ((u32)f2b(p[j][12]) << 16);
            w1.z = (u32)f2b(p[j][13]) | ((u32)f2b(p[j][14]) << 16);
            w1.w = (u32)f2b(p[j][15]) | ((u32)f2b(p[j][16]) << 16);
            ((uint4*)glds)[r * 2]     = w0;
            ((uint4*)glds)[r * 2 + 1] = w1;
            vlds[r] *= p[j][0];
        }
        __syncthreads();
    }
}

// ---------------------------------------------------------------------------
// scan pass 1: per chunk of 32 steps compute P_c = A_31..A_0, e_c.
// ---------------------------------------------------------------------------
__global__ __launch_bounds__(64) void scan_p1(
    const u16* __restrict__ gates, const float* __restrict__ vvT,
    float* __restrict__ Pmat, float* __restrict__ evec)
{
    const int c = blockIdx.x, chain = blockIdx.y;
    const int lane = threadIdx.x;
    const int i = lane >> 2, q = lane & 3;
    __shared__ alignas(16) u16   glds[32 * 272];
    __shared__ alignas(16) float vlds[32 * 16];
    __shared__ alignas(16) float Pb[2][256];
    __shared__ float slds[16];

    const char* gbase = (const char*)(gates + ((size_t)chain * T_ + c * 32) * 272);
    #pragma unroll
    for (int it = 0; it < 17; ++it)
        stage16(gbase + it * 1024 + lane * 16, (char*)glds + it * 1024);
    const char* vbase = (const char*)(vvT + ((size_t)chain * T_ + c * 32) * 16);
    #pragma unroll
    for (int it = 0; it < 2; ++it)
        stage16(vbase + it * 1024 + lane * 16, (char*)vlds + it * 1024);
    __syncthreads();

    scan_prep(glds, vlds, lane);

    {
        f32x4 idq;
        #pragma unroll
        for (int m = 0; m < 4; ++m) idq[m] = (i == q * 4 + m) ? 1.f : 0.f;
        *(f32x4*)&Pb[0][i * 16 + q * 4] = idq;
    }
    f32x4 e4[4] = {};
    f32x4 np = {};
    float neLast = 0.f;
    int cur = 0;

    for (int st = 0; st < 32; ++st) {
        const uint4* rp = (const uint4*)((const char*)glds + (st * 16 + i) * 32);
        uint4 d0 = rp[0], d1 = rp[1];
        float ar[16];
        ar[0]  = blo(d0.x); ar[1]  = bhi(d0.x);
        ar[2]  = blo(d0.y); ar[3]  = bhi(d0.y);
        ar[4]  = blo(d0.z); ar[5]  = bhi(d0.z);
        ar[6]  = blo(d0.w); ar[7]  = bhi(d0.w);
        ar[8]  = blo(d1.x); ar[9]  = bhi(d1.x);
        ar[10] = blo(d1.y); ar[11] = bhi(d1.y);
        ar[12] = blo(d1.z); ar[13] = bhi(d1.z);
        ar[14] = blo(d1.w); ar[15] = bhi(d1.w);

        f32x4 pk[16];
        #pragma unroll
        for (int k = 0; k < 16; ++k)
            pk[k] = *(const f32x4*)&Pb[cur][k * 16 + q * 4];

        f32x4 a = pk[0] * ar[0];
        #pragma unroll
        for (int k = 1; k < 16; ++k) a += pk[k] * ar[k];
        np = a;

        float ne0 = ar[0] * e4[0][0] + ar[1] * e4[0][1] + ar[2] * e4[0][2] + ar[3] * e4[0][3];
        float ne1 = ar[4] * e4[1][0] + ar[5] * e4[1][1] + ar[6] * e4[1][2] + ar[7] * e4[1][3];
        float ne2 = ar[8] * e4[2][0] + ar[9] * e4[2][1] + ar[10] * e4[2][2] + ar[11] * e4[2][3];
        float ne3 = ar[12] * e4[3][0] + ar[13] * e4[3][1] + ar[14] * e4[3][2] + ar[15] * e4[3][3];
        float ne = (ne0 + ne1) + (ne2 + ne3) + vlds[st * 16 + i];

        *(f32x4*)&Pb[cur ^ 1][i * 16 + q * 4] = np;
        if (q == 0) slds[i] = ne;
        #pragma unroll
        for (int m = 0; m < 4; ++m) e4[m] = *(const f32x4*)&slds[m * 4];
        neLast = ne;
        cur ^= 1;
    }

    float* Pd = Pmat + ((size_t)chain * 32 + c) * 256;
    *(f32x4*)&Pd[i * 16 + q * 4] = np;
    if (q == 0) evec[((size_t)chain * 32 + c) * 16 + i] = neLast;
}

// ---------------------------------------------------------------------------
// scan pass 2: per chain, sequentially combine 32 chunks; sIn[c] = entry state.
// ---------------------------------------------------------------------------
__global__ __launch_bounds__(64) void scan_comb(
    const float* __restrict__ Pmat, const float* __restrict__ evec, float* __restrict__ sIn)
{
    const int chain = blockIdx.x;
    const int lane = threadIdx.x;
    const int i = lane >> 2, q = lane & 3;
    __shared__ alignas(16) float Pl[32 * 256];
    __shared__ alignas(16) float El[32 * 16];
    __shared__ float slds[16];

    const char* Pg = (const char*)(Pmat + (size_t)chain * 32 * 256);
    #pragma unroll
    for (int it = 0; it < 32; ++it)
        stage16(Pg + it * 1024 + lane * 16, (char*)Pl + it * 1024);
    const char* Eg = (const char*)(evec + (size_t)chain * 32 * 16);
    #pragma unroll
    for (int it = 0; it < 2; ++it)
        stage16(Eg + it * 1024 + lane * 16, (char*)El + it * 1024);
    __syncthreads();

    f32x4 s4[4] = {};
    if (q == 0) sIn[((size_t)chain * 32 + 0) * 16 + i] = 0.f;
    for (int cc = 0; cc < 32; ++cc) {
        f32x4 pr[4];
        #pragma unroll
        for (int m = 0; m < 4; ++m)
            pr[m] = *(const f32x4*)&Pl[cc * 256 + i * 16 + m * 4];
        float ne = 0.f;
        #pragma unroll
        for (int k = 0; k < 16; ++k) ne += pr[k >> 2][k & 3] * s4[k >> 2][k & 3];
        ne += El[cc * 16 + i];
        if (q == 0) {
            slds[i] = ne;
            if (cc < 31) sIn[((size_t)chain * 32 + cc + 1) * 16 + i] = ne;
        }
        #pragma unroll
        for (int m = 0; m < 4; ++m) s4[m] = *(const f32x4*)&slds[m * 4];
    }
}

// ---------------------------------------------------------------------------
// scan pass 3: replay each chunk from its entry state, write h_out.
// ---------------------------------------------------------------------------
__global__ __launch_bounds__(64) void scan_p2(
    const u16* __restrict__ gates, const float* __restrict__ vvT,
    const float* __restrict__ sIn, u16* __restrict__ hout)
{
    const int c = blockIdx.x, chain = blockIdx.y;
    const int b = chain >> 6, hh = chain & 63;
    const int lane = threadIdx.x;
    const int i = lane >> 2, q = lane & 3;
    __shared__ alignas(16) u16   glds[32 * 272];
    __shared__ alignas(16) float vlds[32 * 16];
    __shared__ float slds[16];

    const char* gbase = (const char*)(gates + ((size_t)chain * T_ + c * 32) * 272);
    #pragma unroll
    for (int it = 0; it < 17; ++it)
        stage16(gbase + it * 1024 + lane * 16, (char*)glds + it * 1024);
    const char* vbase = (const char*)(vvT + ((size_t)chain * T_ + c * 32) * 16);
    #pragma unroll
    for (int it = 0; it < 2; ++it)
        stage16(vbase + it * 1024 + lane * 16, (char*)vlds + it * 1024);
    __syncthreads();

    scan_prep(glds, vlds, lane);

    const float* sp = sIn + ((size_t)chain * 32 + c) * 16;
    f32x4 s4[4];
    #pragma unroll
    for (int m = 0; m < 4; ++m) s4[m] = *(const f32x4*)(sp + m * 4);

    u16* hbase = hout + ((size_t)(b * T_ + c * 32)) * D_ + hh * 16;
    for (int st = 0; st < 32; ++st) {
        const uint4* rp = (const uint4*)((const char*)glds + (st * 16 + i) * 32);
        uint4 d0 = rp[0], d1 = rp[1];
        float ne0 = blo(d0.x) * s4[0][0] + bhi(d0.x) * s4[0][1]
                  + blo(d0.y) * s4[0][2] + bhi(d0.y) * s4[0][3];
        float ne1 = blo(d0.z) * s4[1][0] + bhi(d0.z) * s4[1][1]
                  + blo(d0.w) * s4[1][2] + bhi(d0.w) * s4[1][3];
        float ne2 = blo(d1.x) * s4[2][0] + bhi(d1.x) * s4[2][1]
                  + blo(d1.y) * s4[2][2] + bhi(d1.y) * s4[2][3];
        float ne3 = blo(d1.z) * s4[3][0] + bhi(d1.z) * s4[3][1]
                  + blo(d1.w) * s4[3][2] + bhi(d1.w) * s4[3][3];
        float ne = (ne0 + ne1) + (ne2 + ne3) + vlds[st * 16 + i];
        if (q == 0) {
            slds[i] = ne;
            hbase[(size_t)st * D_ + i] = f2b(ne);
        }
        #pragma unroll
        for (int m = 0; m < 4; ++m) s4[m] = *(const f32x4*)&slds[m * 4];
    }
}

// ---------------------------------------------------------------------------
extern "C" void kernel_launch(void* const* d_in, const int* in_sizes, int n_in,
                              void* d_out, int out_size, void* d_ws, size_t ws_size,
                              hipStream_t stream)
{
    const float* x    = (const float*)d_in[0];
    const float* anw  = (const float*)d_in[1];
    const float* wqkv = (const float*)d_in[2];
    const float* wao  = (const float*)d_in[3];
    const float* lnw  = (const float*)d_in[4];
    const float* wv   = (const float*)d_in[5];
    const float* wa   = (const float*)d_in[6];
    const float* wop  = (const float*)d_in[7];

    char* ws = (char*)d_ws;
    const size_t MB = 1u << 20;
    u16*   h     = (u16*)  (ws +   0 * MB);   //  4 MB
    u16*   h2    = (u16*)  (ws +   4 * MB);   //  4 MB
    u16*   wqkvT = (u16*)  (ws +   8 * MB);   //  6 MB
    u16*   waoT  = (u16*)  (ws +  14 * MB);   //  2 MB
    u16*   wopT  = (u16*)  (ws +  16 * MB);   //  2 MB
    u16*   waT   = (u16*)  (ws +  18 * MB);   // 36 MB (wa 17408 rows + wv 1024 rows)
    float* qkvf  = (float*)(ws +  54 * MB);   // 24 MB (dead after rope)
    float* x2    = (float*)(ws +  54 * MB);   //  8 MB aliases qkvf head
    float* vvT   = (float*)(ws +  62 * MB);   //  8 MB scan layout [chain][t][16]
    u16*   Qb    = (u16*)  (ws +  78 * MB);   //  4 MB (dead after QK^T)
    float* Pmat  = (float*)(ws +  78 * MB);   //  4 MB aliases Qb
    u16*   Kb    = (u16*)  (ws +  82 * MB);   //  4 MB (dead after QK^T)
    float* evec  = (float*)(ws +  82 * MB);   // 256 KB aliases Kb
    float* sIn   = (float*)(ws +  82 * MB + 256 * 1024); // 256 KB
    u16*   Vb    = (u16*)  (ws +  86 * MB);   //  4 MB (dead after transpose)
    u16*   Vt    = (u16*)  (ws +  90 * MB);   //  4 MB (dead after PV)
    u16*   S     = (u16*)  (ws +  94 * MB);   // 64 MB (dead after PV)
    u16*   omat  = (u16*)  (ws + 158 * MB);   //  4 MB (dead after attn_out)
    u16*   gates = (u16*)  (ws +  94 * MB);   // 68 MB aliases S+omat
    u16*   hout  = (u16*)  (ws + 162 * MB);   //  4 MB (end: 166 MB)
    (void)in_sizes; (void)n_in; (void)out_size; (void)ws_size;

    dim3 tb(32, 8);
    convT_all<<<dim3(736, 32), tb, 0, stream>>>(
        wqkv, wao, wv, wa, wop, wqkvT, waoT, waT, wopT);

    rmsnorm_k<<<2048, 256, 0, stream>>>(x, anw, h);
    gemm_bt<128, 128, 32, 0, false, false><<<dim3(24, 16, 1), 256, 0, stream>>>(
        h, wqkvT, (void*)qkvf, nullptr, nullptr, 2048, 3072, 1024, 0, 0, 0);
    rope_k<<<2048, 256, 0, stream>>>(qkvf, Qb, Kb, Vb);
    transpose_bf16_k<<<dim3(2, 32, 32), tb, 0, stream>>>(Vb, Vt, 1024, 64);

    // QK^T: K=64 -> BK=64, single staging round per block
    gemm_bt<128, 128, 64, 1, false, true><<<dim3(8, 8, 32), 256, 0, stream>>>(
        Qb, Kb, (void*)S, nullptr, nullptr, 1024, 1024, 64, 65536, 65536, 1048576);
    softmax_causal_k<<<32768, 256, 0, stream>>>(S);
    // PV: BM=64 -> 512 blocks (2/CU) instead of 256
    gemm_bt<64, 64, 32, 2, true, false><<<dim3(1, 16, 32), 256, 0, stream>>>(
        S, Vt, (void*)omat, nullptr, nullptr, 1024, 64, 1024, 1048576, 65536, 0);

    gemm_bt<128, 128, 32, 0, false, false><<<dim3(8, 16, 1), 256, 0, stream>>>(
        omat, waoT, (void*)x2, nullptr, x, 2048, 1024, 1024, 0, 0, 0);
    rmsnorm_k<<<2048, 256, 0, stream>>>(x2, lnw, h2);

    // fused gates + w_v GEMM: N = 17408 + 1024, BK=32, non-swapped grid
    gemm_bt<128, 128, 32, 5, false, false><<<dim3(144, 16, 1), 256, 0, stream>>>(
        h2, waT, (void*)gates, (void*)vvT, nullptr, 2048, 18432, 1024, 0, 0, 0);

    scan_p1<<<dim3(32, 128), 64, 0, stream>>>(gates, vvT, Pmat, evec);
    scan_comb<<<128, 64, 0, stream>>>(Pmat, evec, sIn);
    scan_p2<<<dim3(32, 128), 64, 0, stream>>>(gates, vvT, sIn, hout);

    gemm_bt<128, 128, 32, 0, false, false><<<dim3(8, 16, 1), 256, 0, stream>>>(
        hout, wopT, d_out, nullptr, x2, 2048, 1024, 1024, 0, 0, 0);
}

// Round 6
// 505.343 us; speedup vs baseline: 2.3851x; 1.0847x over previous
//
#include <hip/hip_runtime.h>

// HKSABlock on MI355X (gfx950). Round 6: small-M GEMMs at BM=64 (2x blocks),
// wave-per-row softmax, PV BK=64, XCD-aware swizzle on the gates GEMM
// (A-panel locality: each XCD owns 2 m-rows x all n-tiles).
// B=2, T=1024, D=1024, NH=16, HD=64, H=64, M=16.

typedef unsigned short u16;
typedef unsigned int   u32;
typedef __bf16 bf16x8 __attribute__((ext_vector_type(8)));
typedef float  f32x4  __attribute__((ext_vector_type(4)));

#define B_  2
#define T_  1024
#define D_  1024
#define NH_ 16
#define HD_ 64
#define H_  64
#define M_  16

__device__ __forceinline__ float b2f(u16 u) {
    return __uint_as_float(((u32)u) << 16);
}
__device__ __forceinline__ u16 f2b(float f) {
    u32 u = __float_as_uint(f);
    u32 r = (u + 0x7FFFu + ((u >> 16) & 1u)) >> 16;  // RNE
    return (u16)r;
}
__device__ __forceinline__ float blo(u32 u) { return __uint_as_float(u << 16); }
__device__ __forceinline__ float bhi(u32 u) { return __uint_as_float(u & 0xFFFF0000u); }

// Async global->LDS, 16 B per lane. LDS dest must be wave-uniform base.
__device__ __forceinline__ void stage16(const void* gp, void* lp) {
    typedef __attribute__((address_space(1))) const unsigned int GU;
    typedef __attribute__((address_space(3))) unsigned int LU;
    __builtin_amdgcn_global_load_lds((GU*)gp, (LU*)lp, 16, 0, 0);
}

// ---------------------------------------------------------------------------
// Generic MFMA GEMM: C[M,N] = A[M,K] * Bt[N,K]^T  (A,Bt bf16 row-major).
// 4 waves: wr = w>>1 (m-half), wc = w&1 (n-half). MT = BM/32, NT = BN/32.
// MODE 0: C fp32 (+ optional fp32 addend). MODE 1: C bf16.
// MODE 2: bf16 scatter into o_mat[(b*T + row)*1024 + h*64 + col], z = b*16+h.
// MODE 5: col<17408 -> gates scan layout [chain][t][272] bf16 (wave-uniform
//         cg -> scalar-ish div); col>=17408 -> vvT [chain][t][16] fp32 (Cout2).
// CAUSAL: skip blocks with n0 > m0+BM-1. TRUNCK: K truncated to m0+BM.
// SWZ: remap (x,y) so blocks sharing an A-panel (same y) land on one XCD
//      (assumes flat-id round-robin over 8 XCDs; worst case neutral).
// ---------------------------------------------------------------------------
template<int BM, int BN, int BK, int MODE, bool TRUNCK, bool CAUSAL, bool SWZ>
__global__ __launch_bounds__(256) void gemm_bt(
    const u16* __restrict__ A, const u16* __restrict__ Bt,
    void* __restrict__ Cout, void* __restrict__ Cout2,
    const float* __restrict__ addend,
    int M, int N, int K, long strideA, long strideB, long strideC)
{
    constexpr int MT = BM / 32;
    constexpr int NT = BN / 32;
    constexpr int KCH = BK / 8;                  // 16B slots per row
    const int z  = blockIdx.z;
    int bx = blockIdx.x, by = blockIdx.y;
    if (SWZ) {
        int f = by * gridDim.x + bx;
        int xcd = f & 7, k = f >> 3;
        bx = k % gridDim.x;
        by = xcd * (gridDim.y >> 3) + k / gridDim.x;
    }
    const int m0 = by * BM;
    const int n0 = bx * BN;
    if (CAUSAL && n0 > m0 + BM - 1) return;
    const int Keff = TRUNCK ? (K < m0 + BM ? K : m0 + BM) : K;

    const u16* Ab = A  + (size_t)z * (size_t)strideA;
    const u16* Bb = Bt + (size_t)z * (size_t)strideB;

    __shared__ alignas(16) u16 As[BM * BK];
    __shared__ alignas(16) u16 Bs[BN * BK];

    const int tid  = threadIdx.x;
    const int lane = tid & 63, w = tid >> 6;
    const int wr = w >> 1, wc = w & 1;
    const int quad = lane >> 4, l16 = lane & 15;

    f32x4 acc[MT][NT] = {};

    constexpr int AITER = (BM * BK / 8) / 256;
    constexpr int BITER = (BN * BK / 8) / 256;

    for (int k0 = 0; k0 < Keff; k0 += BK) {
        #pragma unroll
        for (int it = 0; it < AITER; ++it) {
            int c = it * 256 + tid;
            int m = c / KCH, kc = c % KCH;
            stage16(Ab + (size_t)(m0 + m) * K + k0 + kc * 8,
                    &As[(it * 256 + w * 64) * 8]);
        }
        #pragma unroll
        for (int it = 0; it < BITER; ++it) {
            int c = it * 256 + tid;
            int n = c / KCH, kc = c % KCH;
            stage16(Bb + (size_t)(n0 + n) * K + k0 + kc * 8,
                    &Bs[(it * 256 + w * 64) * 8]);
        }
        __syncthreads();

        #pragma unroll
        for (int kk = 0; kk < BK; kk += 32) {
            bf16x8 af[MT], bfr[NT];
            #pragma unroll
            for (int mt = 0; mt < MT; ++mt)
                af[mt] = *(const bf16x8*)&As[(wr * (BM / 2) + mt * 16 + l16) * BK + kk + quad * 8];
            #pragma unroll
            for (int nt = 0; nt < NT; ++nt)
                bfr[nt] = *(const bf16x8*)&Bs[(wc * (BN / 2) + nt * 16 + l16) * BK + kk + quad * 8];
            #pragma unroll
            for (int mt = 0; mt < MT; ++mt)
                #pragma unroll
                for (int nt = 0; nt < NT; ++nt)
                    acc[mt][nt] = __builtin_amdgcn_mfma_f32_16x16x32_bf16(
                        af[mt], bfr[nt], acc[mt][nt], 0, 0, 0);
        }
        __syncthreads();
    }

    // Epilogue. C/D layout: col = lane&15, row = (lane>>4)*4 + reg  [m89]
    #pragma unroll
    for (int mt = 0; mt < MT; ++mt) {
        #pragma unroll
        for (int nt = 0; nt < NT; ++nt) {
            #pragma unroll
            for (int r = 0; r < 4; ++r) {
                int row = m0 + wr * (BM / 2) + mt * 16 + quad * 4 + r;
                int col = n0 + wc * (BN / 2) + nt * 16 + l16;
                float val = acc[mt][nt][r];
                if (MODE == 0) {
                    if (addend) val += addend[(size_t)row * N + col];
                    ((float*)Cout)[(size_t)z * (size_t)strideC + (size_t)row * N + col] = val;
                } else if (MODE == 1) {
                    ((u16*)Cout)[(size_t)z * (size_t)strideC + (size_t)row * N + col] = f2b(val);
                } else if (MODE == 2) {
                    size_t idx = ((size_t)(z >> 4) * T_ + row) * (size_t)D_ + (z & 15) * HD_ + col;
                    ((u16*)Cout)[idx] = f2b(val);
                } else {  // MODE 5 — cg is lane-uniform
                    const int t  = row & (T_ - 1);
                    const int bb = m0 >> 10;
                    const int cg = (n0 >> 4) + wc * (BN / 32) + nt;
                    if (cg >= 1088) {
                        const int hh = cg - 1088;
                        ((float*)Cout2)[(((size_t)(bb * 64 + hh)) * T_ + t) * 16 + l16] = val;
                    } else {
                        const int hh  = cg / 17;
                        const int rem = cg - hh * 17;
                        ((u16*)Cout)[(((size_t)(bb * 64 + hh)) * T_ + t) * 272 + rem * 16 + l16] = f2b(val);
                    }
                }
            }
        }
    }
}

// ---------------------------------------------------------------------------
__global__ __launch_bounds__(256) void rmsnorm_k(
    const float* __restrict__ x, const float* __restrict__ w, u16* __restrict__ out)
{
    const int row = blockIdx.x, tid = threadIdx.x;
    float4 v = ((const float4*)(x + (size_t)row * D_))[tid];
    float ss = v.x * v.x + v.y * v.y + v.z * v.z + v.w * v.w;
    #pragma unroll
    for (int o = 32; o >= 1; o >>= 1) ss += __shfl_xor(ss, o, 64);
    __shared__ float red[4];
    if ((tid & 63) == 0) red[tid >> 6] = ss;
    __syncthreads();
    ss = red[0] + red[1] + red[2] + red[3];
    float scale = rsqrtf(ss * (1.0f / D_) + 1e-5f);
    float4 wv = ((const float4*)w)[tid];
    ushort4 o4;
    o4.x = f2b(v.x * scale * wv.x);
    o4.y = f2b(v.y * scale * wv.y);
    o4.z = f2b(v.z * scale * wv.z);
    o4.w = f2b(v.w * scale * wv.w);
    ((ushort4*)(out + (size_t)row * D_))[tid] = o4;
}

// ---------------------------------------------------------------------------
// All weight converts in one launch. Segments by blockIdx.x (all R=1024):
//   [0,96)   wqkv C=3072 -> wqkvT
//   [96,128) wao  C=1024 -> waoT
//   [128,160)wv   C=1024 -> waT + 17408*1024 (contiguous with waT)
//   [160,704)wa   C=17408-> waT
//   [704,736)wop  C=1024 -> wopT
// ---------------------------------------------------------------------------
__global__ void convT_all(
    const float* __restrict__ wqkv, const float* __restrict__ wao,
    const float* __restrict__ wv,   const float* __restrict__ wa,
    const float* __restrict__ wop,
    u16* __restrict__ wqkvT, u16* __restrict__ waoT,
    u16* __restrict__ waT,   u16* __restrict__ wopT)
{
    const int x = blockIdx.x;
    const float* in; u16* out; int C, xb;
    if (x < 96)       { in = wqkv; out = wqkvT; C = 3072;  xb = x; }
    else if (x < 128) { in = wao;  out = waoT;  C = 1024;  xb = x - 96; }
    else if (x < 160) { in = wv;   out = waT + (size_t)17408 * 1024; C = 1024; xb = x - 128; }
    else if (x < 704) { in = wa;   out = waT;   C = 17408; xb = x - 160; }
    else              { in = wop;  out = wopT;  C = 1024;  xb = x - 704; }
    constexpr int R = 1024;
    __shared__ float tile[32][33];
    const int c0 = xb * 32, r0 = blockIdx.y * 32;
    const int tx = threadIdx.x, ty = threadIdx.y;
    #pragma unroll
    for (int k = 0; k < 4; ++k)
        tile[ty + 8 * k][tx] = in[(size_t)(r0 + ty + 8 * k) * C + c0 + tx];
    __syncthreads();
    #pragma unroll
    for (int k = 0; k < 4; ++k)
        out[(size_t)(c0 + ty + 8 * k) * R + r0 + tx] = f2b(tile[tx][ty + 8 * k]);
}

__global__ void transpose_bf16_k(const u16* __restrict__ in_, u16* __restrict__ out_, int R, int C)
{
    __shared__ u16 tile[32][33];
    const u16* in = in_ + (size_t)blockIdx.z * R * C;
    u16* out      = out_ + (size_t)blockIdx.z * R * C;
    const int c0 = blockIdx.x * 32, r0 = blockIdx.y * 32;
    const int tx = threadIdx.x, ty = threadIdx.y;
    #pragma unroll
    for (int k = 0; k < 4; ++k)
        tile[ty + 8 * k][tx] = in[(size_t)(r0 + ty + 8 * k) * C + c0 + tx];
    __syncthreads();
    #pragma unroll
    for (int k = 0; k < 4; ++k)
        out[(size_t)(c0 + ty + 8 * k) * R + r0 + tx] = tile[tx][ty + 8 * k];
}

// ---------------------------------------------------------------------------
__global__ __launch_bounds__(256) void rope_k(
    const float* __restrict__ qkv, u16* __restrict__ Qb, u16* __restrict__ Kb, u16* __restrict__ Vb)
{
    const int bt = blockIdx.x;
    const int b = bt >> 10, t = bt & (T_ - 1);
    const float* row = qkv + (size_t)bt * 3072;
    const int tid = threadIdx.x;
    #pragma unroll
    for (int it = 0; it < 2; ++it) {
        int p = tid + it * 256;
        int h = p >> 5, i = p & 31;
        float ang = (float)t * exp2f(-(float)i * 0.41524101186092034f);
        float sn, cs;
        sincosf(ang, &sn, &cs);
        float q1 = row[h * 64 + i], q2 = row[h * 64 + i + 32];
        float k1 = row[1024 + h * 64 + i], k2 = row[1024 + h * 64 + i + 32];
        size_t ob = ((size_t)(b * NH_ + h) * T_ + t) * HD_ + i;
        Qb[ob]      = f2b(q1 * cs - q2 * sn);
        Qb[ob + 32] = f2b(q2 * cs + q1 * sn);
        Kb[ob]      = f2b(k1 * cs - k2 * sn);
        Kb[ob + 32] = f2b(k2 * cs + k1 * sn);
    }
    #pragma unroll
    for (int it = 0; it < 4; ++it) {
        int d = tid + it * 256;
        int h = d >> 6, i = d & 63;
        Vb[((size_t)(b * NH_ + h) * T_ + t) * HD_ + i] = f2b(row[2048 + d]);
    }
}

// ---------------------------------------------------------------------------
// Causal softmax, wave-per-row (4 rows/block). Only k < kmax = roundup(t+1,64)
// is read/written (PV's TRUNCK reads exactly that range).
// ---------------------------------------------------------------------------
__global__ __launch_bounds__(256) void softmax_causal_k(u16* __restrict__ S)
{
    const int w = threadIdx.x >> 6, lane = threadIdx.x & 63;
    const int z = blockIdx.x * 4 + w;         // (b*NH+h)*T + t
    const int t = z & (T_ - 1);
    u16* row = S + (size_t)z * T_;
    const int n = t + 1;
    const int kmax = (t & ~63) + 64;
    const int kb = lane * 4;
    float v[4][4];
    float mx = -1e30f;
    #pragma unroll
    for (int it = 0; it < 4; ++it) {
        int k = it * 256 + kb;
        if (k < kmax) {
            uint2 d = *(const uint2*)(row + k);
            v[it][0] = (k + 0 < n) ? blo(d.x) * 0.125f : -1e30f;
            v[it][1] = (k + 1 < n) ? bhi(d.x) * 0.125f : -1e30f;
            v[it][2] = (k + 2 < n) ? blo(d.y) * 0.125f : -1e30f;
            v[it][3] = (k + 3 < n) ? bhi(d.y) * 0.125f : -1e30f;
        } else {
            v[it][0] = v[it][1] = v[it][2] = v[it][3] = -1e30f;
        }
        mx = fmaxf(mx, fmaxf(fmaxf(v[it][0], v[it][1]), fmaxf(v[it][2], v[it][3])));
    }
    #pragma unroll
    for (int o = 32; o >= 1; o >>= 1) mx = fmaxf(mx, __shfl_xor(mx, o, 64));
    float sum = 0.f;
    #pragma unroll
    for (int it = 0; it < 4; ++it)
        #pragma unroll
        for (int j = 0; j < 4; ++j) {
            float e = (v[it][j] > -1e29f) ? __expf(v[it][j] - mx) : 0.f;
            v[it][j] = e;
            sum += e;
        }
    #pragma unroll
    for (int o = 32; o >= 1; o >>= 1) sum += __shfl_xor(sum, o, 64);
    float inv = 1.0f / sum;
    #pragma unroll
    for (int it = 0; it < 4; ++it) {
        int k = it * 256 + kb;
        if (k < kmax) {
            uint2 d;
            d.x = (u32)f2b(v[it][0] * inv) | ((u32)f2b(v[it][1] * inv) << 16);
            d.y = (u32)f2b(v[it][2] * inv) | ((u32)f2b(v[it][3] * inv) << 16);
            *(uint2*)(row + k) = d;
        }
    }
}

// ---------------------------------------------------------------------------
// Scan-chunk prep (shared by p1/p2): raw gate logits for a 32-step chunk in
// glds (32 x 16 rows x 17 bf16 @ 34 B). Softmax each row, repack the 16
// A-entries in place to (st*16+i)*32 B (bf16), scale vlds (v -> a0*v).
// ---------------------------------------------------------------------------
__device__ __forceinline__ void scan_prep(u16* glds, float* vlds, int lane)
{
    #pragma unroll
    for (int rnd = 0; rnd < 2; ++rnd) {
        float p[4][17];
        #pragma unroll
        for (int j = 0; j < 4; ++j) {
            int r = rnd * 256 + j * 64 + lane;
            const u16* g = &glds[r * 17];
            float vv[17];
            float mx = -1e30f;
            #pragma unroll
            for (int tt = 0; tt < 17; ++tt) { vv[tt] = b2f(g[tt]); mx = fmaxf(mx, vv[tt]); }
            float s = 0.f;
            #pragma unroll
            for (int tt = 0; tt < 17; ++tt) { vv[tt] = __expf(vv[tt] - mx); s += vv[tt]; }
            float inv = 1.0f / s;
            #pragma unroll
            for (int tt = 0; tt < 17; ++tt) p[j][tt] = vv[tt] * inv;
        }
        __syncthreads();
        #pragma unroll
        for (int j = 0; j < 4; ++j) {
            int r = rnd * 256 + j * 64 + lane;
            uint4 w0, w1;
            w0.x = (u32)f2b(p[j][1])  | ((u32)f2b(p[j][2])  << 16);
            w0.y = (u32)f2b(p[j][3])  | ((u32)f2b(p[j][4])  << 16);
            w0.z = (u32)f2b(p[j][5])  | ((u32)f2b(p[j][6])  << 16);
            w0.w = (u32)f2b(p[j][7])  | ((u32)f2b(p[j][8])  << 16);
            w1.x = (u32)f2b(p[j][9])  | ((u32)f2b(p[j][10]) << 16);
            w1.y = (u32)f2b(p[j][11]) | ((u32)f2b(p[j][12]) << 16);
            w1.z = (u32)f2b(p[j][13]) | ((u32)f2b(p[j][14]) << 16);
            w1.w = (u32)f2b(p[j][15]) | ((u32)f2b(p[j][16]) << 16);
            ((uint4*)glds)[r * 2]     = w0;
            ((uint4*)glds)[r * 2 + 1] = w1;
            vlds[r] *= p[j][0];
        }
        __syncthreads();
    }
}

// ---------------------------------------------------------------------------
// scan pass 1: per chunk of 32 steps compute P_c = A_31..A_0, e_c.
// ---------------------------------------------------------------------------
__global__ __launch_bounds__(64) void scan_p1(
    const u16* __restrict__ gates, const float* __restrict__ vvT,
    float* __restrict__ Pmat, float* __restrict__ evec)
{
    const int c = blockIdx.x, chain = blockIdx.y;
    const int lane = threadIdx.x;
    const int i = lane >> 2, q = lane & 3;
    __shared__ alignas(16) u16   glds[32 * 272];
    __shared__ alignas(16) float vlds[32 * 16];
    __shared__ alignas(16) float Pb[2][256];
    __shared__ float slds[16];

    const char* gbase = (const char*)(gates + ((size_t)chain * T_ + c * 32) * 272);
    #pragma unroll
    for (int it = 0; it < 17; ++it)
        stage16(gbase + it * 1024 + lane * 16, (char*)glds + it * 1024);
    const char* vbase = (const char*)(vvT + ((size_t)chain * T_ + c * 32) * 16);
    #pragma unroll
    for (int it = 0; it < 2; ++it)
        stage16(vbase + it * 1024 + lane * 16, (char*)vlds + it * 1024);
    __syncthreads();

    scan_prep(glds, vlds, lane);

    {
        f32x4 idq;
        #pragma unroll
        for (int m = 0; m < 4; ++m) idq[m] = (i == q * 4 + m) ? 1.f : 0.f;
        *(f32x4*)&Pb[0][i * 16 + q * 4] = idq;
    }
    f32x4 e4[4] = {};
    f32x4 np = {};
    float neLast = 0.f;
    int cur = 0;

    for (int st = 0; st < 32; ++st) {
        const uint4* rp = (const uint4*)((const char*)glds + (st * 16 + i) * 32);
        uint4 d0 = rp[0], d1 = rp[1];
        float ar[16];
        ar[0]  = blo(d0.x); ar[1]  = bhi(d0.x);
        ar[2]  = blo(d0.y); ar[3]  = bhi(d0.y);
        ar[4]  = blo(d0.z); ar[5]  = bhi(d0.z);
        ar[6]  = blo(d0.w); ar[7]  = bhi(d0.w);
        ar[8]  = blo(d1.x); ar[9]  = bhi(d1.x);
        ar[10] = blo(d1.y); ar[11] = bhi(d1.y);
        ar[12] = blo(d1.z); ar[13] = bhi(d1.z);
        ar[14] = blo(d1.w); ar[15] = bhi(d1.w);

        f32x4 pk[16];
        #pragma unroll
        for (int k = 0; k < 16; ++k)
            pk[k] = *(const f32x4*)&Pb[cur][k * 16 + q * 4];

        f32x4 a = pk[0] * ar[0];
        #pragma unroll
        for (int k = 1; k < 16; ++k) a += pk[k] * ar[k];
        np = a;

        float ne0 = ar[0] * e4[0][0] + ar[1] * e4[0][1] + ar[2] * e4[0][2] + ar[3] * e4[0][3];
        float ne1 = ar[4] * e4[1][0] + ar[5] * e4[1][1] + ar[6] * e4[1][2] + ar[7] * e4[1][3];
        float ne2 = ar[8] * e4[2][0] + ar[9] * e4[2][1] + ar[10] * e4[2][2] + ar[11] * e4[2][3];
        float ne3 = ar[12] * e4[3][0] + ar[13] * e4[3][1] + ar[14] * e4[3][2] + ar[15] * e4[3][3];
        float ne = (ne0 + ne1) + (ne2 + ne3) + vlds[st * 16 + i];

        *(f32x4*)&Pb[cur ^ 1][i * 16 + q * 4] = np;
        if (q == 0) slds[i] = ne;
        #pragma unroll
        for (int m = 0; m < 4; ++m) e4[m] = *(const f32x4*)&slds[m * 4];
        neLast = ne;
        cur ^= 1;
    }

    float* Pd = Pmat + ((size_t)chain * 32 + c) * 256;
    *(f32x4*)&Pd[i * 16 + q * 4] = np;
    if (q == 0) evec[((size_t)chain * 32 + c) * 16 + i] = neLast;
}

// ---------------------------------------------------------------------------
// scan pass 2: per chain, sequentially combine 32 chunks; sIn[c] = entry state.
// ---------------------------------------------------------------------------
__global__ __launch_bounds__(64) void scan_comb(
    const float* __restrict__ Pmat, const float* __restrict__ evec, float* __restrict__ sIn)
{
    const int chain = blockIdx.x;
    const int lane = threadIdx.x;
    const int i = lane >> 2, q = lane & 3;
    __shared__ alignas(16) float Pl[32 * 256];
    __shared__ alignas(16) float El[32 * 16];
    __shared__ float slds[16];

    const char* Pg = (const char*)(Pmat + (size_t)chain * 32 * 256);
    #pragma unroll
    for (int it = 0; it < 32; ++it)
        stage16(Pg + it * 1024 + lane * 16, (char*)Pl + it * 1024);
    const char* Eg = (const char*)(evec + (size_t)chain * 32 * 16);
    #pragma unroll
    for (int it = 0; it < 2; ++it)
        stage16(Eg + it * 1024 + lane * 16, (char*)El + it * 1024);
    __syncthreads();

    f32x4 s4[4] = {};
    if (q == 0) sIn[((size_t)chain * 32 + 0) * 16 + i] = 0.f;
    for (int cc = 0; cc < 32; ++cc) {
        f32x4 pr[4];
        #pragma unroll
        for (int m = 0; m < 4; ++m)
            pr[m] = *(const f32x4*)&Pl[cc * 256 + i * 16 + m * 4];
        float ne = 0.f;
        #pragma unroll
        for (int k = 0; k < 16; ++k) ne += pr[k >> 2][k & 3] * s4[k >> 2][k & 3];
        ne += El[cc * 16 + i];
        if (q == 0) {
            slds[i] = ne;
            if (cc < 31) sIn[((size_t)chain * 32 + cc + 1) * 16 + i] = ne;
        }
        #pragma unroll
        for (int m = 0; m < 4; ++m) s4[m] = *(const f32x4*)&slds[m * 4];
    }
}

// ---------------------------------------------------------------------------
// scan pass 3: replay each chunk from its entry state, write h_out.
// ---------------------------------------------------------------------------
__global__ __launch_bounds__(64) void scan_p2(
    const u16* __restrict__ gates, const float* __restrict__ vvT,
    const float* __restrict__ sIn, u16* __restrict__ hout)
{
    const int c = blockIdx.x, chain = blockIdx.y;
    const int b = chain >> 6, hh = chain & 63;
    const int lane = threadIdx.x;
    const int i = lane >> 2, q = lane & 3;
    __shared__ alignas(16) u16   glds[32 * 272];
    __shared__ alignas(16) float vlds[32 * 16];
    __shared__ float slds[16];

    const char* gbase = (const char*)(gates + ((size_t)chain * T_ + c * 32) * 272);
    #pragma unroll
    for (int it = 0; it < 17; ++it)
        stage16(gbase + it * 1024 + lane * 16, (char*)glds + it * 1024);
    const char* vbase = (const char*)(vvT + ((size_t)chain * T_ + c * 32) * 16);
    #pragma unroll
    for (int it = 0; it < 2; ++it)
        stage16(vbase + it * 1024 + lane * 16, (char*)vlds + it * 1024);
    __syncthreads();

    scan_prep(glds, vlds, lane);

    const float* sp = sIn + ((size_t)chain * 32 + c) * 16;
    f32x4 s4[4];
    #pragma unroll
    for (int m = 0; m < 4; ++m) s4[m] = *(const f32x4*)(sp + m * 4);

    u16* hbase = hout + ((size_t)(b * T_ + c * 32)) * D_ + hh * 16;
    for (int st = 0; st < 32; ++st) {
        const uint4* rp = (const uint4*)((const char*)glds + (st * 16 + i) * 32);
        uint4 d0 = rp[0], d1 = rp[1];
        float ne0 = blo(d0.x) * s4[0][0] + bhi(d0.x) * s4[0][1]
                  + blo(d0.y) * s4[0][2] + bhi(d0.y) * s4[0][3];
        float ne1 = blo(d0.z) * s4[1][0] + bhi(d0.z) * s4[1][1]
                  + blo(d0.w) * s4[1][2] + bhi(d0.w) * s4[1][3];
        float ne2 = blo(d1.x) * s4[2][0] + bhi(d1.x) * s4[2][1]
                  + blo(d1.y) * s4[2][2] + bhi(d1.y) * s4[2][3];
        float ne3 = blo(d1.z) * s4[3][0] + bhi(d1.z) * s4[3][1]
                  + blo(d1.w) * s4[3][2] + bhi(d1.w) * s4[3][3];
        float ne = (ne0 + ne1) + (ne2 + ne3) + vlds[st * 16 + i];
        if (q == 0) {
            slds[i] = ne;
            hbase[(size_t)st * D_ + i] = f2b(ne);
        }
        #pragma unroll
        for (int m = 0; m < 4; ++m) s4[m] = *(const f32x4*)&slds[m * 4];
    }
}

// ---------------------------------------------------------------------------
extern "C" void kernel_launch(void* const* d_in, const int* in_sizes, int n_in,
                              void* d_out, int out_size, void* d_ws, size_t ws_size,
                              hipStream_t stream)
{
    const float* x    = (const float*)d_in[0];
    const float* anw  = (const float*)d_in[1];
    const float* wqkv = (const float*)d_in[2];
    const float* wao  = (const float*)d_in[3];
    const float* lnw  = (const float*)d_in[4];
    const float* wv   = (const float*)d_in[5];
    const float* wa   = (const float*)d_in[6];
    const float* wop  = (const float*)d_in[7];

    char* ws = (char*)d_ws;
    const size_t MB = 1u << 20;
    u16*   h     = (u16*)  (ws +   0 * MB);   //  4 MB
    u16*   h2    = (u16*)  (ws +   4 * MB);   //  4 MB
    u16*   wqkvT = (u16*)  (ws +   8 * MB);   //  6 MB
    u16*   waoT  = (u16*)  (ws +  14 * MB);   //  2 MB
    u16*   wopT  = (u16*)  (ws +  16 * MB);   //  2 MB
    u16*   waT   = (u16*)  (ws +  18 * MB);   // 36 MB (wa 17408 rows + wv 1024 rows)
    float* qkvf  = (float*)(ws +  54 * MB);   // 24 MB (dead after rope)
    float* x2    = (float*)(ws +  54 * MB);   //  8 MB aliases qkvf head
    float* vvT   = (float*)(ws +  62 * MB);   //  8 MB scan layout [chain][t][16]
    u16*   Qb    = (u16*)  (ws +  78 * MB);   //  4 MB (dead after QK^T)
    float* Pmat  = (float*)(ws +  78 * MB);   //  4 MB aliases Qb
    u16*   Kb    = (u16*)  (ws +  82 * MB);   //  4 MB (dead after QK^T)
    float* evec  = (float*)(ws +  82 * MB);   // 256 KB aliases Kb
    float* sIn   = (float*)(ws +  82 * MB + 256 * 1024); // 256 KB
    u16*   Vb    = (u16*)  (ws +  86 * MB);   //  4 MB (dead after transpose)
    u16*   Vt    = (u16*)  (ws +  90 * MB);   //  4 MB (dead after PV)
    u16*   S     = (u16*)  (ws +  94 * MB);   // 64 MB (dead after PV)
    u16*   omat  = (u16*)  (ws + 158 * MB);   //  4 MB (dead after attn_out)
    u16*   gates = (u16*)  (ws +  94 * MB);   // 68 MB aliases S+omat
    u16*   hout  = (u16*)  (ws + 162 * MB);   //  4 MB (end: 166 MB)
    (void)in_sizes; (void)n_in; (void)out_size; (void)ws_size;

    dim3 tb(32, 8);
    convT_all<<<dim3(736, 32), tb, 0, stream>>>(
        wqkv, wao, wv, wa, wop, wqkvT, waoT, waT, wopT);

    rmsnorm_k<<<2048, 256, 0, stream>>>(x, anw, h);
    gemm_bt<64, 128, 32, 0, false, false, false><<<dim3(24, 32, 1), 256, 0, stream>>>(
        h, wqkvT, (void*)qkvf, nullptr, nullptr, 2048, 3072, 1024, 0, 0, 0);
    rope_k<<<2048, 256, 0, stream>>>(qkvf, Qb, Kb, Vb);
    transpose_bf16_k<<<dim3(2, 32, 32), tb, 0, stream>>>(Vb, Vt, 1024, 64);

    // QK^T: K=64 -> BK=64, single staging round per block
    gemm_bt<128, 128, 64, 1, false, true, false><<<dim3(8, 8, 32), 256, 0, stream>>>(
        Qb, Kb, (void*)S, nullptr, nullptr, 1024, 1024, 64, 65536, 65536, 1048576);
    softmax_causal_k<<<8192, 256, 0, stream>>>(S);
    // PV: BM=64, BK=64 -> half the barrier drains
    gemm_bt<64, 64, 64, 2, true, false, false><<<dim3(1, 16, 32), 256, 0, stream>>>(
        S, Vt, (void*)omat, nullptr, nullptr, 1024, 64, 1024, 1048576, 65536, 0);

    gemm_bt<64, 128, 32, 0, false, false, false><<<dim3(8, 32, 1), 256, 0, stream>>>(
        omat, waoT, (void*)x2, nullptr, x, 2048, 1024, 1024, 0, 0, 0);
    rmsnorm_k<<<2048, 256, 0, stream>>>(x2, lnw, h2);

    // fused gates + w_v GEMM: N = 17408 + 1024, BK=32, XCD swizzle
    gemm_bt<128, 128, 32, 5, false, false, true><<<dim3(144, 16, 1), 256, 0, stream>>>(
        h2, waT, (void*)gates, (void*)vvT, nullptr, 2048, 18432, 1024, 0, 0, 0);

    scan_p1<<<dim3(32, 128), 64, 0, stream>>>(gates, vvT, Pmat, evec);
    scan_comb<<<128, 64, 0, stream>>>(Pmat, evec, sIn);
    scan_p2<<<dim3(32, 128), 64, 0, stream>>>(gates, vvT, sIn, hout);

    gemm_bt<64, 128, 32, 0, false, false, false><<<dim3(8, 32, 1), 256, 0, stream>>>(
        hout, wopT, d_out, nullptr, x2, 2048, 1024, 1024, 0, 0, 0);
}

// Round 7
// 492.574 us; speedup vs baseline: 2.4469x; 1.0259x over previous
//
#include <hip/hip_runtime.h>

// HKSABlock on MI355X (gfx950). Round 7: gates GEMM bx-band XCD swizzle
// (R6's FETCH=8xB confirmed flat-id->XCD round-robin; now each XCD owns an
// 18-wide bx band x all by, B-panels L2-shared by 16 blocks), RoPE fused
// into qkv GEMM epilogue (rope_k + 36 MB qkvf traffic eliminated).
// B=2, T=1024, D=1024, NH=16, HD=64, H=64, M=16.

typedef unsigned short u16;
typedef unsigned int   u32;
typedef __bf16 bf16x8 __attribute__((ext_vector_type(8)));
typedef float  f32x4  __attribute__((ext_vector_type(4)));

#define B_  2
#define T_  1024
#define D_  1024
#define NH_ 16
#define HD_ 64
#define H_  64
#define M_  16

__device__ __forceinline__ float b2f(u16 u) {
    return __uint_as_float(((u32)u) << 16);
}
__device__ __forceinline__ u16 f2b(float f) {
    u32 u = __float_as_uint(f);
    u32 r = (u + 0x7FFFu + ((u >> 16) & 1u)) >> 16;  // RNE
    return (u16)r;
}
__device__ __forceinline__ float blo(u32 u) { return __uint_as_float(u << 16); }
__device__ __forceinline__ float bhi(u32 u) { return __uint_as_float(u & 0xFFFF0000u); }

// Async global->LDS, 16 B per lane. LDS dest must be wave-uniform base.
__device__ __forceinline__ void stage16(const void* gp, void* lp) {
    typedef __attribute__((address_space(1))) const unsigned int GU;
    typedef __attribute__((address_space(3))) unsigned int LU;
    __builtin_amdgcn_global_load_lds((GU*)gp, (LU*)lp, 16, 0, 0);
}

// ---------------------------------------------------------------------------
// Generic MFMA GEMM: C[M,N] = A[M,K] * Bt[N,K]^T  (A,Bt bf16 row-major).
// 4 waves: wr = w>>1 (m-half), wc = w&1 (n-half). MT = BM/32, NT = BN/32.
// MODE 0: C fp32 (+ optional fp32 addend). MODE 1: C bf16.
// MODE 2: bf16 scatter into o_mat[(b*T + row)*1024 + h*64 + col], z = b*16+h.
// MODE 5: col<17408 -> gates scan layout [chain][t][272] bf16; col>=17408 ->
//         vvT [chain][t][16] fp32 (Cout2).
// MODE 6: qkv + fused RoPE. N=3072; region = n0>>10 (0=Q,1=K,2=V). Each wave
//         owns one head's 64 cols; RoPE pair (i,i+32) = acc nt and nt+2.
//         Writes Qb(Cout)/Kb(Cout2)/Vb(Cout3) bf16 in (b,h,t,d).
// CAUSAL: skip blocks with n0 > m0+BM-1. TRUNCK: K truncated to m0+BM.
// SWZ==2: XCD band swizzle — xcd = flat&7 owns bx band of gridDim.x/8,
//         by innermost (16 blocks share each B-panel in XCD L2).
// ---------------------------------------------------------------------------
template<int BM, int BN, int BK, int MODE, bool TRUNCK, bool CAUSAL, int SWZ>
__global__ __launch_bounds__(256) void gemm_bt(
    const u16* __restrict__ A, const u16* __restrict__ Bt,
    void* __restrict__ Cout, void* __restrict__ Cout2, void* __restrict__ Cout3,
    const float* __restrict__ addend,
    int M, int N, int K, long strideA, long strideB, long strideC)
{
    constexpr int MT = BM / 32;
    constexpr int NT = BN / 32;
    constexpr int KCH = BK / 8;                  // 16B slots per row
    const int z  = blockIdx.z;
    int bx = blockIdx.x, by = blockIdx.y;
    if (SWZ == 2) {
        int f = by * gridDim.x + bx;
        int xcd = f & 7, k = f >> 3;
        by = k & 15;                             // by innermost per XCD
        bx = xcd * (gridDim.x >> 3) + (k >> 4);  // 18-wide band per XCD
    }
    const int m0 = by * BM;
    const int n0 = bx * BN;
    if (CAUSAL && n0 > m0 + BM - 1) return;
    const int Keff = TRUNCK ? (K < m0 + BM ? K : m0 + BM) : K;

    const u16* Ab = A  + (size_t)z * (size_t)strideA;
    const u16* Bb = Bt + (size_t)z * (size_t)strideB;

    __shared__ alignas(16) u16 As[BM * BK];
    __shared__ alignas(16) u16 Bs[BN * BK];

    const int tid  = threadIdx.x;
    const int lane = tid & 63, w = tid >> 6;
    const int wr = w >> 1, wc = w & 1;
    const int quad = lane >> 4, l16 = lane & 15;

    f32x4 acc[MT][NT] = {};

    constexpr int AITER = (BM * BK / 8) / 256;
    constexpr int BITER = (BN * BK / 8) / 256;

    for (int k0 = 0; k0 < Keff; k0 += BK) {
        #pragma unroll
        for (int it = 0; it < AITER; ++it) {
            int c = it * 256 + tid;
            int m = c / KCH, kc = c % KCH;
            stage16(Ab + (size_t)(m0 + m) * K + k0 + kc * 8,
                    &As[(it * 256 + w * 64) * 8]);
        }
        #pragma unroll
        for (int it = 0; it < BITER; ++it) {
            int c = it * 256 + tid;
            int n = c / KCH, kc = c % KCH;
            stage16(Bb + (size_t)(n0 + n) * K + k0 + kc * 8,
                    &Bs[(it * 256 + w * 64) * 8]);
        }
        __syncthreads();

        #pragma unroll
        for (int kk = 0; kk < BK; kk += 32) {
            bf16x8 af[MT], bfr[NT];
            #pragma unroll
            for (int mt = 0; mt < MT; ++mt)
                af[mt] = *(const bf16x8*)&As[(wr * (BM / 2) + mt * 16 + l16) * BK + kk + quad * 8];
            #pragma unroll
            for (int nt = 0; nt < NT; ++nt)
                bfr[nt] = *(const bf16x8*)&Bs[(wc * (BN / 2) + nt * 16 + l16) * BK + kk + quad * 8];
            #pragma unroll
            for (int mt = 0; mt < MT; ++mt)
                #pragma unroll
                for (int nt = 0; nt < NT; ++nt)
                    acc[mt][nt] = __builtin_amdgcn_mfma_f32_16x16x32_bf16(
                        af[mt], bfr[nt], acc[mt][nt], 0, 0, 0);
        }
        __syncthreads();
    }

    // Epilogue. C/D layout: col = lane&15, row = (lane>>4)*4 + reg  [m89]
    if (MODE == 6) {
        // dedicated RoPE epilogue (NT==4, BN==128 required)
        const int reg = n0 >> 10;                      // 0=Q, 1=K, 2=V
        const int hh  = ((n0 & 1023) >> 6) + wc;       // head
        #pragma unroll
        for (int mt = 0; mt < MT; ++mt) {
            #pragma unroll
            for (int r = 0; r < 4; ++r) {
                int row = m0 + wr * (BM / 2) + mt * 16 + quad * 4 + r;
                int t = row & (T_ - 1), bb = row >> 10;
                size_t obase = ((size_t)(bb * NH_ + hh) * T_ + t) * HD_;
                if (reg == 2) {
                    #pragma unroll
                    for (int nt = 0; nt < 4; ++nt)
                        ((u16*)Cout3)[obase + nt * 16 + l16] = f2b(acc[mt][nt][r]);
                } else {
                    u16* dst = (reg == 0) ? (u16*)Cout : (u16*)Cout2;
                    #pragma unroll
                    for (int nt = 0; nt < 2; ++nt) {
                        int i = nt * 16 + l16;
                        float ang = (float)t * exp2f(-(float)i * 0.41524101186092034f);
                        float sn, cs;
                        sincosf(ang, &sn, &cs);
                        float q1 = acc[mt][nt][r], q2 = acc[mt][nt + 2][r];
                        dst[obase + i]      = f2b(q1 * cs - q2 * sn);
                        dst[obase + i + 32] = f2b(q2 * cs + q1 * sn);
                    }
                }
            }
        }
        return;
    }
    #pragma unroll
    for (int mt = 0; mt < MT; ++mt) {
        #pragma unroll
        for (int nt = 0; nt < NT; ++nt) {
            #pragma unroll
            for (int r = 0; r < 4; ++r) {
                int row = m0 + wr * (BM / 2) + mt * 16 + quad * 4 + r;
                int col = n0 + wc * (BN / 2) + nt * 16 + l16;
                float val = acc[mt][nt][r];
                if (MODE == 0) {
                    if (addend) val += addend[(size_t)row * N + col];
                    ((float*)Cout)[(size_t)z * (size_t)strideC + (size_t)row * N + col] = val;
                } else if (MODE == 1) {
                    ((u16*)Cout)[(size_t)z * (size_t)strideC + (size_t)row * N + col] = f2b(val);
                } else if (MODE == 2) {
                    size_t idx = ((size_t)(z >> 4) * T_ + row) * (size_t)D_ + (z & 15) * HD_ + col;
                    ((u16*)Cout)[idx] = f2b(val);
                } else {  // MODE 5 — cg is lane-uniform
                    const int t  = row & (T_ - 1);
                    const int bb = m0 >> 10;
                    const int cg = (n0 >> 4) + wc * (BN / 32) + nt;
                    if (cg >= 1088) {
                        const int hh = cg - 1088;
                        ((float*)Cout2)[(((size_t)(bb * 64 + hh)) * T_ + t) * 16 + l16] = val;
                    } else {
                        const int hh  = cg / 17;
                        const int rem = cg - hh * 17;
                        ((u16*)Cout)[(((size_t)(bb * 64 + hh)) * T_ + t) * 272 + rem * 16 + l16] = f2b(val);
                    }
                }
            }
        }
    }
}

// ---------------------------------------------------------------------------
__global__ __launch_bounds__(256) void rmsnorm_k(
    const float* __restrict__ x, const float* __restrict__ w, u16* __restrict__ out)
{
    const int row = blockIdx.x, tid = threadIdx.x;
    float4 v = ((const float4*)(x + (size_t)row * D_))[tid];
    float ss = v.x * v.x + v.y * v.y + v.z * v.z + v.w * v.w;
    #pragma unroll
    for (int o = 32; o >= 1; o >>= 1) ss += __shfl_xor(ss, o, 64);
    __shared__ float red[4];
    if ((tid & 63) == 0) red[tid >> 6] = ss;
    __syncthreads();
    ss = red[0] + red[1] + red[2] + red[3];
    float scale = rsqrtf(ss * (1.0f / D_) + 1e-5f);
    float4 wv = ((const float4*)w)[tid];
    ushort4 o4;
    o4.x = f2b(v.x * scale * wv.x);
    o4.y = f2b(v.y * scale * wv.y);
    o4.z = f2b(v.z * scale * wv.z);
    o4.w = f2b(v.w * scale * wv.w);
    ((ushort4*)(out + (size_t)row * D_))[tid] = o4;
}

// ---------------------------------------------------------------------------
// All weight converts in one launch. Segments by blockIdx.x (all R=1024):
//   [0,96)   wqkv C=3072 -> wqkvT
//   [96,128) wao  C=1024 -> waoT
//   [128,160)wv   C=1024 -> waT + 17408*1024 (contiguous with waT)
//   [160,704)wa   C=17408-> waT
//   [704,736)wop  C=1024 -> wopT
// ---------------------------------------------------------------------------
__global__ void convT_all(
    const float* __restrict__ wqkv, const float* __restrict__ wao,
    const float* __restrict__ wv,   const float* __restrict__ wa,
    const float* __restrict__ wop,
    u16* __restrict__ wqkvT, u16* __restrict__ waoT,
    u16* __restrict__ waT,   u16* __restrict__ wopT)
{
    const int x = blockIdx.x;
    const float* in; u16* out; int C, xb;
    if (x < 96)       { in = wqkv; out = wqkvT; C = 3072;  xb = x; }
    else if (x < 128) { in = wao;  out = waoT;  C = 1024;  xb = x - 96; }
    else if (x < 160) { in = wv;   out = waT + (size_t)17408 * 1024; C = 1024; xb = x - 128; }
    else if (x < 704) { in = wa;   out = waT;   C = 17408; xb = x - 160; }
    else              { in = wop;  out = wopT;  C = 1024;  xb = x - 704; }
    constexpr int R = 1024;
    __shared__ float tile[32][33];
    const int c0 = xb * 32, r0 = blockIdx.y * 32;
    const int tx = threadIdx.x, ty = threadIdx.y;
    #pragma unroll
    for (int k = 0; k < 4; ++k)
        tile[ty + 8 * k][tx] = in[(size_t)(r0 + ty + 8 * k) * C + c0 + tx];
    __syncthreads();
    #pragma unroll
    for (int k = 0; k < 4; ++k)
        out[(size_t)(c0 + ty + 8 * k) * R + r0 + tx] = f2b(tile[tx][ty + 8 * k]);
}

__global__ void transpose_bf16_k(const u16* __restrict__ in_, u16* __restrict__ out_, int R, int C)
{
    __shared__ u16 tile[32][33];
    const u16* in = in_ + (size_t)blockIdx.z * R * C;
    u16* out      = out_ + (size_t)blockIdx.z * R * C;
    const int c0 = blockIdx.x * 32, r0 = blockIdx.y * 32;
    const int tx = threadIdx.x, ty = threadIdx.y;
    #pragma unroll
    for (int k = 0; k < 4; ++k)
        tile[ty + 8 * k][tx] = in[(size_t)(r0 + ty + 8 * k) * C + c0 + tx];
    __syncthreads();
    #pragma unroll
    for (int k = 0; k < 4; ++k)
        out[(size_t)(c0 + ty + 8 * k) * R + r0 + tx] = tile[tx][ty + 8 * k];
}

// ---------------------------------------------------------------------------
// Causal softmax, wave-per-row (4 rows/block). Only k < kmax = roundup(t+1,64)
// is read/written (PV's TRUNCK reads exactly that range).
// ---------------------------------------------------------------------------
__global__ __launch_bounds__(256) void softmax_causal_k(u16* __restrict__ S)
{
    const int w = threadIdx.x >> 6, lane = threadIdx.x & 63;
    const int z = blockIdx.x * 4 + w;
    const int t = z & (T_ - 1);
    u16* row = S + (size_t)z * T_;
    const int n = t + 1;
    const int kmax = (t & ~63) + 64;
    const int kb = lane * 4;
    float v[4][4];
    float mx = -1e30f;
    #pragma unroll
    for (int it = 0; it < 4; ++it) {
        int k = it * 256 + kb;
        if (k < kmax) {
            uint2 d = *(const uint2*)(row + k);
            v[it][0] = (k + 0 < n) ? blo(d.x) * 0.125f : -1e30f;
            v[it][1] = (k + 1 < n) ? bhi(d.x) * 0.125f : -1e30f;
            v[it][2] = (k + 2 < n) ? blo(d.y) * 0.125f : -1e30f;
            v[it][3] = (k + 3 < n) ? bhi(d.y) * 0.125f : -1e30f;
        } else {
            v[it][0] = v[it][1] = v[it][2] = v[it][3] = -1e30f;
        }
        mx = fmaxf(mx, fmaxf(fmaxf(v[it][0], v[it][1]), fmaxf(v[it][2], v[it][3])));
    }
    #pragma unroll
    for (int o = 32; o >= 1; o >>= 1) mx = fmaxf(mx, __shfl_xor(mx, o, 64));
    float sum = 0.f;
    #pragma unroll
    for (int it = 0; it < 4; ++it)
        #pragma unroll
        for (int j = 0; j < 4; ++j) {
            float e = (v[it][j] > -1e29f) ? __expf(v[it][j] - mx) : 0.f;
            v[it][j] = e;
            sum += e;
        }
    #pragma unroll
    for (int o = 32; o >= 1; o >>= 1) sum += __shfl_xor(sum, o, 64);
    float inv = 1.0f / sum;
    #pragma unroll
    for (int it = 0; it < 4; ++it) {
        int k = it * 256 + kb;
        if (k < kmax) {
            uint2 d;
            d.x = (u32)f2b(v[it][0] * inv) | ((u32)f2b(v[it][1] * inv) << 16);
            d.y = (u32)f2b(v[it][2] * inv) | ((u32)f2b(v[it][3] * inv) << 16);
            *(uint2*)(row + k) = d;
        }
    }
}

// ---------------------------------------------------------------------------
// Scan-chunk prep (shared by p1/p2): raw gate logits for a 32-step chunk in
// glds (32 x 16 rows x 17 bf16 @ 34 B). Softmax each row, repack the 16
// A-entries in place to (st*16+i)*32 B (bf16), scale vlds (v -> a0*v).
// ---------------------------------------------------------------------------
__device__ __forceinline__ void scan_prep(u16* glds, float* vlds, int lane)
{
    #pragma unroll
    for (int rnd = 0; rnd < 2; ++rnd) {
        float p[4][17];
        #pragma unroll
        for (int j = 0; j < 4; ++j) {
            int r = rnd * 256 + j * 64 + lane;
            const u16* g = &glds[r * 17];
            float vv[17];
            float mx = -1e30f;
            #pragma unroll
            for (int tt = 0; tt < 17; ++tt) { vv[tt] = b2f(g[tt]); mx = fmaxf(mx, vv[tt]); }
            float s = 0.f;
            #pragma unroll
            for (int tt = 0; tt < 17; ++tt) { vv[tt] = __expf(vv[tt] - mx); s += vv[tt]; }
            float inv = 1.0f / s;
            #pragma unroll
            for (int tt = 0; tt < 17; ++tt) p[j][tt] = vv[tt] * inv;
        }
        __syncthreads();
        #pragma unroll
        for (int j = 0; j < 4; ++j) {
            int r = rnd * 256 + j * 64 + lane;
            uint4 w0, w1;
            w0.x = (u32)f2b(p[j][1])  | ((u32)f2b(p[j][2])  << 16);
            w0.y = (u32)f2b(p[j][3])  | ((u32)f2b(p[j][4])  << 16);
            w0.z = (u32)f2b(p[j][5])  | ((u32)f2b(p[j][6])  << 16);
            w0.w = (u32)f2b(p[j][7])  | ((u32)f2b(p[j][8])  << 16);
            w1.x = (u32)f2b(p[j][9])  | ((u32)f2b(p[j][10]) << 16);
            w1.y = (u32)f2b(p[j][11]) | ((u32)f2b(p[j][12]) << 16);
            w1.z = (u32)f2b(p[j][13]) | ((u32)f2b(p[j][14]) << 16);
            w1.w = (u32)f2b(p[j][15]) | ((u32)f2b(p[j][16]) << 16);
            ((uint4*)glds)[r * 2]     = w0;
            ((uint4*)glds)[r * 2 + 1] = w1;
            vlds[r] *= p[j][0];
        }
        __syncthreads();
    }
}

// ---------------------------------------------------------------------------
// scan pass 1: per chunk of 32 steps compute P_c = A_31..A_0, e_c.
// ---------------------------------------------------------------------------
__global__ __launch_bounds__(64) void scan_p1(
    const u16* __restrict__ gates, const float* __restrict__ vvT,
    float* __restrict__ Pmat, float* __restrict__ evec)
{
    const int c = blockIdx.x, chain = blockIdx.y;
    const int lane = threadIdx.x;
    const int i = lane >> 2, q = lane & 3;
    __shared__ alignas(16) u16   glds[32 * 272];
    __shared__ alignas(16) float vlds[32 * 16];
    __shared__ alignas(16) float Pb[2][256];
    __shared__ float slds[16];

    const char* gbase = (const char*)(gates + ((size_t)chain * T_ + c * 32) * 272);
    #pragma unroll
    for (int it = 0; it < 17; ++it)
        stage16(gbase + it * 1024 + lane * 16, (char*)glds + it * 1024);
    const char* vbase = (const char*)(vvT + ((size_t)chain * T_ + c * 32) * 16);
    #pragma unroll
    for (int it = 0; it < 2; ++it)
        stage16(vbase + it * 1024 + lane * 16, (char*)vlds + it * 1024);
    __syncthreads();

    scan_prep(glds, vlds, lane);

    {
        f32x4 idq;
        #pragma unroll
        for (int m = 0; m < 4; ++m) idq[m] = (i == q * 4 + m) ? 1.f : 0.f;
        *(f32x4*)&Pb[0][i * 16 + q * 4] = idq;
    }
    f32x4 e4[4] = {};
    f32x4 np = {};
    float neLast = 0.f;
    int cur = 0;

    for (int st = 0; st < 32; ++st) {
        const uint4* rp = (const uint4*)((const char*)glds + (st * 16 + i) * 32);
        uint4 d0 = rp[0], d1 = rp[1];
        float ar[16];
        ar[0]  = blo(d0.x); ar[1]  = bhi(d0.x);
        ar[2]  = blo(d0.y); ar[3]  = bhi(d0.y);
        ar[4]  = blo(d0.z); ar[5]  = bhi(d0.z);
        ar[6]  = blo(d0.w); ar[7]  = bhi(d0.w);
        ar[8]  = blo(d1.x); ar[9]  = bhi(d1.x);
        ar[10] = blo(d1.y); ar[11] = bhi(d1.y);
        ar[12] = blo(d1.z); ar[13] = bhi(d1.z);
        ar[14] = blo(d1.w); ar[15] = bhi(d1.w);

        f32x4 pk[16];
        #pragma unroll
        for (int k = 0; k < 16; ++k)
            pk[k] = *(const f32x4*)&Pb[cur][k * 16 + q * 4];

        f32x4 a = pk[0] * ar[0];
        #pragma unroll
        for (int k = 1; k < 16; ++k) a += pk[k] * ar[k];
        np = a;

        float ne0 = ar[0] * e4[0][0] + ar[1] * e4[0][1] + ar[2] * e4[0][2] + ar[3] * e4[0][3];
        float ne1 = ar[4] * e4[1][0] + ar[5] * e4[1][1] + ar[6] * e4[1][2] + ar[7] * e4[1][3];
        float ne2 = ar[8] * e4[2][0] + ar[9] * e4[2][1] + ar[10] * e4[2][2] + ar[11] * e4[2][3];
        float ne3 = ar[12] * e4[3][0] + ar[13] * e4[3][1] + ar[14] * e4[3][2] + ar[15] * e4[3][3];
        float ne = (ne0 + ne1) + (ne2 + ne3) + vlds[st * 16 + i];

        *(f32x4*)&Pb[cur ^ 1][i * 16 + q * 4] = np;
        if (q == 0) slds[i] = ne;
        #pragma unroll
        for (int m = 0; m < 4; ++m) e4[m] = *(const f32x4*)&slds[m * 4];
        neLast = ne;
        cur ^= 1;
    }

    float* Pd = Pmat + ((size_t)chain * 32 + c) * 256;
    *(f32x4*)&Pd[i * 16 + q * 4] = np;
    if (q == 0) evec[((size_t)chain * 32 + c) * 16 + i] = neLast;
}

// ---------------------------------------------------------------------------
// scan pass 2: per chain, sequentially combine 32 chunks; sIn[c] = entry state.
// ---------------------------------------------------------------------------
__global__ __launch_bounds__(64) void scan_comb(
    const float* __restrict__ Pmat, const float* __restrict__ evec, float* __restrict__ sIn)
{
    const int chain = blockIdx.x;
    const int lane = threadIdx.x;
    const int i = lane >> 2, q = lane & 3;
    __shared__ alignas(16) float Pl[32 * 256];
    __shared__ alignas(16) float El[32 * 16];
    __shared__ float slds[16];

    const char* Pg = (const char*)(Pmat + (size_t)chain * 32 * 256);
    #pragma unroll
    for (int it = 0; it < 32; ++it)
        stage16(Pg + it * 1024 + lane * 16, (char*)Pl + it * 1024);
    const char* Eg = (const char*)(evec + (size_t)chain * 32 * 16);
    #pragma unroll
    for (int it = 0; it < 2; ++it)
        stage16(Eg + it * 1024 + lane * 16, (char*)El + it * 1024);
    __syncthreads();

    f32x4 s4[4] = {};
    if (q == 0) sIn[((size_t)chain * 32 + 0) * 16 + i] = 0.f;
    for (int cc = 0; cc < 32; ++cc) {
        f32x4 pr[4];
        #pragma unroll
        for (int m = 0; m < 4; ++m)
            pr[m] = *(const f32x4*)&Pl[cc * 256 + i * 16 + m * 4];
        float ne = 0.f;
        #pragma unroll
        for (int k = 0; k < 16; ++k) ne += pr[k >> 2][k & 3] * s4[k >> 2][k & 3];
        ne += El[cc * 16 + i];
        if (q == 0) {
            slds[i] = ne;
            if (cc < 31) sIn[((size_t)chain * 32 + cc + 1) * 16 + i] = ne;
        }
        #pragma unroll
        for (int m = 0; m < 4; ++m) s4[m] = *(const f32x4*)&slds[m * 4];
    }
}

// ---------------------------------------------------------------------------
// scan pass 3: replay each chunk from its entry state, write h_out.
// ---------------------------------------------------------------------------
__global__ __launch_bounds__(64) void scan_p2(
    const u16* __restrict__ gates, const float* __restrict__ vvT,
    const float* __restrict__ sIn, u16* __restrict__ hout)
{
    const int c = blockIdx.x, chain = blockIdx.y;
    const int b = chain >> 6, hh = chain & 63;
    const int lane = threadIdx.x;
    const int i = lane >> 2, q = lane & 3;
    __shared__ alignas(16) u16   glds[32 * 272];
    __shared__ alignas(16) float vlds[32 * 16];
    __shared__ float slds[16];

    const char* gbase = (const char*)(gates + ((size_t)chain * T_ + c * 32) * 272);
    #pragma unroll
    for (int it = 0; it < 17; ++it)
        stage16(gbase + it * 1024 + lane * 16, (char*)glds + it * 1024);
    const char* vbase = (const char*)(vvT + ((size_t)chain * T_ + c * 32) * 16);
    #pragma unroll
    for (int it = 0; it < 2; ++it)
        stage16(vbase + it * 1024 + lane * 16, (char*)vlds + it * 1024);
    __syncthreads();

    scan_prep(glds, vlds, lane);

    const float* sp = sIn + ((size_t)chain * 32 + c) * 16;
    f32x4 s4[4];
    #pragma unroll
    for (int m = 0; m < 4; ++m) s4[m] = *(const f32x4*)(sp + m * 4);

    u16* hbase = hout + ((size_t)(b * T_ + c * 32)) * D_ + hh * 16;
    for (int st = 0; st < 32; ++st) {
        const uint4* rp = (const uint4*)((const char*)glds + (st * 16 + i) * 32);
        uint4 d0 = rp[0], d1 = rp[1];
        float ne0 = blo(d0.x) * s4[0][0] + bhi(d0.x) * s4[0][1]
                  + blo(d0.y) * s4[0][2] + bhi(d0.y) * s4[0][3];
        float ne1 = blo(d0.z) * s4[1][0] + bhi(d0.z) * s4[1][1]
                  + blo(d0.w) * s4[1][2] + bhi(d0.w) * s4[1][3];
        float ne2 = blo(d1.x) * s4[2][0] + bhi(d1.x) * s4[2][1]
                  + blo(d1.y) * s4[2][2] + bhi(d1.y) * s4[2][3];
        float ne3 = blo(d1.z) * s4[3][0] + bhi(d1.z) * s4[3][1]
                  + blo(d1.w) * s4[3][2] + bhi(d1.w) * s4[3][3];
        float ne = (ne0 + ne1) + (ne2 + ne3) + vlds[st * 16 + i];
        if (q == 0) {
            slds[i] = ne;
            hbase[(size_t)st * D_ + i] = f2b(ne);
        }
        #pragma unroll
        for (int m = 0; m < 4; ++m) s4[m] = *(const f32x4*)&slds[m * 4];
    }
}

// ---------------------------------------------------------------------------
extern "C" void kernel_launch(void* const* d_in, const int* in_sizes, int n_in,
                              void* d_out, int out_size, void* d_ws, size_t ws_size,
                              hipStream_t stream)
{
    const float* x    = (const float*)d_in[0];
    const float* anw  = (const float*)d_in[1];
    const float* wqkv = (const float*)d_in[2];
    const float* wao  = (const float*)d_in[3];
    const float* lnw  = (const float*)d_in[4];
    const float* wv   = (const float*)d_in[5];
    const float* wa   = (const float*)d_in[6];
    const float* wop  = (const float*)d_in[7];

    char* ws = (char*)d_ws;
    const size_t MB = 1u << 20;
    u16*   h     = (u16*)  (ws +   0 * MB);   //  4 MB
    u16*   h2    = (u16*)  (ws +   4 * MB);   //  4 MB
    u16*   wqkvT = (u16*)  (ws +   8 * MB);   //  6 MB
    u16*   waoT  = (u16*)  (ws +  14 * MB);   //  2 MB
    u16*   wopT  = (u16*)  (ws +  16 * MB);   //  2 MB
    u16*   waT   = (u16*)  (ws +  18 * MB);   // 36 MB (wa 17408 rows + wv 1024 rows)
    float* x2    = (float*)(ws +  54 * MB);   //  8 MB
    float* vvT   = (float*)(ws +  62 * MB);   //  8 MB scan layout [chain][t][16]
    u16*   Qb    = (u16*)  (ws +  78 * MB);   //  4 MB (dead after QK^T)
    float* Pmat  = (float*)(ws +  78 * MB);   //  4 MB aliases Qb
    u16*   Kb    = (u16*)  (ws +  82 * MB);   //  4 MB (dead after QK^T)
    float* evec  = (float*)(ws +  82 * MB);   // 256 KB aliases Kb
    float* sIn   = (float*)(ws +  82 * MB + 256 * 1024); // 256 KB
    u16*   Vb    = (u16*)  (ws +  86 * MB);   //  4 MB (dead after transpose)
    u16*   Vt    = (u16*)  (ws +  90 * MB);   //  4 MB (dead after PV)
    u16*   S     = (u16*)  (ws +  94 * MB);   // 64 MB (dead after PV)
    u16*   omat  = (u16*)  (ws + 158 * MB);   //  4 MB (dead after attn_out)
    u16*   gates = (u16*)  (ws +  94 * MB);   // 68 MB aliases S+omat
    u16*   hout  = (u16*)  (ws + 162 * MB);   //  4 MB (end: 166 MB)
    (void)in_sizes; (void)n_in; (void)out_size; (void)ws_size;

    dim3 tb(32, 8);
    convT_all<<<dim3(736, 32), tb, 0, stream>>>(
        wqkv, wao, wv, wa, wop, wqkvT, waoT, waT, wopT);

    rmsnorm_k<<<2048, 256, 0, stream>>>(x, anw, h);
    // qkv GEMM with fused RoPE epilogue -> Qb, Kb, Vb directly
    gemm_bt<64, 128, 32, 6, false, false, 0><<<dim3(24, 32, 1), 256, 0, stream>>>(
        h, wqkvT, (void*)Qb, (void*)Kb, (void*)Vb, nullptr, 2048, 3072, 1024, 0, 0, 0);
    transpose_bf16_k<<<dim3(2, 32, 32), tb, 0, stream>>>(Vb, Vt, 1024, 64);

    // QK^T: K=64 -> BK=64, single staging round per block
    gemm_bt<128, 128, 64, 1, false, true, 0><<<dim3(8, 8, 32), 256, 0, stream>>>(
        Qb, Kb, (void*)S, nullptr, nullptr, nullptr, 1024, 1024, 64, 65536, 65536, 1048576);
    softmax_causal_k<<<8192, 256, 0, stream>>>(S);
    // PV: BM=64, BK=64
    gemm_bt<64, 64, 64, 2, true, false, 0><<<dim3(1, 16, 32), 256, 0, stream>>>(
        S, Vt, (void*)omat, nullptr, nullptr, nullptr, 1024, 64, 1024, 1048576, 65536, 0);

    gemm_bt<64, 128, 32, 0, false, false, 0><<<dim3(8, 32, 1), 256, 0, stream>>>(
        omat, waoT, (void*)x2, nullptr, nullptr, x, 2048, 1024, 1024, 0, 0, 0);
    rmsnorm_k<<<2048, 256, 0, stream>>>(x2, lnw, h2);

    // fused gates + w_v GEMM: N = 17408 + 1024, BK=32, bx-band XCD swizzle
    gemm_bt<128, 128, 32, 5, false, false, 2><<<dim3(144, 16, 1), 256, 0, stream>>>(
        h2, waT, (void*)gates, (void*)vvT, nullptr, nullptr, 2048, 18432, 1024, 0, 0, 0);

    scan_p1<<<dim3(32, 128), 64, 0, stream>>>(gates, vvT, Pmat, evec);
    scan_comb<<<128, 64, 0, stream>>>(Pmat, evec, sIn);
    scan_p2<<<dim3(32, 128), 64, 0, stream>>>(gates, vvT, sIn, hout);

    gemm_bt<64, 128, 32, 0, false, false, 0><<<dim3(8, 32, 1), 256, 0, stream>>>(
        hout, wopT, d_out, nullptr, nullptr, x2, 2048, 1024, 1024, 0, 0, 0);
}